// Round 2
// baseline (444.836 us; speedup 1.0000x reference)
//
#include <hip/hip_runtime.h>
#include <hip/hip_bf16.h>

// Problem constants
#define B_    2
#define S_    2048
#define E_    2048
#define H_    16
#define HKV_  4
#define D_    128
#define QKV_  3072   // D*(H+2*HKV)

#define LOG2E  1.4426950408889634f
#define SCALE  0.08838834764831845f   // 1/sqrt(128)
#define SL     0.127517431f           // SCALE * LOG2E
#define DEFER_THR 62.7f               // 8 / SL: defer-max threshold (P <= 2^8)

typedef __attribute__((ext_vector_type(8))) short short8;   // 8 x bf16 (4 VGPRs)
typedef __attribute__((ext_vector_type(4))) float floatx4;  // MFMA 16x16 accumulator

typedef __attribute__((address_space(1))) const unsigned int gu32;
typedef __attribute__((address_space(3))) unsigned int lu32;

__device__ __forceinline__ void load_lds16(const unsigned short* g, unsigned short* l) {
    // async global->LDS, 16B/lane, dest = wave-uniform base + lane*16 (m97/m104)
    __builtin_amdgcn_global_load_lds((gu32*)g, (lu32*)l, 16, 0, 0);
}

__device__ __forceinline__ float b2f(unsigned short u) {
    union { unsigned int i; float f; } v; v.i = ((unsigned int)u) << 16; return v.f;
}
__device__ __forceinline__ unsigned short f2b(float f) {
    union { float f; unsigned int i; } v; v.f = f;
    unsigned int r = v.i + 0x7FFFu + ((v.i >> 16) & 1u);  // round-to-nearest-even
    return (unsigned short)(r >> 16);
}
__device__ __forceinline__ unsigned int fbits(float f) {
    union { float f; unsigned int i; } v; v.f = f; return v.i;
}
__device__ __forceinline__ float bits2f(unsigned int i) {
    union { unsigned int i; float f; } v; v.i = i; return v.f;
}

// counted vmcnt wait (never 0 in steady state; T4)
template<int N> __device__ __forceinline__ void waitcnt_vm() {
    static_assert(N >= 0 && N <= 8, "vmcnt out of range");
    if constexpr (N == 0) asm volatile("s_waitcnt vmcnt(0)" ::: "memory");
    else if constexpr (N == 1) asm volatile("s_waitcnt vmcnt(1)" ::: "memory");
    else if constexpr (N == 2) asm volatile("s_waitcnt vmcnt(2)" ::: "memory");
    else if constexpr (N == 3) asm volatile("s_waitcnt vmcnt(3)" ::: "memory");
    else if constexpr (N == 4) asm volatile("s_waitcnt vmcnt(4)" ::: "memory");
    else if constexpr (N == 5) asm volatile("s_waitcnt vmcnt(5)" ::: "memory");
    else if constexpr (N == 6) asm volatile("s_waitcnt vmcnt(6)" ::: "memory");
    else if constexpr (N == 7) asm volatile("s_waitcnt vmcnt(7)" ::: "memory");
    else asm volatile("s_waitcnt vmcnt(8)" ::: "memory");
}

// ---------------------------------------------------------------------------
// f32 -> bf16 convert (contiguous). 4 elems/thread.
// ---------------------------------------------------------------------------
__global__ __launch_bounds__(256) void cvt_f32_bf16(
    const float* __restrict__ src, unsigned short* __restrict__ dst, int n)
{
    int i = (blockIdx.x * 256 + threadIdx.x) * 4;
    if (i + 3 < n) {
        float4 v = *(const float4*)&src[i];
        ushort4 o;
        o.x = f2b(v.x); o.y = f2b(v.y); o.z = f2b(v.z); o.w = f2b(v.w);
        *(ushort4*)&dst[i] = o;
    }
}

// ---------------------------------------------------------------------------
// f32 -> bf16 transpose: src[R][C] f32 -> dst[C][R] bf16. block (32,8).
// ---------------------------------------------------------------------------
__global__ __launch_bounds__(256) void transpose_f32_bf16(
    const float* __restrict__ src, unsigned short* __restrict__ dst,
    int R, int C)
{
    __shared__ unsigned short tile[32][33];
    const int c0 = blockIdx.x * 32, r0 = blockIdx.y * 32;
    const int tx = threadIdx.x, ty = threadIdx.y;
    #pragma unroll
    for (int i = 0; i < 4; i++)
        tile[ty + 8 * i][tx] = f2b(src[(size_t)(r0 + ty + 8 * i) * C + c0 + tx]);
    __syncthreads();
    #pragma unroll
    for (int i = 0; i < 4; i++)
        dst[(size_t)(c0 + ty + 8 * i) * R + r0 + tx] = tile[tx][ty + 8 * i];
}

// ---------------------------------------------------------------------------
// bf16 -> bf16 batched transpose (for V): src[batch][R][C] -> dst[batch][C][R]
// ---------------------------------------------------------------------------
__global__ __launch_bounds__(256) void transpose_bf16(
    const unsigned short* __restrict__ src, unsigned short* __restrict__ dst,
    int R, int C)
{
    __shared__ unsigned short tile[32][33];
    const size_t boff = (size_t)blockIdx.z * R * C;
    src += boff; dst += boff;
    const int c0 = blockIdx.x * 32, r0 = blockIdx.y * 32;
    const int tx = threadIdx.x, ty = threadIdx.y;
    #pragma unroll
    for (int i = 0; i < 4; i++)
        tile[ty + 8 * i][tx] = src[(size_t)(r0 + ty + 8 * i) * C + c0 + tx];
    __syncthreads();
    #pragma unroll
    for (int i = 0; i < 4; i++)
        dst[(size_t)(c0 + ty + 8 * i) * R + r0 + tx] = tile[tx][ty + 8 * i];
}

// ---------------------------------------------------------------------------
// 8-phase 256-wide MFMA GEMM (m194-m204 template, plain HIP).
//   C[M][N] = A[M][K] @ Bt[N][K]^T + bias[N]
// BM=256 fixed; BN in {256,128}. 512 threads = 8 waves, wave grid WM x WN.
// K-tile BK=64 double-buffered; 4 phases per K-tile; counted vmcnt (T3+T4);
// setprio around MFMA clusters (T5); XCD-chunked block swizzle (T1);
// 16B-granule XOR swizzle realized as linear LDS dest + inverse-swizzled
// global source (rule #21).
// ---------------------------------------------------------------------------
template<int WR, int QR, int LX>
__device__ __forceinline__ void stage_unit8(
    const unsigned short* __restrict__ G, unsigned short* ls,
    int uu, int g0, int K, int k0, int wave, int lane)
{
    #pragma unroll
    for (int l = 0; l < LX; ++l) {
        const int c    = wave * LX + l;
        const int rr   = c / (QR / 8);
        const int row0 = rr * WR + uu * QR + (c % (QR / 8)) * 8;
        const int srow = row0 + (lane >> 3);
        const int sg   = (lane & 7) ^ (lane >> 3);
        load_lds16(&G[(size_t)(g0 + srow) * K + k0 + sg * 8], &ls[row0 * 64]);
    }
}

template<int BN, int WM, int WN, int OUTF32>
__global__ __launch_bounds__(512, 2) void gemm8(
    const unsigned short* __restrict__ A, const unsigned short* __restrict__ Bt,
    const float* __restrict__ bias, void* __restrict__ Cv,
    int M, int N, int K)
{
    constexpr int BM   = 256;
    constexpr int WMR  = BM / WM, WNR = BN / WN;   // wave tile
    constexpr int QMR  = WMR / 2, QNR = WNR / 2;   // quadrant
    constexpr int FM   = QMR / 16, FN = QNR / 16;  // frags per quadrant
    constexpr int LA   = BM / 128, LB = BN / 128;  // loads per unit
    constexpr int TILE = (BM + BN) * 64;           // ushorts per buffer

    __shared__ unsigned short lds[2 * TILE];       // 128 KiB (BN=256) / 96 KiB

    const int tid  = threadIdx.x;
    const int wave = tid >> 6, lane = tid & 63;
    const int ln   = lane & 15, kq = lane >> 4;
    const int wm   = wave / WN, wn = wave % WN;

    // T1: XCD-chunked swizzle (valid: nwg % 8 == 0 for both shapes)
    const int nwg = gridDim.x;
    const int wg  = (blockIdx.x & 7) * (nwg >> 3) + (blockIdx.x >> 3);
    const int nbn = N / BN;
    const int m0  = (wg / nbn) * BM, n0 = (wg % nbn) * BN;

    floatx4 acc[2 * FM][2 * FN];
    #pragma unroll
    for (int i = 0; i < 2 * FM; ++i)
        #pragma unroll
        for (int j = 0; j < 2 * FN; ++j) {
            acc[i][j][0] = 0.f; acc[i][j][1] = 0.f;
            acc[i][j][2] = 0.f; acc[i][j][3] = 0.f;
        }

    // prologue: stage K-tile 0 into buf 0, order [A0,B0,B1,A1]
    stage_unit8<WMR, QMR, LA>(A,  &lds[0],       0, m0, K, 0, wave, lane);
    stage_unit8<WNR, QNR, LB>(Bt, &lds[BM * 64], 0, n0, K, 0, wave, lane);
    stage_unit8<WNR, QNR, LB>(Bt, &lds[BM * 64], 1, n0, K, 0, wave, lane);
    stage_unit8<WMR, QMR, LA>(A,  &lds[0],       1, m0, K, 0, wave, lane);
    waitcnt_vm<LA + LB>();          // A0,B0 landed (B1,A1 still in flight)
    __builtin_amdgcn_s_barrier();

    const int NT = K >> 6;
    int cur = 0;

    for (int t = 0; t < NT - 1; ++t) {
        const unsigned short* Asp = &lds[cur * TILE];
        const unsigned short* Bsp = Asp + BM * 64;
        unsigned short* Ssp = &lds[(cur ^ 1) * TILE];
        const int k1 = (t + 1) << 6;
        #pragma unroll
        for (int p = 0; p < 4; ++p) {
            const int qm = p >> 1, qn = p & 1;
            // ds-read this quadrant's fragments (swizzled granule)
            short8 af[2][FM], bg[2][FN];
            #pragma unroll
            for (int ks = 0; ks < 2; ++ks) {
                #pragma unroll
                for (int i = 0; i < FM; ++i)
                    af[ks][i] = *(const short8*)&Asp[(wm * WMR + qm * QMR + i * 16 + ln) * 64
                                                     + (((ks * 4 + kq) ^ (ln & 7)) * 8)];
                #pragma unroll
                for (int j = 0; j < FN; ++j)
                    bg[ks][j] = *(const short8*)&Bsp[(wn * WNR + qn * QNR + j * 16 + ln) * 64
                                                     + (((ks * 4 + kq) ^ (ln & 7)) * 8)];
            }
            // stage one unit of K-tile t+1 into the other buffer
            if (p == 0)      stage_unit8<WMR, QMR, LA>(A,  Ssp,           0, m0, K, k1, wave, lane);
            else if (p == 1) stage_unit8<WNR, QNR, LB>(Bt, Ssp + BM * 64, 0, n0, K, k1, wave, lane);
            else if (p == 2) stage_unit8<WNR, QNR, LB>(Bt, Ssp + BM * 64, 1, n0, K, k1, wave, lane);
            else             stage_unit8<WMR, QMR, LA>(A,  Ssp,           1, m0, K, k1, wave, lane);
            __builtin_amdgcn_s_barrier();
            __builtin_amdgcn_s_setprio(1);
            #pragma unroll
            for (int ks = 0; ks < 2; ++ks)
                #pragma unroll
                for (int i = 0; i < FM; ++i)
                    #pragma unroll
                    for (int j = 0; j < FN; ++j)
                        acc[qm * FM + i][qn * FN + j] = __builtin_amdgcn_mfma_f32_16x16x32_bf16(
                            af[ks][i], bg[ks][j], acc[qm * FM + i][qn * FN + j], 0, 0, 0);
            __builtin_amdgcn_s_setprio(0);
            // counted wait guarding the NEXT phase's ds_reads (never 0)
            if (p == 0)      waitcnt_vm<2 * LA>();
            else if (p == 1) waitcnt_vm<LA + LB>();
            else if (p == 2) waitcnt_vm<LA + 2 * LB>();
            else             waitcnt_vm<LA + LB>();
            __builtin_amdgcn_s_barrier();
        }
        cur ^= 1;
    }

    // peeled last K-tile: drain once, then pure compute (no barriers needed)
    asm volatile("s_waitcnt vmcnt(0)" ::: "memory");
    __builtin_amdgcn_s_barrier();
    {
        const unsigned short* Asp = &lds[cur * TILE];
        const unsigned short* Bsp = Asp + BM * 64;
        #pragma unroll
        for (int p = 0; p < 4; ++p) {
            const int qm = p >> 1, qn = p & 1;
            short8 af[2][FM], bg[2][FN];
            #pragma unroll
            for (int ks = 0; ks < 2; ++ks) {
                #pragma unroll
                for (int i = 0; i < FM; ++i)
                    af[ks][i] = *(const short8*)&Asp[(wm * WMR + qm * QMR + i * 16 + ln) * 64
                                                     + (((ks * 4 + kq) ^ (ln & 7)) * 8)];
                #pragma unroll
                for (int j = 0; j < FN; ++j)
                    bg[ks][j] = *(const short8*)&Bsp[(wn * WNR + qn * QNR + j * 16 + ln) * 64
                                                     + (((ks * 4 + kq) ^ (ln & 7)) * 8)];
            }
            __builtin_amdgcn_s_setprio(1);
            #pragma unroll
            for (int ks = 0; ks < 2; ++ks)
                #pragma unroll
                for (int i = 0; i < FM; ++i)
                    #pragma unroll
                    for (int j = 0; j < FN; ++j)
                        acc[qm * FM + i][qn * FN + j] = __builtin_amdgcn_mfma_f32_16x16x32_bf16(
                            af[ks][i], bg[ks][j], acc[qm * FM + i][qn * FN + j], 0, 0, 0);
            __builtin_amdgcn_s_setprio(0);
        }
    }

    // epilogue: bias add + store (C/D map: col=ln, row=kq*4+r)
    #pragma unroll
    for (int nj = 0; nj < 2 * FN; ++nj) {
        const int col = n0 + wn * WNR + nj * 16 + ln;
        const float bv = bias[col];
        #pragma unroll
        for (int mi = 0; mi < 2 * FM; ++mi) {
            const int rowb = m0 + wm * WMR + mi * 16 + kq * 4;
            #pragma unroll
            for (int r = 0; r < 4; ++r) {
                const float val = acc[mi][nj][r] + bv;
                if (OUTF32) ((float*)Cv)[(size_t)(rowb + r) * N + col] = val;
                else ((unsigned short*)Cv)[(size_t)(rowb + r) * N + col] = f2b(val);
            }
        }
    }
}

// ---------------------------------------------------------------------------
// Fused depthwise causal conv (DCONV=4) + RoPE + q/k/v split-scatter.
// ---------------------------------------------------------------------------
__device__ __forceinline__ float conv_at(
    const unsigned short* __restrict__ qb, const float* __restrict__ cw,
    const float* __restrict__ cb, int s, int c)
{
    float acc = cb[c];
    const float* w = cw + c * 4;
    #pragma unroll
    for (int t = 0; t < 4; t++) {
        int sp = s - 3 + t;
        if (sp >= 0) acc += b2f(qb[(size_t)sp * QKV_ + c]) * w[t];
    }
    return acc;
}

__global__ __launch_bounds__(256) void conv_rot(
    const unsigned short* __restrict__ qkv, const float* __restrict__ cw,
    const float* __restrict__ cb, unsigned short* __restrict__ qo,
    unsigned short* __restrict__ ko, unsigned short* __restrict__ vo)
{
    const int bs = blockIdx.x;
    const int b = bs >> 11, s = bs & 2047;
    const unsigned short* qb = qkv + (size_t)b * S_ * QKV_;

    for (int it = threadIdx.x; it < 1792; it += 256) {
        if (it < 1280) {
            const int isq = it < 1024;
            const int rel = isq ? it : it - 1024;
            const int head = rel >> 6, d = rel & 63;
            const int c1 = (isq ? head * 128 : 2048 + head * 128) + d;
            float x1 = conv_at(qb, cw, cb, s, c1);
            float x2 = conv_at(qb, cw, cb, s, c1 + 64);
            float inv = exp2f((float)d * -0.2076205059304601f);  // 10000^(-d/64)
            float ang = (float)s * inv;
            float sn, cs;
            __sincosf(ang, &sn, &cs);   // fast-math: hw v_sin/v_cos, bf16-accurate
            float r1 = x1 * cs - x2 * sn;
            float r2 = x2 * cs + x1 * sn;
            unsigned short* dst = isq
                ? qo + ((size_t)(b * H_   + head) * S_ + s) * D_
                : ko + ((size_t)(b * HKV_ + head) * S_ + s) * D_;
            dst[d]      = f2b(r1);
            dst[d + 64] = f2b(r2);
        } else {
            const int idx = it - 1280;          // 0..511
            const int g = idx >> 7, d = idx & 127;
            float vv = conv_at(qb, cw, cb, s, 2560 + idx);
            vo[((size_t)(b * HKV_ + g) * S_ + s) * D_ + d] = f2b(vv);
        }
    }
}

// ---------------------------------------------------------------------------
// Flash attention (causal, GQA rep=4). Grid (h=16, qy=32, b=2), qt = 31-qy.
// 1024 blocks = 4/CU; LDS 40960 B; __launch_bounds__(256,4) caps VGPR at 128.
// T14 async-STAGE: K/V tile kt+1 global->REG loads issued right after tile
// kt's LDS writes; ds_write at next iteration top. The only vmcnt drain
// (first __syncthreads) coincides with when the data is needed.
// T13 defer-max: skip O-rescale when per-tile max growth <= 8/SL.
// T5 setprio around both MFMA clusters.
// LDS image identical to previous round (swizzle applied on ds_write addr).
// ---------------------------------------------------------------------------
__global__ __launch_bounds__(256, 4) void attn(
    const unsigned short* __restrict__ q, const unsigned short* __restrict__ k,
    const unsigned short* __restrict__ vT, unsigned short* __restrict__ ctx)
{
    __shared__ unsigned short Ks[64 * 128];    // 16 KB, swizzled
    __shared__ unsigned short Vs[128 * 64];    // 16 KB, swizzled
    __shared__ unsigned short Ps[4][16][64];   // 8 KB, per-wave, swizzled

    const int h = blockIdx.x, qt = 31 - blockIdx.y, b = blockIdx.z, g = h >> 2;
    const int tid = threadIdx.x, wave = tid >> 6, lane = tid & 63;
    const int ln = lane & 15, kq = lane >> 4;

    const unsigned short* qh = q  + (size_t)(b * H_   + h) * S_ * D_;
    const unsigned short* kh = k  + (size_t)(b * HKV_ + g) * S_ * D_;
    const unsigned short* vh = vT + (size_t)(b * HKV_ + g) * D_ * S_;

    // staging geometry (per wave, 4 chunks of 1 KB each for K and V)
    const int rK = (lane >> 4);          // +4*chunk rows of K per chunk
    const int pK = lane & 15;            // logical granule within K row
    const int rV = (lane >> 3);          // +8*chunk rows of V per chunk
    const int pV = lane & 7;             // logical granule within V row

    const int qrow0 = qt * 64 + wave * 16;

    short8 qf[4];
    #pragma unroll
    for (int f = 0; f < 4; f++)
        qf[f] = *(const short8*)&qh[(size_t)(qrow0 + ln) * D_ + f * 32 + kq * 8];

    floatx4 o[8];
    #pragma unroll
    for (int i = 0; i < 8; i++) { o[i][0] = 0.f; o[i][1] = 0.f; o[i][2] = 0.f; o[i][3] = 0.f; }
    float mr = -INFINITY, lr = 0.f;

    // T14 prologue: prefetch tile 0 into registers (coalesced, linear granule)
    short8 kpre[4], vpre[4];
    #pragma unroll
    for (int c = 0; c < 4; c++) {
        const int chunk = wave * 4 + c;
        kpre[c] = *(const short8*)&kh[(size_t)(chunk * 4 + rK) * D_ + pK * 8];
        vpre[c] = *(const short8*)&vh[(size_t)(chunk * 8 + rV) * S_ + pV * 8];
    }

    for (int kt = 0; kt <= qt; kt++) {
        __syncthreads();   // prev tile's LDS reads done by all waves; drains
                           // the in-flight prefetch (needed right now anyway)
        // LDS write with XOR swizzle on the write address (same image as
        // the old inverse-swizzled-source + linear global_load_lds)
        #pragma unroll
        for (int c = 0; c < 4; c++) {
            const int chunk = wave * 4 + c;
            const int r  = chunk * 4 + rK;
            const int rv = chunk * 8 + rV;
            *(short8*)&Ks[r * 128 + ((pK ^ (r & 15)) * 8)] = kpre[c];
            *(short8*)&Vs[rv * 64 + ((pV ^ (rv & 7)) * 8)] = vpre[c];
        }
        __syncthreads();   // writes visible (no vmem outstanding here)

        // issue next tile's global->reg loads; latency hides under compute
        if (kt < qt) {
            #pragma unroll
            for (int c = 0; c < 4; c++) {
                const int chunk = wave * 4 + c;
                kpre[c] = *(const short8*)&kh[(size_t)((kt + 1) * 64 + chunk * 4 + rK) * D_ + pK * 8];
                vpre[c] = *(const short8*)&vh[(size_t)(chunk * 8 + rV) * S_ + (kt + 1) * 64 + pV * 8];
            }
        }

        // S^T = K Q^T : per lane, 16 kv values for q-row (qrow0 + ln)
        floatx4 scv[4];
        #pragma unroll
        for (int nb = 0; nb < 4; nb++) { scv[nb][0]=0.f; scv[nb][1]=0.f; scv[nb][2]=0.f; scv[nb][3]=0.f; }
        __builtin_amdgcn_s_setprio(1);
        #pragma unroll
        for (int ks = 0; ks < 4; ks++) {
            #pragma unroll
            for (int nb = 0; nb < 4; nb++) {
                short8 kf = *(const short8*)&Ks[(nb * 16 + ln) * 128 + (((ks * 4 + kq) ^ ln) * 8)];
                scv[nb] = __builtin_amdgcn_mfma_f32_16x16x32_bf16(kf, qf[ks], scv[nb], 0, 0, 0);
            }
        }
        __builtin_amdgcn_s_setprio(0);

        // causal mask on diagonal tile:
        // kv_local = nb*16+kq*4+r, q_local (in 64-tile) = wave*16 + ln
        if (kt == qt) {
            const int qloc = wave * 16 + ln;
            #pragma unroll
            for (int nb = 0; nb < 4; nb++)
                #pragma unroll
                for (int r = 0; r < 4; r++)
                    if (nb * 16 + kq * 4 + r > qloc) scv[nb][r] = -INFINITY;
        }

        // per-lane online softmax (raw-score domain; SL folds scale+log2e)
        float mx = -INFINITY;
        #pragma unroll
        for (int nb = 0; nb < 4; nb++) {
            float a0 = fmaxf(scv[nb][0], scv[nb][1]);
            float a1 = fmaxf(scv[nb][2], scv[nb][3]);
            mx = fmaxf(mx, fmaxf(a0, a1));
        }
        mx = fmaxf(mx, __shfl_xor(mx, 16));
        mx = fmaxf(mx, __shfl_xor(mx, 32));

        // T13 defer-max: skip rescale when growth bounded (P <= 2^8, bf16-safe)
        float mt = mr, al = 1.0f;
        if (!__all(mx - mr <= DEFER_THR)) {
            mt = fmaxf(mr, mx);
            al = exp2f((mr - mt) * SL);
            mr = mt;
            float alr[4];
            #pragma unroll
            for (int r = 0; r < 4; r++) alr[r] = __shfl(al, kq * 4 + r);
            #pragma unroll
            for (int dn = 0; dn < 8; dn++)
                #pragma unroll
                for (int r = 0; r < 4; r++) o[dn][r] *= alr[r];
        }

        // p truncated to bf16 (denominator sums the SAME truncated values);
        // paired ds_write_b32 into granule-swizzled Ps (phys gran = g^(ln&7))
        float rs = 0.f;
        #pragma unroll
        for (int nb = 0; nb < 4; nb++) {
            const int gct = 2 * nb + (kq >> 1);
            const int pbase = ((gct ^ (ln & 7)) << 3) + ((kq & 1) << 2);
            #pragma unroll
            for (int rr = 0; rr < 2; rr++) {
                unsigned int u0 = fbits(exp2f((scv[nb][2 * rr]     - mt) * SL));
                unsigned int u1 = fbits(exp2f((scv[nb][2 * rr + 1] - mt) * SL));
                rs += bits2f(u0 & 0xFFFF0000u) + bits2f(u1 & 0xFFFF0000u);
                *(unsigned int*)&Ps[wave][ln][pbase + 2 * rr] =
                    (u0 >> 16) | (u1 & 0xFFFF0000u);
            }
        }
        rs += __shfl_xor(rs, 16);
        rs += __shfl_xor(rs, 32);
        lr = lr * al + rs;

        // O += P V  (Ps wave-private: lgkmcnt ordering suffices, no barrier)
        short8 pa0 = *(const short8*)&Ps[wave][ln][(kq ^ (ln & 7)) << 3];
        short8 pa1 = *(const short8*)&Ps[wave][ln][((4 + kq) ^ (ln & 7)) << 3];
        __builtin_amdgcn_s_setprio(1);
        #pragma unroll
        for (int dn = 0; dn < 8; dn++) {
            short8 b0 = *(const short8*)&Vs[(dn * 16 + ln) * 64 + ((kq ^ (ln & 7)) * 8)];
            o[dn] = __builtin_amdgcn_mfma_f32_16x16x32_bf16(pa0, b0, o[dn], 0, 0, 0);
            short8 b1 = *(const short8*)&Vs[(dn * 16 + ln) * 64 + (((4 + kq) ^ (ln & 7)) * 8)];
            o[dn] = __builtin_amdgcn_mfma_f32_16x16x32_bf16(pa1, b1, o[dn], 0, 0, 0);
        }
        __builtin_amdgcn_s_setprio(0);
    }

    // epilogue: broadcast 1/l to o-layout rows, write ctx[b*S+s][h*D+d]
    float lrr[4];
    #pragma unroll
    for (int r = 0; r < 4; r++) lrr[r] = 1.0f / __shfl(lr, kq * 4 + r);
    #pragma unroll
    for (int r = 0; r < 4; r++) {
        size_t rowoff = (size_t)(b * S_ + qt * 64 + wave * 16 + kq * 4 + r) * (H_ * D_) + h * D_;
        #pragma unroll
        for (int dn = 0; dn < 8; dn++)
            ctx[rowoff + dn * 16 + ln] = f2b(o[dn][r] * lrr[r]);
    }
}

// ---------------------------------------------------------------------------
// kernel_launch — ws layout (bf16 buffers, total 88 MB):
//   WtIn [3072][2048] @0 (12MB) | WtOut [2048][2048] @12MB (8MB)
//   x16 [4096][2048] @20MB (16MB, ctx aliases after GEMM1)
//   qkv [4096][3072] @36MB (24MB) | q @60MB (16MB) | k @76MB (4MB)
//   v @80MB (4MB) | vT @84MB (4MB)
// ---------------------------------------------------------------------------
extern "C" void kernel_launch(void* const* d_in, const int* in_sizes, int n_in,
                              void* d_out, int out_size, void* d_ws, size_t ws_size,
                              hipStream_t stream)
{
    const float* x     = (const float*)d_in[0];
    const float* W_in  = (const float*)d_in[1];
    const float* b_in  = (const float*)d_in[2];
    const float* cw    = (const float*)d_in[3];
    const float* cb    = (const float*)d_in[4];
    const float* W_out = (const float*)d_in[5];
    const float* b_out = (const float*)d_in[6];
    float* out = (float*)d_out;
    char* ws = (char*)d_ws;

    const size_t MB = 1024 * 1024;
    unsigned short* WtIn  = (unsigned short*)(ws);
    unsigned short* WtOut = (unsigned short*)(ws + 12 * MB);
    unsigned short* x16   = (unsigned short*)(ws + 20 * MB);
    unsigned short* qkv   = (unsigned short*)(ws + 36 * MB);
    unsigned short* qa    = (unsigned short*)(ws + 60 * MB);
    unsigned short* ka    = (unsigned short*)(ws + 76 * MB);
    unsigned short* va    = (unsigned short*)(ws + 80 * MB);
    unsigned short* vTa   = (unsigned short*)(ws + 84 * MB);
    unsigned short* ctx   = (unsigned short*)(ws + 20 * MB);  // aliases x16

    dim3 tb(32, 8);
    hipLaunchKernelGGL(cvt_f32_bf16, dim3(8192), dim3(256), 0, stream, x, x16, 8388608);
    hipLaunchKernelGGL(transpose_f32_bf16, dim3(96, 64), tb, 0, stream, W_in,  WtIn,  2048, 3072);
    hipLaunchKernelGGL(transpose_f32_bf16, dim3(64, 64), tb, 0, stream, W_out, WtOut, 2048, 2048);
    // GEMM1: 4096x3072x2048, 256x256 tiles -> 16x12 = 192 blocks (192%8==0)
    hipLaunchKernelGGL((gemm8<256, 2, 4, 0>), dim3(192), dim3(512), 0, stream,
                       x16, WtIn, b_in, (void*)qkv, 4096, 3072, 2048);
    hipLaunchKernelGGL(conv_rot, dim3(4096), dim3(256), 0, stream, qkv, cw, cb, qa, ka, va);
    hipLaunchKernelGGL(transpose_bf16, dim3(4, 64, 8), tb, 0, stream, va, vTa, 2048, 128);
    hipLaunchKernelGGL(attn, dim3(16, 32, 2), dim3(256), 0, stream, qa, ka, vTa, ctx);
    // GEMM2: 4096x2048x2048, 256x128 tiles -> 16x16 = 256 blocks (full device)
    hipLaunchKernelGGL((gemm8<128, 4, 2, 1>), dim3(256), dim3(512), 0, stream,
                       ctx, WtOut, b_out, (void*)out, 4096, 2048, 2048);
}

// Round 3
// 391.257 us; speedup vs baseline: 1.1369x; 1.1369x over previous
//
#include <hip/hip_runtime.h>
#include <hip/hip_bf16.h>

// Problem constants
#define B_    2
#define S_    2048
#define E_    2048
#define H_    16
#define HKV_  4
#define D_    128
#define QKV_  3072   // D*(H+2*HKV)

#define LOG2E  1.4426950408889634f
#define SCALE  0.08838834764831845f   // 1/sqrt(128)
#define SL     0.127517431f           // SCALE * LOG2E
#define DEFER_THR 62.7f               // 8 / SL: defer-max threshold (P <= 2^8)

typedef __attribute__((ext_vector_type(8))) short short8;   // 8 x bf16 (4 VGPRs)
typedef __attribute__((ext_vector_type(4))) float floatx4;  // MFMA 16x16 accumulator

typedef __attribute__((address_space(1))) const unsigned int gu32;
typedef __attribute__((address_space(3))) unsigned int lu32;

__device__ __forceinline__ void load_lds16(const unsigned short* g, unsigned short* l) {
    // async global->LDS, 16B/lane, dest = wave-uniform base + lane*16 (m97/m104)
    __builtin_amdgcn_global_load_lds((gu32*)g, (lu32*)l, 16, 0, 0);
}

__device__ __forceinline__ float b2f(unsigned short u) {
    union { unsigned int i; float f; } v; v.i = ((unsigned int)u) << 16; return v.f;
}
__device__ __forceinline__ unsigned short f2b(float f) {
    union { float f; unsigned int i; } v; v.f = f;
    unsigned int r = v.i + 0x7FFFu + ((v.i >> 16) & 1u);  // round-to-nearest-even
    return (unsigned short)(r >> 16);
}
__device__ __forceinline__ unsigned int fbits(float f) {
    union { float f; unsigned int i; } v; v.f = f; return v.i;
}
__device__ __forceinline__ float bits2f(unsigned int i) {
    union { unsigned int i; float f; } v; v.i = i; return v.f;
}

// counted vmcnt wait (never 0 in steady state; T4)
template<int N> __device__ __forceinline__ void waitcnt_vm() {
    static_assert(N >= 0 && N <= 16, "vmcnt out of range");
    if constexpr (N == 0) asm volatile("s_waitcnt vmcnt(0)" ::: "memory");
    else if constexpr (N == 4) asm volatile("s_waitcnt vmcnt(4)" ::: "memory");
    else if constexpr (N == 6) asm volatile("s_waitcnt vmcnt(6)" ::: "memory");
    else if constexpr (N == 8) asm volatile("s_waitcnt vmcnt(8)" ::: "memory");
    else asm volatile("s_waitcnt vmcnt(2)" ::: "memory");
}

// ---------------------------------------------------------------------------
// f32 -> bf16 convert (contiguous). 4 elems/thread.
// ---------------------------------------------------------------------------
__global__ __launch_bounds__(256) void cvt_f32_bf16(
    const float* __restrict__ src, unsigned short* __restrict__ dst, int n)
{
    int i = (blockIdx.x * 256 + threadIdx.x) * 4;
    if (i + 3 < n) {
        float4 v = *(const float4*)&src[i];
        ushort4 o;
        o.x = f2b(v.x); o.y = f2b(v.y); o.z = f2b(v.z); o.w = f2b(v.w);
        *(ushort4*)&dst[i] = o;
    }
}

// ---------------------------------------------------------------------------
// f32 -> bf16 transpose: src[R][C] f32 -> dst[C][R] bf16. block (32,8).
// ---------------------------------------------------------------------------
__global__ __launch_bounds__(256) void transpose_f32_bf16(
    const float* __restrict__ src, unsigned short* __restrict__ dst,
    int R, int C)
{
    __shared__ unsigned short tile[32][33];
    const int c0 = blockIdx.x * 32, r0 = blockIdx.y * 32;
    const int tx = threadIdx.x, ty = threadIdx.y;
    #pragma unroll
    for (int i = 0; i < 4; i++)
        tile[ty + 8 * i][tx] = f2b(src[(size_t)(r0 + ty + 8 * i) * C + c0 + tx]);
    __syncthreads();
    #pragma unroll
    for (int i = 0; i < 4; i++)
        dst[(size_t)(c0 + ty + 8 * i) * R + r0 + tx] = tile[tx][ty + 8 * i];
}

// ---------------------------------------------------------------------------
// bf16 -> bf16 batched transpose (for V): src[batch][R][C] -> dst[batch][C][R]
// ---------------------------------------------------------------------------
__global__ __launch_bounds__(256) void transpose_bf16(
    const unsigned short* __restrict__ src, unsigned short* __restrict__ dst,
    int R, int C)
{
    __shared__ unsigned short tile[32][33];
    const size_t boff = (size_t)blockIdx.z * R * C;
    src += boff; dst += boff;
    const int c0 = blockIdx.x * 32, r0 = blockIdx.y * 32;
    const int tx = threadIdx.x, ty = threadIdx.y;
    #pragma unroll
    for (int i = 0; i < 4; i++)
        tile[ty + 8 * i][tx] = src[(size_t)(r0 + ty + 8 * i) * C + c0 + tx];
    __syncthreads();
    #pragma unroll
    for (int i = 0; i < 4; i++)
        dst[(size_t)(c0 + ty + 8 * i) * R + r0 + tx] = tile[tx][ty + 8 * i];
}

// ---------------------------------------------------------------------------
// 8-phase 256-wide MFMA GEMM (m194-m204 template, plain HIP).
//   C[M][N] = A[M][K] @ Bt[N][K]^T + bias[N]
// BM=256 fixed; BN in {256,128}. 512 threads = 8 waves, wave grid WM x WN.
// K-tile BK=64 double-buffered; 4 phases per K-tile; counted vmcnt (T3+T4);
// setprio around MFMA clusters (T5); XCD-chunked block swizzle (T1);
// 16B-granule XOR swizzle realized as linear LDS dest + inverse-swizzled
// global source (rule #21).
// ---------------------------------------------------------------------------
template<int WR, int QR, int LX>
__device__ __forceinline__ void stage_unit8(
    const unsigned short* __restrict__ G, unsigned short* ls,
    int uu, int g0, int K, int k0, int wave, int lane)
{
    #pragma unroll
    for (int l = 0; l < LX; ++l) {
        const int c    = wave * LX + l;
        const int rr   = c / (QR / 8);
        const int row0 = rr * WR + uu * QR + (c % (QR / 8)) * 8;
        const int srow = row0 + (lane >> 3);
        const int sg   = (lane & 7) ^ (lane >> 3);
        load_lds16(&G[(size_t)(g0 + srow) * K + k0 + sg * 8], &ls[row0 * 64]);
    }
}

template<int BN, int WM, int WN, int OUTF32>
__global__ __launch_bounds__(512, 2) void gemm8(
    const unsigned short* __restrict__ A, const unsigned short* __restrict__ Bt,
    const float* __restrict__ bias, void* __restrict__ Cv,
    int M, int N, int K)
{
    constexpr int BM   = 256;
    constexpr int WMR  = BM / WM, WNR = BN / WN;   // wave tile
    constexpr int QMR  = WMR / 2, QNR = WNR / 2;   // quadrant
    constexpr int FM   = QMR / 16, FN = QNR / 16;  // frags per quadrant
    constexpr int LA   = BM / 128, LB = BN / 128;  // loads per unit
    constexpr int TILE = (BM + BN) * 64;           // ushorts per buffer

    __shared__ unsigned short lds[2 * TILE];       // 128 KiB (BN=256) / 96 KiB

    const int tid  = threadIdx.x;
    const int wave = tid >> 6, lane = tid & 63;
    const int ln   = lane & 15, kq = lane >> 4;
    const int wm   = wave / WN, wn = wave % WN;

    // T1: XCD-chunked swizzle (valid: nwg % 8 == 0 for both shapes)
    const int nwg = gridDim.x;
    const int wg  = (blockIdx.x & 7) * (nwg >> 3) + (blockIdx.x >> 3);
    const int nbn = N / BN;
    const int m0  = (wg / nbn) * BM, n0 = (wg % nbn) * BN;

    floatx4 acc[2 * FM][2 * FN];
    #pragma unroll
    for (int i = 0; i < 2 * FM; ++i)
        #pragma unroll
        for (int j = 0; j < 2 * FN; ++j) {
            acc[i][j][0] = 0.f; acc[i][j][1] = 0.f;
            acc[i][j][2] = 0.f; acc[i][j][3] = 0.f;
        }

    // prologue: stage K-tile 0 into buf 0, order [A0,B0,B1,A1]
    stage_unit8<WMR, QMR, LA>(A,  &lds[0],       0, m0, K, 0, wave, lane);
    stage_unit8<WNR, QNR, LB>(Bt, &lds[BM * 64], 0, n0, K, 0, wave, lane);
    stage_unit8<WNR, QNR, LB>(Bt, &lds[BM * 64], 1, n0, K, 0, wave, lane);
    stage_unit8<WMR, QMR, LA>(A,  &lds[0],       1, m0, K, 0, wave, lane);
    waitcnt_vm<4>();                // A0,B0 landed (B1,A1 still in flight)
    __builtin_amdgcn_s_barrier();

    const int NT = K >> 6;
    int cur = 0;

    for (int t = 0; t < NT - 1; ++t) {
        const unsigned short* Asp = &lds[cur * TILE];
        const unsigned short* Bsp = Asp + BM * 64;
        unsigned short* Ssp = &lds[(cur ^ 1) * TILE];
        const int k1 = (t + 1) << 6;
        #pragma unroll
        for (int p = 0; p < 4; ++p) {
            const int qm = p >> 1, qn = p & 1;
            // ds-read this quadrant's fragments (swizzled granule)
            short8 af[2][FM], bg[2][FN];
            #pragma unroll
            for (int ks = 0; ks < 2; ++ks) {
                #pragma unroll
                for (int i = 0; i < FM; ++i)
                    af[ks][i] = *(const short8*)&Asp[(wm * WMR + qm * QMR + i * 16 + ln) * 64
                                                     + (((ks * 4 + kq) ^ (ln & 7)) * 8)];
                #pragma unroll
                for (int j = 0; j < FN; ++j)
                    bg[ks][j] = *(const short8*)&Bsp[(wn * WNR + qn * QNR + j * 16 + ln) * 64
                                                     + (((ks * 4 + kq) ^ (ln & 7)) * 8)];
            }
            // stage one unit of K-tile t+1 into the other buffer
            if (p == 0)      stage_unit8<WMR, QMR, LA>(A,  Ssp,           0, m0, K, k1, wave, lane);
            else if (p == 1) stage_unit8<WNR, QNR, LB>(Bt, Ssp + BM * 64, 0, n0, K, k1, wave, lane);
            else if (p == 2) stage_unit8<WNR, QNR, LB>(Bt, Ssp + BM * 64, 1, n0, K, k1, wave, lane);
            else             stage_unit8<WMR, QMR, LA>(A,  Ssp,           1, m0, K, k1, wave, lane);
            __builtin_amdgcn_s_barrier();
            __builtin_amdgcn_s_setprio(1);
            #pragma unroll
            for (int ks = 0; ks < 2; ++ks)
                #pragma unroll
                for (int i = 0; i < FM; ++i)
                    #pragma unroll
                    for (int j = 0; j < FN; ++j)
                        acc[qm * FM + i][qn * FN + j] = __builtin_amdgcn_mfma_f32_16x16x32_bf16(
                            af[ks][i], bg[ks][j], acc[qm * FM + i][qn * FN + j], 0, 0, 0);
            __builtin_amdgcn_s_setprio(0);
            // counted wait guarding the NEXT phase's ds_reads (never 0)
            if (p == 0)      waitcnt_vm<2 * LA>();
            else if (p == 1) waitcnt_vm<LA + LB>();
            else if (p == 2) waitcnt_vm<LA + 2 * LB>();
            else             waitcnt_vm<LA + LB>();
            __builtin_amdgcn_s_barrier();
        }
        cur ^= 1;
    }

    // peeled last K-tile: drain once, then pure compute (no barriers needed)
    asm volatile("s_waitcnt vmcnt(0)" ::: "memory");
    __builtin_amdgcn_s_barrier();
    {
        const unsigned short* Asp = &lds[cur * TILE];
        const unsigned short* Bsp = Asp + BM * 64;
        #pragma unroll
        for (int p = 0; p < 4; ++p) {
            const int qm = p >> 1, qn = p & 1;
            short8 af[2][FM], bg[2][FN];
            #pragma unroll
            for (int ks = 0; ks < 2; ++ks) {
                #pragma unroll
                for (int i = 0; i < FM; ++i)
                    af[ks][i] = *(const short8*)&Asp[(wm * WMR + qm * QMR + i * 16 + ln) * 64
                                                     + (((ks * 4 + kq) ^ (ln & 7)) * 8)];
                #pragma unroll
                for (int j = 0; j < FN; ++j)
                    bg[ks][j] = *(const short8*)&Bsp[(wn * WNR + qn * QNR + j * 16 + ln) * 64
                                                     + (((ks * 4 + kq) ^ (ln & 7)) * 8)];
            }
            __builtin_amdgcn_s_setprio(1);
            #pragma unroll
            for (int ks = 0; ks < 2; ++ks)
                #pragma unroll
                for (int i = 0; i < FM; ++i)
                    #pragma unroll
                    for (int j = 0; j < FN; ++j)
                        acc[qm * FM + i][qn * FN + j] = __builtin_amdgcn_mfma_f32_16x16x32_bf16(
                            af[ks][i], bg[ks][j], acc[qm * FM + i][qn * FN + j], 0, 0, 0);
            __builtin_amdgcn_s_setprio(0);
        }
    }

    // epilogue: bias add + store (C/D map: col=ln, row=kq*4+r)
    #pragma unroll
    for (int nj = 0; nj < 2 * FN; ++nj) {
        const int col = n0 + wn * WNR + nj * 16 + ln;
        const float bv = bias[col];
        #pragma unroll
        for (int mi = 0; mi < 2 * FM; ++mi) {
            const int rowb = m0 + wm * WMR + mi * 16 + kq * 4;
            #pragma unroll
            for (int r = 0; r < 4; ++r) {
                const float val = acc[mi][nj][r] + bv;
                if (OUTF32) ((float*)Cv)[(size_t)(rowb + r) * N + col] = val;
                else ((unsigned short*)Cv)[(size_t)(rowb + r) * N + col] = f2b(val);
            }
        }
    }
}

// ---------------------------------------------------------------------------
// Fused depthwise causal conv (DCONV=4) + RoPE + q/k/v split-scatter.
// ---------------------------------------------------------------------------
__device__ __forceinline__ float conv_at(
    const unsigned short* __restrict__ qb, const float* __restrict__ cw,
    const float* __restrict__ cb, int s, int c)
{
    float acc = cb[c];
    const float* w = cw + c * 4;
    #pragma unroll
    for (int t = 0; t < 4; t++) {
        int sp = s - 3 + t;
        if (sp >= 0) acc += b2f(qb[(size_t)sp * QKV_ + c]) * w[t];
    }
    return acc;
}

__global__ __launch_bounds__(256) void conv_rot(
    const unsigned short* __restrict__ qkv, const float* __restrict__ cw,
    const float* __restrict__ cb, unsigned short* __restrict__ qo,
    unsigned short* __restrict__ ko, unsigned short* __restrict__ vo)
{
    const int bs = blockIdx.x;
    const int b = bs >> 11, s = bs & 2047;
    const unsigned short* qb = qkv + (size_t)b * S_ * QKV_;

    for (int it = threadIdx.x; it < 1792; it += 256) {
        if (it < 1280) {
            const int isq = it < 1024;
            const int rel = isq ? it : it - 1024;
            const int head = rel >> 6, d = rel & 63;
            const int c1 = (isq ? head * 128 : 2048 + head * 128) + d;
            float x1 = conv_at(qb, cw, cb, s, c1);
            float x2 = conv_at(qb, cw, cb, s, c1 + 64);
            float inv = exp2f((float)d * -0.2076205059304601f);  // 10000^(-d/64)
            float ang = (float)s * inv;
            float sn, cs;
            __sincosf(ang, &sn, &cs);   // fast-math: hw v_sin/v_cos, bf16-accurate
            float r1 = x1 * cs - x2 * sn;
            float r2 = x2 * cs + x1 * sn;
            unsigned short* dst = isq
                ? qo + ((size_t)(b * H_   + head) * S_ + s) * D_
                : ko + ((size_t)(b * HKV_ + head) * S_ + s) * D_;
            dst[d]      = f2b(r1);
            dst[d + 64] = f2b(r2);
        } else {
            const int idx = it - 1280;          // 0..511
            const int g = idx >> 7, d = idx & 127;
            float vv = conv_at(qb, cw, cb, s, 2560 + idx);
            vo[((size_t)(b * HKV_ + g) * S_ + s) * D_ + d] = f2b(vv);
        }
    }
}

// ---------------------------------------------------------------------------
// Flash attention (causal, GQA rep=4). QBLK=128: 4 waves x 32 q-rows (2 sets
// of 16). Each K/V LDS fragment read now feeds 2 MFMAs -> LDS bandwidth per
// MFMA halved vs the 64-row version (the measured binding resource).
// K/V double-buffered in LDS (80 KB total = exactly 2 blocks/CU); staging via
// global_load_lds issued at iteration top for tile kt+1, counted
// s_waitcnt vmcnt(8) waits only tile kt's loads (T3-min + T4; no reg staging
// -> no spill, cf. round-2 regression). T13 defer-max; T5 setprio.
// Grid (16 h, 16 qy, 2 b) = 512 blocks, qt = 15-qy for LPT backfill.
// ---------------------------------------------------------------------------
__device__ __forceinline__ void attn_stage(
    const unsigned short* __restrict__ kh, const unsigned short* __restrict__ vh,
    unsigned short* KsB, unsigned short* VsB,
    int kt, int wave, int rK, int pK, int rV, int pV)
{
    #pragma unroll
    for (int c = 0; c < 4; c++) {
        const int chunk = wave * 4 + c;        // 0..15
        const int r  = chunk * 4 + rK;
        const int gc = pK ^ (r & 15);
        load_lds16(&kh[(size_t)(kt * 64 + r) * D_ + gc * 8], &KsB[chunk * 512]);
        const int rv = chunk * 8 + rV;
        const int gv = pV ^ (rv & 7);
        load_lds16(&vh[(size_t)rv * S_ + kt * 64 + gv * 8], &VsB[chunk * 512]);
    }
}

__global__ __launch_bounds__(256, 2) void attn(
    const unsigned short* __restrict__ q, const unsigned short* __restrict__ k,
    const unsigned short* __restrict__ vT, unsigned short* __restrict__ ctx)
{
    __shared__ unsigned short Ks[2][64 * 128];   // 2 x 16 KB, swizzled
    __shared__ unsigned short Vs[2][128 * 64];   // 2 x 16 KB, swizzled
    __shared__ unsigned short Ps[4][32][64];     // 16 KB, per-wave, swizzled

    const int h = blockIdx.x, qt = 15 - blockIdx.y, b = blockIdx.z, g = h >> 2;
    const int tid = threadIdx.x, wave = tid >> 6, lane = tid & 63;
    const int ln = lane & 15, kq = lane >> 4;

    const unsigned short* qh = q  + (size_t)(b * H_   + h) * S_ * D_;
    const unsigned short* kh = k  + (size_t)(b * HKV_ + g) * S_ * D_;
    const unsigned short* vh = vT + (size_t)(b * HKV_ + g) * D_ * S_;

    const int rK = (lane >> 4);          // +4*chunk rows of K per chunk
    const int pK = lane & 15;            // logical granule within K row
    const int rV = (lane >> 3);          // +8*chunk rows of V per chunk
    const int pV = lane & 7;             // logical granule within V row

    const int qrb = qt * 128 + wave * 32;   // wave's first global q row

    short8 qf[2][4];
    #pragma unroll
    for (int s = 0; s < 2; s++)
        #pragma unroll
        for (int f = 0; f < 4; f++)
            qf[s][f] = *(const short8*)&qh[(size_t)(qrb + s * 16 + ln) * D_ + f * 32 + kq * 8];

    floatx4 o[2][8];
    #pragma unroll
    for (int s = 0; s < 2; s++)
        #pragma unroll
        for (int i = 0; i < 8; i++) { o[s][i][0]=0.f; o[s][i][1]=0.f; o[s][i][2]=0.f; o[s][i][3]=0.f; }
    float mr[2] = { -INFINITY, -INFINITY };
    float lr[2] = { 0.f, 0.f };

    const int KT = 2 * qt + 2;           // kv tiles covering q rows

    // prologue: stage tile 0 into buf 0
    attn_stage(kh, vh, &Ks[0][0], &Vs[0][0], 0, wave, rK, pK, rV, pV);

    for (int kt = 0; kt < KT; kt++) {
        const int buf = kt & 1;
        // issue next tile's staging into the other buffer (freed by the
        // end-of-previous-iteration barrier), then counted wait for THIS
        // tile's 8 loads (8 newer stay in flight)
        if (kt + 1 < KT) {
            attn_stage(kh, vh, &Ks[buf ^ 1][0], &Vs[buf ^ 1][0], kt + 1,
                       wave, rK, pK, rV, pV);
            waitcnt_vm<8>();
        } else {
            waitcnt_vm<0>();
        }
        __builtin_amdgcn_s_barrier();

        // S^T = K Q^T : each kf read feeds both q-sets (2 MFMAs)
        floatx4 scv[2][4];
        #pragma unroll
        for (int s = 0; s < 2; s++)
            #pragma unroll
            for (int nb = 0; nb < 4; nb++) { scv[s][nb][0]=0.f; scv[s][nb][1]=0.f; scv[s][nb][2]=0.f; scv[s][nb][3]=0.f; }
        __builtin_amdgcn_s_setprio(1);
        #pragma unroll
        for (int ks = 0; ks < 4; ks++) {
            #pragma unroll
            for (int nb = 0; nb < 4; nb++) {
                short8 kf = *(const short8*)&Ks[buf][(nb * 16 + ln) * 128 + (((ks * 4 + kq) ^ ln) * 8)];
                scv[0][nb] = __builtin_amdgcn_mfma_f32_16x16x32_bf16(kf, qf[0][ks], scv[0][nb], 0, 0, 0);
                scv[1][nb] = __builtin_amdgcn_mfma_f32_16x16x32_bf16(kf, qf[1][ks], scv[1][nb], 0, 0, 0);
            }
        }
        __builtin_amdgcn_s_setprio(0);

        // causal mask: only the last two kv tiles can cross the diagonal
        if (kt >= 2 * qt) {
            #pragma unroll
            for (int s = 0; s < 2; s++) {
                const int qi = qrb + s * 16 + ln;
                #pragma unroll
                for (int nb = 0; nb < 4; nb++)
                    #pragma unroll
                    for (int r = 0; r < 4; r++)
                        if (kt * 64 + nb * 16 + kq * 4 + r > qi) scv[s][nb][r] = -INFINITY;
            }
        }

        // per-lane online softmax per set (raw-score domain)
        float mx[2];
        #pragma unroll
        for (int s = 0; s < 2; s++) {
            float m = -INFINITY;
            #pragma unroll
            for (int nb = 0; nb < 4; nb++) {
                float a0 = fmaxf(scv[s][nb][0], scv[s][nb][1]);
                float a1 = fmaxf(scv[s][nb][2], scv[s][nb][3]);
                m = fmaxf(m, fmaxf(a0, a1));
            }
            m = fmaxf(m, __shfl_xor(m, 16));
            m = fmaxf(m, __shfl_xor(m, 32));
            mx[s] = m;
        }

        // T13 defer-max (joint over both sets)
        float mt[2] = { mr[0], mr[1] };
        float al[2] = { 1.0f, 1.0f };
        if (!__all((mx[0] - mr[0] <= DEFER_THR) && (mx[1] - mr[1] <= DEFER_THR))) {
            #pragma unroll
            for (int s = 0; s < 2; s++) {
                mt[s] = fmaxf(mr[s], mx[s]);
                al[s] = exp2f((mr[s] - mt[s]) * SL);
                mr[s] = mt[s];
                float alr[4];
                #pragma unroll
                for (int r = 0; r < 4; r++) alr[r] = __shfl(al[s], kq * 4 + r);
                #pragma unroll
                for (int dn = 0; dn < 8; dn++)
                    #pragma unroll
                    for (int r = 0; r < 4; r++) o[s][dn][r] *= alr[r];
            }
        }

        // p truncated to bf16 (denominator sums the SAME truncated values)
        #pragma unroll
        for (int s = 0; s < 2; s++) {
            float rs = 0.f;
            #pragma unroll
            for (int nb = 0; nb < 4; nb++) {
                const int gct = 2 * nb + (kq >> 1);
                const int pbase = ((gct ^ (ln & 7)) << 3) + ((kq & 1) << 2);
                #pragma unroll
                for (int rr = 0; rr < 2; rr++) {
                    unsigned int u0 = fbits(exp2f((scv[s][nb][2 * rr]     - mt[s]) * SL));
                    unsigned int u1 = fbits(exp2f((scv[s][nb][2 * rr + 1] - mt[s]) * SL));
                    rs += bits2f(u0 & 0xFFFF0000u) + bits2f(u1 & 0xFFFF0000u);
                    *(unsigned int*)&Ps[wave][s * 16 + ln][pbase + 2 * rr] =
                        (u0 >> 16) | (u1 & 0xFFFF0000u);
                }
            }
            rs += __shfl_xor(rs, 16);
            rs += __shfl_xor(rs, 32);
            lr[s] = lr[s] * al[s] + rs;
        }

        // O += P V : each Vs read feeds both q-sets (Ps wave-private)
        short8 pa[2][2];
        #pragma unroll
        for (int s = 0; s < 2; s++) {
            pa[s][0] = *(const short8*)&Ps[wave][s * 16 + ln][(kq ^ (ln & 7)) << 3];
            pa[s][1] = *(const short8*)&Ps[wave][s * 16 + ln][((4 + kq) ^ (ln & 7)) << 3];
        }
        __builtin_amdgcn_s_setprio(1);
        #pragma unroll
        for (int dn = 0; dn < 8; dn++) {
            short8 b0 = *(const short8*)&Vs[buf][(dn * 16 + ln) * 64 + ((kq ^ (ln & 7)) * 8)];
            o[0][dn] = __builtin_amdgcn_mfma_f32_16x16x32_bf16(pa[0][0], b0, o[0][dn], 0, 0, 0);
            o[1][dn] = __builtin_amdgcn_mfma_f32_16x16x32_bf16(pa[1][0], b0, o[1][dn], 0, 0, 0);
            short8 b1 = *(const short8*)&Vs[buf][(dn * 16 + ln) * 64 + (((4 + kq) ^ (ln & 7)) * 8)];
            o[0][dn] = __builtin_amdgcn_mfma_f32_16x16x32_bf16(pa[0][1], b1, o[0][dn], 0, 0, 0);
            o[1][dn] = __builtin_amdgcn_mfma_f32_16x16x32_bf16(pa[1][1], b1, o[1][dn], 0, 0, 0);
        }
        __builtin_amdgcn_s_setprio(0);

        __builtin_amdgcn_s_barrier();   // all waves done reading buf before
                                        // next iteration's stage overwrites it
    }

    // epilogue: per set, broadcast 1/l to o-layout rows, write ctx
    #pragma unroll
    for (int s = 0; s < 2; s++) {
        float lrr[4];
        #pragma unroll
        for (int r = 0; r < 4; r++) lrr[r] = 1.0f / __shfl(lr[s], kq * 4 + r);
        #pragma unroll
        for (int r = 0; r < 4; r++) {
            size_t rowoff = (size_t)(b * S_ + qrb + s * 16 + kq * 4 + r) * (H_ * D_) + h * D_;
            #pragma unroll
            for (int dn = 0; dn < 8; dn++)
                ctx[rowoff + dn * 16 + ln] = f2b(o[s][dn][r] * lrr[r]);
        }
    }
}

// ---------------------------------------------------------------------------
// kernel_launch — ws layout (bf16 buffers, total 88 MB):
//   WtIn [3072][2048] @0 (12MB) | WtOut [2048][2048] @12MB (8MB)
//   x16 [4096][2048] @20MB (16MB, ctx aliases after GEMM1)
//   qkv [4096][3072] @36MB (24MB) | q @60MB (16MB) | k @76MB (4MB)
//   v @80MB (4MB) | vT @84MB (4MB)
// ---------------------------------------------------------------------------
extern "C" void kernel_launch(void* const* d_in, const int* in_sizes, int n_in,
                              void* d_out, int out_size, void* d_ws, size_t ws_size,
                              hipStream_t stream)
{
    const float* x     = (const float*)d_in[0];
    const float* W_in  = (const float*)d_in[1];
    const float* b_in  = (const float*)d_in[2];
    const float* cw    = (const float*)d_in[3];
    const float* cb    = (const float*)d_in[4];
    const float* W_out = (const float*)d_in[5];
    const float* b_out = (const float*)d_in[6];
    float* out = (float*)d_out;
    char* ws = (char*)d_ws;

    const size_t MB = 1024 * 1024;
    unsigned short* WtIn  = (unsigned short*)(ws);
    unsigned short* WtOut = (unsigned short*)(ws + 12 * MB);
    unsigned short* x16   = (unsigned short*)(ws + 20 * MB);
    unsigned short* qkv   = (unsigned short*)(ws + 36 * MB);
    unsigned short* qa    = (unsigned short*)(ws + 60 * MB);
    unsigned short* ka    = (unsigned short*)(ws + 76 * MB);
    unsigned short* va    = (unsigned short*)(ws + 80 * MB);
    unsigned short* vTa   = (unsigned short*)(ws + 84 * MB);
    unsigned short* ctx   = (unsigned short*)(ws + 20 * MB);  // aliases x16

    dim3 tb(32, 8);
    hipLaunchKernelGGL(cvt_f32_bf16, dim3(8192), dim3(256), 0, stream, x, x16, 8388608);
    hipLaunchKernelGGL(transpose_f32_bf16, dim3(96, 64), tb, 0, stream, W_in,  WtIn,  2048, 3072);
    hipLaunchKernelGGL(transpose_f32_bf16, dim3(64, 64), tb, 0, stream, W_out, WtOut, 2048, 2048);
    // GEMM1: 4096x3072x2048, 256x256 tiles -> 16x12 = 192 blocks (192%8==0)
    hipLaunchKernelGGL((gemm8<256, 2, 4, 0>), dim3(192), dim3(512), 0, stream,
                       x16, WtIn, b_in, (void*)qkv, 4096, 3072, 2048);
    hipLaunchKernelGGL(conv_rot, dim3(4096), dim3(256), 0, stream, qkv, cw, cb, qa, ka, va);
    hipLaunchKernelGGL(transpose_bf16, dim3(4, 64, 8), tb, 0, stream, va, vTa, 2048, 128);
    // attn: QBLK=128, grid (h, qy=16, b) = 512 blocks, 2/CU
    hipLaunchKernelGGL(attn, dim3(16, 16, 2), dim3(256), 0, stream, qa, ka, vTa, ctx);
    // GEMM2: 4096x2048x2048, 256x128 tiles -> 16x16 = 256 blocks (full device)
    hipLaunchKernelGGL((gemm8<128, 4, 2, 1>), dim3(256), dim3(512), 0, stream,
                       ctx, WtOut, b_out, (void*)out, 4096, 2048, 2048);
}

// Round 4
// 367.014 us; speedup vs baseline: 1.2120x; 1.0661x over previous
//
#include <hip/hip_runtime.h>
#include <hip/hip_bf16.h>

// Problem constants
#define B_    2
#define S_    2048
#define E_    2048
#define H_    16
#define HKV_  4
#define D_    128
#define QKV_  3072   // D*(H+2*HKV)

#define LOG2E  1.4426950408889634f
#define SCALE  0.08838834764831845f   // 1/sqrt(128)
#define SL     0.127517431f           // SCALE * LOG2E
#define DEFER_THR 62.7f               // 8 / SL: defer-max threshold (P <= 2^8)

typedef __attribute__((ext_vector_type(8))) short short8;   // 8 x bf16 (4 VGPRs)
typedef __attribute__((ext_vector_type(4))) float floatx4;  // MFMA 16x16 accumulator

typedef __attribute__((address_space(1))) const unsigned int gu32;
typedef __attribute__((address_space(3))) unsigned int lu32;

__device__ __forceinline__ void load_lds16(const unsigned short* g, unsigned short* l) {
    // async global->LDS, 16B/lane, dest = wave-uniform base + lane*16 (m97/m104)
    __builtin_amdgcn_global_load_lds((gu32*)g, (lu32*)l, 16, 0, 0);
}

__device__ __forceinline__ float b2f(unsigned short u) {
    union { unsigned int i; float f; } v; v.i = ((unsigned int)u) << 16; return v.f;
}
__device__ __forceinline__ unsigned short f2b(float f) {
    union { float f; unsigned int i; } v; v.f = f;
    unsigned int r = v.i + 0x7FFFu + ((v.i >> 16) & 1u);  // round-to-nearest-even
    return (unsigned short)(r >> 16);
}
__device__ __forceinline__ unsigned int fbits(float f) {
    union { float f; unsigned int i; } v; v.f = f; return v.i;
}
__device__ __forceinline__ float bits2f(unsigned int i) {
    union { unsigned int i; float f; } v; v.i = i; return v.f;
}

// counted vmcnt wait (never 0 in steady state; T4)
template<int N> __device__ __forceinline__ void waitcnt_vm() {
    static_assert(N >= 0 && N <= 16, "vmcnt out of range");
    if constexpr (N == 0) asm volatile("s_waitcnt vmcnt(0)" ::: "memory");
    else if constexpr (N == 4) asm volatile("s_waitcnt vmcnt(4)" ::: "memory");
    else if constexpr (N == 6) asm volatile("s_waitcnt vmcnt(6)" ::: "memory");
    else if constexpr (N == 8) asm volatile("s_waitcnt vmcnt(8)" ::: "memory");
    else asm volatile("s_waitcnt vmcnt(2)" ::: "memory");
}

// ---------------------------------------------------------------------------
// f32 -> bf16 convert (contiguous). 4 elems/thread.
// ---------------------------------------------------------------------------
__global__ __launch_bounds__(256) void cvt_f32_bf16(
    const float* __restrict__ src, unsigned short* __restrict__ dst, int n)
{
    int i = (blockIdx.x * 256 + threadIdx.x) * 4;
    if (i + 3 < n) {
        float4 v = *(const float4*)&src[i];
        ushort4 o;
        o.x = f2b(v.x); o.y = f2b(v.y); o.z = f2b(v.z); o.w = f2b(v.w);
        *(ushort4*)&dst[i] = o;
    }
}

// ---------------------------------------------------------------------------
// f32 -> bf16 transpose: src[R][C] f32 -> dst[C][R] bf16. block (32,8).
// ---------------------------------------------------------------------------
__global__ __launch_bounds__(256) void transpose_f32_bf16(
    const float* __restrict__ src, unsigned short* __restrict__ dst,
    int R, int C)
{
    __shared__ unsigned short tile[32][33];
    const int c0 = blockIdx.x * 32, r0 = blockIdx.y * 32;
    const int tx = threadIdx.x, ty = threadIdx.y;
    #pragma unroll
    for (int i = 0; i < 4; i++)
        tile[ty + 8 * i][tx] = f2b(src[(size_t)(r0 + ty + 8 * i) * C + c0 + tx]);
    __syncthreads();
    #pragma unroll
    for (int i = 0; i < 4; i++)
        dst[(size_t)(c0 + ty + 8 * i) * R + r0 + tx] = tile[tx][ty + 8 * i];
}

// ---------------------------------------------------------------------------
// bf16 -> bf16 batched transpose (for V): src[batch][R][C] -> dst[batch][C][R]
// ---------------------------------------------------------------------------
__global__ __launch_bounds__(256) void transpose_bf16(
    const unsigned short* __restrict__ src, unsigned short* __restrict__ dst,
    int R, int C)
{
    __shared__ unsigned short tile[32][33];
    const size_t boff = (size_t)blockIdx.z * R * C;
    src += boff; dst += boff;
    const int c0 = blockIdx.x * 32, r0 = blockIdx.y * 32;
    const int tx = threadIdx.x, ty = threadIdx.y;
    #pragma unroll
    for (int i = 0; i < 4; i++)
        tile[ty + 8 * i][tx] = src[(size_t)(r0 + ty + 8 * i) * C + c0 + tx];
    __syncthreads();
    #pragma unroll
    for (int i = 0; i < 4; i++)
        dst[(size_t)(c0 + ty + 8 * i) * R + r0 + tx] = tile[tx][ty + 8 * i];
}

// ---------------------------------------------------------------------------
// 8-phase 256-wide MFMA GEMM (m194-m204 template, plain HIP).
//   C[M][N] = A[M][K] @ Bt[N][K]^T + bias[N]
// BM=256 fixed; BN in {256,128}. 512 threads = 8 waves, wave grid WM x WN.
// K-tile BK=64 double-buffered; 4 phases per K-tile; counted vmcnt (T3+T4);
// setprio around MFMA clusters (T5); XCD-chunked block swizzle (T1);
// 16B-granule XOR swizzle realized as linear LDS dest + inverse-swizzled
// global source (rule #21).
// ---------------------------------------------------------------------------
template<int WR, int QR, int LX>
__device__ __forceinline__ void stage_unit8(
    const unsigned short* __restrict__ G, unsigned short* ls,
    int uu, int g0, int K, int k0, int wave, int lane)
{
    #pragma unroll
    for (int l = 0; l < LX; ++l) {
        const int c    = wave * LX + l;
        const int rr   = c / (QR / 8);
        const int row0 = rr * WR + uu * QR + (c % (QR / 8)) * 8;
        const int srow = row0 + (lane >> 3);
        const int sg   = (lane & 7) ^ (lane >> 3);
        load_lds16(&G[(size_t)(g0 + srow) * K + k0 + sg * 8], &ls[row0 * 64]);
    }
}

template<int BN, int WM, int WN, int OUTF32>
__global__ __launch_bounds__(512, 2) void gemm8(
    const unsigned short* __restrict__ A, const unsigned short* __restrict__ Bt,
    const float* __restrict__ bias, void* __restrict__ Cv,
    int M, int N, int K)
{
    constexpr int BM   = 256;
    constexpr int WMR  = BM / WM, WNR = BN / WN;   // wave tile
    constexpr int QMR  = WMR / 2, QNR = WNR / 2;   // quadrant
    constexpr int FM   = QMR / 16, FN = QNR / 16;  // frags per quadrant
    constexpr int LA   = BM / 128, LB = BN / 128;  // loads per unit
    constexpr int TILE = (BM + BN) * 64;           // ushorts per buffer

    __shared__ unsigned short lds[2 * TILE];       // 128 KiB (BN=256) / 96 KiB

    const int tid  = threadIdx.x;
    const int wave = tid >> 6, lane = tid & 63;
    const int ln   = lane & 15, kq = lane >> 4;
    const int wm   = wave / WN, wn = wave % WN;

    // T1: XCD-chunked swizzle (valid: nwg % 8 == 0 for both shapes)
    const int nwg = gridDim.x;
    const int wg  = (blockIdx.x & 7) * (nwg >> 3) + (blockIdx.x >> 3);
    const int nbn = N / BN;
    const int m0  = (wg / nbn) * BM, n0 = (wg % nbn) * BN;

    floatx4 acc[2 * FM][2 * FN];
    #pragma unroll
    for (int i = 0; i < 2 * FM; ++i)
        #pragma unroll
        for (int j = 0; j < 2 * FN; ++j) {
            acc[i][j][0] = 0.f; acc[i][j][1] = 0.f;
            acc[i][j][2] = 0.f; acc[i][j][3] = 0.f;
        }

    // prologue: stage K-tile 0 into buf 0, order [A0,B0,B1,A1]
    stage_unit8<WMR, QMR, LA>(A,  &lds[0],       0, m0, K, 0, wave, lane);
    stage_unit8<WNR, QNR, LB>(Bt, &lds[BM * 64], 0, n0, K, 0, wave, lane);
    stage_unit8<WNR, QNR, LB>(Bt, &lds[BM * 64], 1, n0, K, 0, wave, lane);
    stage_unit8<WMR, QMR, LA>(A,  &lds[0],       1, m0, K, 0, wave, lane);
    waitcnt_vm<4>();                // A0,B0 landed (B1,A1 still in flight)
    __builtin_amdgcn_s_barrier();

    const int NT = K >> 6;
    int cur = 0;

    for (int t = 0; t < NT - 1; ++t) {
        const unsigned short* Asp = &lds[cur * TILE];
        const unsigned short* Bsp = Asp + BM * 64;
        unsigned short* Ssp = &lds[(cur ^ 1) * TILE];
        const int k1 = (t + 1) << 6;
        #pragma unroll
        for (int p = 0; p < 4; ++p) {
            const int qm = p >> 1, qn = p & 1;
            // ds-read this quadrant's fragments (swizzled granule)
            short8 af[2][FM], bg[2][FN];
            #pragma unroll
            for (int ks = 0; ks < 2; ++ks) {
                #pragma unroll
                for (int i = 0; i < FM; ++i)
                    af[ks][i] = *(const short8*)&Asp[(wm * WMR + qm * QMR + i * 16 + ln) * 64
                                                     + (((ks * 4 + kq) ^ (ln & 7)) * 8)];
                #pragma unroll
                for (int j = 0; j < FN; ++j)
                    bg[ks][j] = *(const short8*)&Bsp[(wn * WNR + qn * QNR + j * 16 + ln) * 64
                                                     + (((ks * 4 + kq) ^ (ln & 7)) * 8)];
            }
            // stage one unit of K-tile t+1 into the other buffer
            if (p == 0)      stage_unit8<WMR, QMR, LA>(A,  Ssp,           0, m0, K, k1, wave, lane);
            else if (p == 1) stage_unit8<WNR, QNR, LB>(Bt, Ssp + BM * 64, 0, n0, K, k1, wave, lane);
            else if (p == 2) stage_unit8<WNR, QNR, LB>(Bt, Ssp + BM * 64, 1, n0, K, k1, wave, lane);
            else             stage_unit8<WMR, QMR, LA>(A,  Ssp,           1, m0, K, k1, wave, lane);
            __builtin_amdgcn_s_barrier();
            __builtin_amdgcn_s_setprio(1);
            #pragma unroll
            for (int ks = 0; ks < 2; ++ks)
                #pragma unroll
                for (int i = 0; i < FM; ++i)
                    #pragma unroll
                    for (int j = 0; j < FN; ++j)
                        acc[qm * FM + i][qn * FN + j] = __builtin_amdgcn_mfma_f32_16x16x32_bf16(
                            af[ks][i], bg[ks][j], acc[qm * FM + i][qn * FN + j], 0, 0, 0);
            __builtin_amdgcn_s_setprio(0);
            // counted wait guarding the NEXT phase's ds_reads (never 0)
            if (p == 0)      waitcnt_vm<2 * LA>();
            else if (p == 1) waitcnt_vm<LA + LB>();
            else if (p == 2) waitcnt_vm<LA + 2 * LB>();
            else             waitcnt_vm<LA + LB>();
            __builtin_amdgcn_s_barrier();
        }
        cur ^= 1;
    }

    // peeled last K-tile: drain once, then pure compute (no barriers needed)
    asm volatile("s_waitcnt vmcnt(0)" ::: "memory");
    __builtin_amdgcn_s_barrier();
    {
        const unsigned short* Asp = &lds[cur * TILE];
        const unsigned short* Bsp = Asp + BM * 64;
        #pragma unroll
        for (int p = 0; p < 4; ++p) {
            const int qm = p >> 1, qn = p & 1;
            short8 af[2][FM], bg[2][FN];
            #pragma unroll
            for (int ks = 0; ks < 2; ++ks) {
                #pragma unroll
                for (int i = 0; i < FM; ++i)
                    af[ks][i] = *(const short8*)&Asp[(wm * WMR + qm * QMR + i * 16 + ln) * 64
                                                     + (((ks * 4 + kq) ^ (ln & 7)) * 8)];
                #pragma unroll
                for (int j = 0; j < FN; ++j)
                    bg[ks][j] = *(const short8*)&Bsp[(wn * WNR + qn * QNR + j * 16 + ln) * 64
                                                     + (((ks * 4 + kq) ^ (ln & 7)) * 8)];
            }
            __builtin_amdgcn_s_setprio(1);
            #pragma unroll
            for (int ks = 0; ks < 2; ++ks)
                #pragma unroll
                for (int i = 0; i < FM; ++i)
                    #pragma unroll
                    for (int j = 0; j < FN; ++j)
                        acc[qm * FM + i][qn * FN + j] = __builtin_amdgcn_mfma_f32_16x16x32_bf16(
                            af[ks][i], bg[ks][j], acc[qm * FM + i][qn * FN + j], 0, 0, 0);
            __builtin_amdgcn_s_setprio(0);
        }
    }

    // epilogue: bias add + store (C/D map: col=ln, row=kq*4+r)
    #pragma unroll
    for (int nj = 0; nj < 2 * FN; ++nj) {
        const int col = n0 + wn * WNR + nj * 16 + ln;
        const float bv = bias[col];
        #pragma unroll
        for (int mi = 0; mi < 2 * FM; ++mi) {
            const int rowb = m0 + wm * WMR + mi * 16 + kq * 4;
            #pragma unroll
            for (int r = 0; r < 4; ++r) {
                const float val = acc[mi][nj][r] + bv;
                if (OUTF32) ((float*)Cv)[(size_t)(rowb + r) * N + col] = val;
                else ((unsigned short*)Cv)[(size_t)(rowb + r) * N + col] = f2b(val);
            }
        }
    }
}

// ---------------------------------------------------------------------------
// Fused depthwise causal conv (DCONV=4) + RoPE + q/k/v split-scatter.
// ---------------------------------------------------------------------------
__device__ __forceinline__ float conv_at(
    const unsigned short* __restrict__ qb, const float* __restrict__ cw,
    const float* __restrict__ cb, int s, int c)
{
    float acc = cb[c];
    const float* w = cw + c * 4;
    #pragma unroll
    for (int t = 0; t < 4; t++) {
        int sp = s - 3 + t;
        if (sp >= 0) acc += b2f(qb[(size_t)sp * QKV_ + c]) * w[t];
    }
    return acc;
}

__global__ __launch_bounds__(256) void conv_rot(
    const unsigned short* __restrict__ qkv, const float* __restrict__ cw,
    const float* __restrict__ cb, unsigned short* __restrict__ qo,
    unsigned short* __restrict__ ko, unsigned short* __restrict__ vo)
{
    const int bs = blockIdx.x;
    const int b = bs >> 11, s = bs & 2047;
    const unsigned short* qb = qkv + (size_t)b * S_ * QKV_;

    for (int it = threadIdx.x; it < 1792; it += 256) {
        if (it < 1280) {
            const int isq = it < 1024;
            const int rel = isq ? it : it - 1024;
            const int head = rel >> 6, d = rel & 63;
            const int c1 = (isq ? head * 128 : 2048 + head * 128) + d;
            float x1 = conv_at(qb, cw, cb, s, c1);
            float x2 = conv_at(qb, cw, cb, s, c1 + 64);
            float inv = exp2f((float)d * -0.2076205059304601f);  // 10000^(-d/64)
            float ang = (float)s * inv;
            float sn, cs;
            __sincosf(ang, &sn, &cs);   // fast-math: hw v_sin/v_cos, bf16-accurate
            float r1 = x1 * cs - x2 * sn;
            float r2 = x2 * cs + x1 * sn;
            unsigned short* dst = isq
                ? qo + ((size_t)(b * H_   + head) * S_ + s) * D_
                : ko + ((size_t)(b * HKV_ + head) * S_ + s) * D_;
            dst[d]      = f2b(r1);
            dst[d + 64] = f2b(r2);
        } else {
            const int idx = it - 1280;          // 0..511
            const int g = idx >> 7, d = idx & 127;
            float vv = conv_at(qb, cw, cb, s, 2560 + idx);
            vo[((size_t)(b * HKV_ + g) * S_ + s) * D_ + d] = f2b(vv);
        }
    }
}

// ---------------------------------------------------------------------------
// Flash attention (causal, GQA rep=4). Grid (h=16, qy=32, b=2), 1024 blocks
// = exactly 4/CU -> ALL blocks resident from t=0, no backfill. Block->CU
// placement is round-robin in blockIdx (XCD = blockIdx%8 measured), so CU c
// hosts blocks {c, c+256, c+512, c+768} with qy in {qy0, qy0+16}. Work per
// block ~ (qt+1). PAIRED qt MAP: qt = qy<16 ? 31-qy : qy-16 makes each CU's
// load = (31-qy0+1)+(qy0+1) = 33 tile-iters x2 -> constant across CUs
// (round-1 measured 22% avg occupancy = 2.6x CU imbalance from qt=31-qy).
// LDS 40960 B so 4 blocks/CU; __launch_bounds__(256,4) caps VGPR (meas. 64).
// T13 defer-max skips O-rescale when tile max growth <= 8/SL; T5 setprio
// around both MFMA clusters. Staging = global_load_lds direct (round-1
// proven; reg-prefetch spilled in round 2 -> never again at this VGPR cap).
// ---------------------------------------------------------------------------
__global__ __launch_bounds__(256, 4) void attn(
    const unsigned short* __restrict__ q, const unsigned short* __restrict__ k,
    const unsigned short* __restrict__ vT, unsigned short* __restrict__ ctx)
{
    __shared__ unsigned short Ks[64 * 128];    // 16 KB, swizzled
    __shared__ unsigned short Vs[128 * 64];    // 16 KB, swizzled
    __shared__ unsigned short Ps[4][16][64];   // 8 KB, per-wave, swizzled

    const int h = blockIdx.x, qy = blockIdx.y, b = blockIdx.z, g = h >> 2;
    const int qt = (qy < 16) ? (31 - qy) : (qy - 16);   // paired-load CU map
    const int tid = threadIdx.x, wave = tid >> 6, lane = tid & 63;
    const int ln = lane & 15, kq = lane >> 4;

    const unsigned short* qh = q  + (size_t)(b * H_   + h) * S_ * D_;
    const unsigned short* kh = k  + (size_t)(b * HKV_ + g) * S_ * D_;
    const unsigned short* vh = vT + (size_t)(b * HKV_ + g) * D_ * S_;

    // staging geometry (per wave, 4 chunks of 1 KB each for K and V)
    const int rK = (lane >> 4);          // +4*chunk rows of K per chunk
    const int pK = lane & 15;            // phys granule within K row
    const int rV = (lane >> 3);          // +8*chunk rows of V per chunk
    const int pV = lane & 7;             // phys granule within V row

    const int qrow0 = qt * 64 + wave * 16;

    short8 qf[4];
    #pragma unroll
    for (int f = 0; f < 4; f++)
        qf[f] = *(const short8*)&qh[(size_t)(qrow0 + ln) * D_ + f * 32 + kq * 8];

    floatx4 o[8];
    #pragma unroll
    for (int i = 0; i < 8; i++) { o[i][0] = 0.f; o[i][1] = 0.f; o[i][2] = 0.f; o[i][3] = 0.f; }
    float mr = -INFINITY, lr = 0.f;

    for (int kt = 0; kt <= qt; kt++) {
        __syncthreads();   // previous tile's LDS reads complete
        #pragma unroll
        for (int c = 0; c < 4; c++) {
            const int chunk = wave * 4 + c;        // 0..15
            // K: rows r = chunk*4 + rK, logical granule = pK ^ (r&15)
            int r  = chunk * 4 + rK;
            int gc = pK ^ (r & 15);
            load_lds16(&kh[(size_t)(kt * 64 + r) * D_ + gc * 8], &Ks[chunk * 512]);
            // V: rows rv = chunk*8 + rV, logical granule = pV ^ (rv&7)
            int rv = chunk * 8 + rV;
            int gv = pV ^ (rv & 7);
            load_lds16(&vh[(size_t)rv * S_ + kt * 64 + gv * 8], &Vs[chunk * 512]);
        }
        __syncthreads();   // vmcnt drained before barrier

        // S^T = K Q^T : per lane, 16 kv values for q-row (qrow0 + ln)
        floatx4 scv[4];
        #pragma unroll
        for (int nb = 0; nb < 4; nb++) { scv[nb][0]=0.f; scv[nb][1]=0.f; scv[nb][2]=0.f; scv[nb][3]=0.f; }
        __builtin_amdgcn_s_setprio(1);
        #pragma unroll
        for (int ks = 0; ks < 4; ks++) {
            #pragma unroll
            for (int nb = 0; nb < 4; nb++) {
                short8 kf = *(const short8*)&Ks[(nb * 16 + ln) * 128 + (((ks * 4 + kq) ^ ln) * 8)];
                scv[nb] = __builtin_amdgcn_mfma_f32_16x16x32_bf16(kf, qf[ks], scv[nb], 0, 0, 0);
            }
        }
        __builtin_amdgcn_s_setprio(0);

        // causal mask on diagonal tile:
        // kv_local = nb*16+kq*4+r, q_local (in 64-tile) = wave*16 + ln
        if (kt == qt) {
            const int qloc = wave * 16 + ln;
            #pragma unroll
            for (int nb = 0; nb < 4; nb++)
                #pragma unroll
                for (int r = 0; r < 4; r++)
                    if (nb * 16 + kq * 4 + r > qloc) scv[nb][r] = -INFINITY;
        }

        // per-lane online softmax (raw-score domain; SL folds scale+log2e)
        float mx = -INFINITY;
        #pragma unroll
        for (int nb = 0; nb < 4; nb++) {
            float a0 = fmaxf(scv[nb][0], scv[nb][1]);
            float a1 = fmaxf(scv[nb][2], scv[nb][3]);
            mx = fmaxf(mx, fmaxf(a0, a1));
        }
        mx = fmaxf(mx, __shfl_xor(mx, 16));
        mx = fmaxf(mx, __shfl_xor(mx, 32));

        // T13 defer-max: skip rescale when growth bounded (P <= 2^8, bf16-safe)
        float mt = mr, al = 1.0f;
        if (!__all(mx - mr <= DEFER_THR)) {
            mt = fmaxf(mr, mx);
            al = exp2f((mr - mt) * SL);
            mr = mt;
            float alr[4];
            #pragma unroll
            for (int r = 0; r < 4; r++) alr[r] = __shfl(al, kq * 4 + r);
            #pragma unroll
            for (int dn = 0; dn < 8; dn++)
                #pragma unroll
                for (int r = 0; r < 4; r++) o[dn][r] *= alr[r];
        }

        // p truncated to bf16 (denominator sums the SAME truncated values);
        // paired ds_write_b32 into granule-swizzled Ps (phys gran = g^(ln&7))
        float rs = 0.f;
        #pragma unroll
        for (int nb = 0; nb < 4; nb++) {
            const int gct = 2 * nb + (kq >> 1);
            const int pbase = ((gct ^ (ln & 7)) << 3) + ((kq & 1) << 2);
            #pragma unroll
            for (int rr = 0; rr < 2; rr++) {
                unsigned int u0 = fbits(exp2f((scv[nb][2 * rr]     - mt) * SL));
                unsigned int u1 = fbits(exp2f((scv[nb][2 * rr + 1] - mt) * SL));
                rs += bits2f(u0 & 0xFFFF0000u) + bits2f(u1 & 0xFFFF0000u);
                *(unsigned int*)&Ps[wave][ln][pbase + 2 * rr] =
                    (u0 >> 16) | (u1 & 0xFFFF0000u);
            }
        }
        rs += __shfl_xor(rs, 16);
        rs += __shfl_xor(rs, 32);
        lr = lr * al + rs;

        // O += P V  (Ps wave-private: lgkmcnt ordering suffices, no barrier)
        short8 pa0 = *(const short8*)&Ps[wave][ln][(kq ^ (ln & 7)) << 3];
        short8 pa1 = *(const short8*)&Ps[wave][ln][((4 + kq) ^ (ln & 7)) << 3];
        __builtin_amdgcn_s_setprio(1);
        #pragma unroll
        for (int dn = 0; dn < 8; dn++) {
            short8 b0 = *(const short8*)&Vs[(dn * 16 + ln) * 64 + ((kq ^ (ln & 7)) * 8)];
            o[dn] = __builtin_amdgcn_mfma_f32_16x16x32_bf16(pa0, b0, o[dn], 0, 0, 0);
            short8 b1 = *(const short8*)&Vs[(dn * 16 + ln) * 64 + (((4 + kq) ^ (ln & 7)) * 8)];
            o[dn] = __builtin_amdgcn_mfma_f32_16x16x32_bf16(pa1, b1, o[dn], 0, 0, 0);
        }
        __builtin_amdgcn_s_setprio(0);
    }

    // epilogue: broadcast 1/l to o-layout rows, write ctx[b*S+s][h*D+d]
    float lrr[4];
    #pragma unroll
    for (int r = 0; r < 4; r++) lrr[r] = 1.0f / __shfl(lr, kq * 4 + r);
    #pragma unroll
    for (int r = 0; r < 4; r++) {
        size_t rowoff = (size_t)(b * S_ + qt * 64 + wave * 16 + kq * 4 + r) * (H_ * D_) + h * D_;
        #pragma unroll
        for (int dn = 0; dn < 8; dn++)
            ctx[rowoff + dn * 16 + ln] = f2b(o[dn][r] * lrr[r]);
    }
}

// ---------------------------------------------------------------------------
// kernel_launch — ws layout (bf16 buffers, total 88 MB):
//   WtIn [3072][2048] @0 (12MB) | WtOut [2048][2048] @12MB (8MB)
//   x16 [4096][2048] @20MB (16MB, ctx aliases after GEMM1)
//   qkv [4096][3072] @36MB (24MB) | q @60MB (16MB) | k @76MB (4MB)
//   v @80MB (4MB) | vT @84MB (4MB)
// ---------------------------------------------------------------------------
extern "C" void kernel_launch(void* const* d_in, const int* in_sizes, int n_in,
                              void* d_out, int out_size, void* d_ws, size_t ws_size,
                              hipStream_t stream)
{
    const float* x     = (const float*)d_in[0];
    const float* W_in  = (const float*)d_in[1];
    const float* b_in  = (const float*)d_in[2];
    const float* cw    = (const float*)d_in[3];
    const float* cb    = (const float*)d_in[4];
    const float* W_out = (const float*)d_in[5];
    const float* b_out = (const float*)d_in[6];
    float* out = (float*)d_out;
    char* ws = (char*)d_ws;

    const size_t MB = 1024 * 1024;
    unsigned short* WtIn  = (unsigned short*)(ws);
    unsigned short* WtOut = (unsigned short*)(ws + 12 * MB);
    unsigned short* x16   = (unsigned short*)(ws + 20 * MB);
    unsigned short* qkv   = (unsigned short*)(ws + 36 * MB);
    unsigned short* qa    = (unsigned short*)(ws + 60 * MB);
    unsigned short* ka    = (unsigned short*)(ws + 76 * MB);
    unsigned short* va    = (unsigned short*)(ws + 80 * MB);
    unsigned short* vTa   = (unsigned short*)(ws + 84 * MB);
    unsigned short* ctx   = (unsigned short*)(ws + 20 * MB);  // aliases x16

    dim3 tb(32, 8);
    hipLaunchKernelGGL(cvt_f32_bf16, dim3(8192), dim3(256), 0, stream, x, x16, 8388608);
    hipLaunchKernelGGL(transpose_f32_bf16, dim3(96, 64), tb, 0, stream, W_in,  WtIn,  2048, 3072);
    hipLaunchKernelGGL(transpose_f32_bf16, dim3(64, 64), tb, 0, stream, W_out, WtOut, 2048, 2048);
    // GEMM1: 4096x3072x2048, 256x256 tiles -> 16x12 = 192 blocks (192%8==0)
    hipLaunchKernelGGL((gemm8<256, 2, 4, 0>), dim3(192), dim3(512), 0, stream,
                       x16, WtIn, b_in, (void*)qkv, 4096, 3072, 2048);
    hipLaunchKernelGGL(conv_rot, dim3(4096), dim3(256), 0, stream, qkv, cw, cb, qa, ka, va);
    hipLaunchKernelGGL(transpose_bf16, dim3(4, 64, 8), tb, 0, stream, va, vTa, 2048, 128);
    hipLaunchKernelGGL(attn, dim3(16, 32, 2), dim3(256), 0, stream, qa, ka, vTa, ctx);
    // GEMM2: 4096x2048x2048, 256x128 tiles -> 16x16 = 256 blocks (full device)
    hipLaunchKernelGGL((gemm8<128, 4, 2, 1>), dim3(256), dim3(512), 0, stream,
                       ctx, WtOut, b_out, (void*)out, 4096, 2048, 2048);
}

// Round 5
// 363.027 us; speedup vs baseline: 1.2254x; 1.0110x over previous
//
#include <hip/hip_runtime.h>
#include <hip/hip_bf16.h>

// Problem constants
#define B_    2
#define S_    2048
#define E_    2048
#define H_    16
#define HKV_  4
#define D_    128
#define QKV_  3072   // D*(H+2*HKV)

#define LOG2E  1.4426950408889634f
#define SCALE  0.08838834764831845f   // 1/sqrt(128)
#define SL     0.127517431f           // SCALE * LOG2E
#define DEFER_THR 62.7f               // 8 / SL: defer-max threshold (P <= 2^8)

typedef __attribute__((ext_vector_type(8))) short short8;   // 8 x bf16 (4 VGPRs)
typedef __attribute__((ext_vector_type(4))) float floatx4;  // MFMA 16x16 accumulator

typedef __attribute__((address_space(1))) const unsigned int gu32;
typedef __attribute__((address_space(3))) unsigned int lu32;

__device__ __forceinline__ void load_lds16(const unsigned short* g, unsigned short* l) {
    // async global->LDS, 16B/lane, dest = wave-uniform base + lane*16 (m97/m104)
    __builtin_amdgcn_global_load_lds((gu32*)g, (lu32*)l, 16, 0, 0);
}

__device__ __forceinline__ float b2f(unsigned short u) {
    union { unsigned int i; float f; } v; v.i = ((unsigned int)u) << 16; return v.f;
}
__device__ __forceinline__ unsigned short f2b(float f) {
    union { float f; unsigned int i; } v; v.f = f;
    unsigned int r = v.i + 0x7FFFu + ((v.i >> 16) & 1u);  // round-to-nearest-even
    return (unsigned short)(r >> 16);
}
__device__ __forceinline__ unsigned int fbits(float f) {
    union { float f; unsigned int i; } v; v.f = f; return v.i;
}
__device__ __forceinline__ float bits2f(unsigned int i) {
    union { unsigned int i; float f; } v; v.i = i; return v.f;
}

// counted vmcnt wait (never 0 in steady state; T4)
template<int N> __device__ __forceinline__ void waitcnt_vm() {
    static_assert(N >= 0 && N <= 16, "vmcnt out of range");
    if constexpr (N == 0) asm volatile("s_waitcnt vmcnt(0)" ::: "memory");
    else if constexpr (N == 4) asm volatile("s_waitcnt vmcnt(4)" ::: "memory");
    else if constexpr (N == 6) asm volatile("s_waitcnt vmcnt(6)" ::: "memory");
    else if constexpr (N == 8) asm volatile("s_waitcnt vmcnt(8)" ::: "memory");
    else asm volatile("s_waitcnt vmcnt(2)" ::: "memory");
}

// ---------------------------------------------------------------------------
// f32 -> bf16 convert (contiguous). 4 elems/thread.
// ---------------------------------------------------------------------------
__global__ __launch_bounds__(256) void cvt_f32_bf16(
    const float* __restrict__ src, unsigned short* __restrict__ dst, int n)
{
    int i = (blockIdx.x * 256 + threadIdx.x) * 4;
    if (i + 3 < n) {
        float4 v = *(const float4*)&src[i];
        ushort4 o;
        o.x = f2b(v.x); o.y = f2b(v.y); o.z = f2b(v.z); o.w = f2b(v.w);
        *(ushort4*)&dst[i] = o;
    }
}

// ---------------------------------------------------------------------------
// f32 -> bf16 transpose: src[R][C] f32 -> dst[C][R] bf16. block (32,8).
// ---------------------------------------------------------------------------
__global__ __launch_bounds__(256) void transpose_f32_bf16(
    const float* __restrict__ src, unsigned short* __restrict__ dst,
    int R, int C)
{
    __shared__ unsigned short tile[32][33];
    const int c0 = blockIdx.x * 32, r0 = blockIdx.y * 32;
    const int tx = threadIdx.x, ty = threadIdx.y;
    #pragma unroll
    for (int i = 0; i < 4; i++)
        tile[ty + 8 * i][tx] = f2b(src[(size_t)(r0 + ty + 8 * i) * C + c0 + tx]);
    __syncthreads();
    #pragma unroll
    for (int i = 0; i < 4; i++)
        dst[(size_t)(c0 + ty + 8 * i) * R + r0 + tx] = tile[tx][ty + 8 * i];
}

// ---------------------------------------------------------------------------
// bf16 -> bf16 batched transpose (for V): src[batch][R][C] -> dst[batch][C][R]
// ---------------------------------------------------------------------------
__global__ __launch_bounds__(256) void transpose_bf16(
    const unsigned short* __restrict__ src, unsigned short* __restrict__ dst,
    int R, int C)
{
    __shared__ unsigned short tile[32][33];
    const size_t boff = (size_t)blockIdx.z * R * C;
    src += boff; dst += boff;
    const int c0 = blockIdx.x * 32, r0 = blockIdx.y * 32;
    const int tx = threadIdx.x, ty = threadIdx.y;
    #pragma unroll
    for (int i = 0; i < 4; i++)
        tile[ty + 8 * i][tx] = src[(size_t)(r0 + ty + 8 * i) * C + c0 + tx];
    __syncthreads();
    #pragma unroll
    for (int i = 0; i < 4; i++)
        dst[(size_t)(c0 + ty + 8 * i) * R + r0 + tx] = tile[tx][ty + 8 * i];
}

// ---------------------------------------------------------------------------
// 8-phase 256-wide MFMA GEMM (m194-m204 template, plain HIP).
//   C[M][N] = A[M][K] @ Bt[N][K]^T + bias[N]
// BM=256 fixed; BN in {256,128}. 512 threads = 8 waves, wave grid WM x WN.
// K-tile BK=64 double-buffered; 4 phases per K-tile; counted vmcnt (T3+T4);
// setprio around MFMA clusters (T5); XCD-chunked block swizzle (T1);
// 16B-granule XOR swizzle realized as linear LDS dest + inverse-swizzled
// global source (rule #21).
// ---------------------------------------------------------------------------
template<int WR, int QR, int LX>
__device__ __forceinline__ void stage_unit8(
    const unsigned short* __restrict__ G, unsigned short* ls,
    int uu, int g0, int K, int k0, int wave, int lane)
{
    #pragma unroll
    for (int l = 0; l < LX; ++l) {
        const int c    = wave * LX + l;
        const int rr   = c / (QR / 8);
        const int row0 = rr * WR + uu * QR + (c % (QR / 8)) * 8;
        const int srow = row0 + (lane >> 3);
        const int sg   = (lane & 7) ^ (lane >> 3);
        load_lds16(&G[(size_t)(g0 + srow) * K + k0 + sg * 8], &ls[row0 * 64]);
    }
}

template<int BN, int WM, int WN, int OUTF32>
__global__ __launch_bounds__(512, 2) void gemm8(
    const unsigned short* __restrict__ A, const unsigned short* __restrict__ Bt,
    const float* __restrict__ bias, void* __restrict__ Cv,
    int M, int N, int K)
{
    constexpr int BM   = 256;
    constexpr int WMR  = BM / WM, WNR = BN / WN;   // wave tile
    constexpr int QMR  = WMR / 2, QNR = WNR / 2;   // quadrant
    constexpr int FM   = QMR / 16, FN = QNR / 16;  // frags per quadrant
    constexpr int LA   = BM / 128, LB = BN / 128;  // loads per unit
    constexpr int TILE = (BM + BN) * 64;           // ushorts per buffer

    __shared__ unsigned short lds[2 * TILE];       // 128 KiB (BN=256) / 96 KiB

    const int tid  = threadIdx.x;
    const int wave = tid >> 6, lane = tid & 63;
    const int ln   = lane & 15, kq = lane >> 4;
    const int wm   = wave / WN, wn = wave % WN;

    // T1: XCD-chunked swizzle (valid: nwg % 8 == 0 for both shapes)
    const int nwg = gridDim.x;
    const int wg  = (blockIdx.x & 7) * (nwg >> 3) + (blockIdx.x >> 3);
    const int nbn = N / BN;
    const int m0  = (wg / nbn) * BM, n0 = (wg % nbn) * BN;

    floatx4 acc[2 * FM][2 * FN];
    #pragma unroll
    for (int i = 0; i < 2 * FM; ++i)
        #pragma unroll
        for (int j = 0; j < 2 * FN; ++j) {
            acc[i][j][0] = 0.f; acc[i][j][1] = 0.f;
            acc[i][j][2] = 0.f; acc[i][j][3] = 0.f;
        }

    // prologue: stage K-tile 0 into buf 0, order [A0,B0,B1,A1]
    stage_unit8<WMR, QMR, LA>(A,  &lds[0],       0, m0, K, 0, wave, lane);
    stage_unit8<WNR, QNR, LB>(Bt, &lds[BM * 64], 0, n0, K, 0, wave, lane);
    stage_unit8<WNR, QNR, LB>(Bt, &lds[BM * 64], 1, n0, K, 0, wave, lane);
    stage_unit8<WMR, QMR, LA>(A,  &lds[0],       1, m0, K, 0, wave, lane);
    waitcnt_vm<4>();                // A0,B0 landed (B1,A1 still in flight)
    __builtin_amdgcn_s_barrier();

    const int NT = K >> 6;
    int cur = 0;

    for (int t = 0; t < NT - 1; ++t) {
        const unsigned short* Asp = &lds[cur * TILE];
        const unsigned short* Bsp = Asp + BM * 64;
        unsigned short* Ssp = &lds[(cur ^ 1) * TILE];
        const int k1 = (t + 1) << 6;
        #pragma unroll
        for (int p = 0; p < 4; ++p) {
            const int qm = p >> 1, qn = p & 1;
            // ds-read this quadrant's fragments (swizzled granule)
            short8 af[2][FM], bg[2][FN];
            #pragma unroll
            for (int ks = 0; ks < 2; ++ks) {
                #pragma unroll
                for (int i = 0; i < FM; ++i)
                    af[ks][i] = *(const short8*)&Asp[(wm * WMR + qm * QMR + i * 16 + ln) * 64
                                                     + (((ks * 4 + kq) ^ (ln & 7)) * 8)];
                #pragma unroll
                for (int j = 0; j < FN; ++j)
                    bg[ks][j] = *(const short8*)&Bsp[(wn * WNR + qn * QNR + j * 16 + ln) * 64
                                                     + (((ks * 4 + kq) ^ (ln & 7)) * 8)];
            }
            // stage one unit of K-tile t+1 into the other buffer
            if (p == 0)      stage_unit8<WMR, QMR, LA>(A,  Ssp,           0, m0, K, k1, wave, lane);
            else if (p == 1) stage_unit8<WNR, QNR, LB>(Bt, Ssp + BM * 64, 0, n0, K, k1, wave, lane);
            else if (p == 2) stage_unit8<WNR, QNR, LB>(Bt, Ssp + BM * 64, 1, n0, K, k1, wave, lane);
            else             stage_unit8<WMR, QMR, LA>(A,  Ssp,           1, m0, K, k1, wave, lane);
            __builtin_amdgcn_s_barrier();
            __builtin_amdgcn_s_setprio(1);
            #pragma unroll
            for (int ks = 0; ks < 2; ++ks)
                #pragma unroll
                for (int i = 0; i < FM; ++i)
                    #pragma unroll
                    for (int j = 0; j < FN; ++j)
                        acc[qm * FM + i][qn * FN + j] = __builtin_amdgcn_mfma_f32_16x16x32_bf16(
                            af[ks][i], bg[ks][j], acc[qm * FM + i][qn * FN + j], 0, 0, 0);
            __builtin_amdgcn_s_setprio(0);
            // counted wait guarding the NEXT phase's ds_reads (never 0)
            if (p == 0)      waitcnt_vm<2 * LA>();
            else if (p == 1) waitcnt_vm<LA + LB>();
            else if (p == 2) waitcnt_vm<LA + 2 * LB>();
            else             waitcnt_vm<LA + LB>();
            __builtin_amdgcn_s_barrier();
        }
        cur ^= 1;
    }

    // peeled last K-tile: drain once, then pure compute (no barriers needed)
    asm volatile("s_waitcnt vmcnt(0)" ::: "memory");
    __builtin_amdgcn_s_barrier();
    {
        const unsigned short* Asp = &lds[cur * TILE];
        const unsigned short* Bsp = Asp + BM * 64;
        #pragma unroll
        for (int p = 0; p < 4; ++p) {
            const int qm = p >> 1, qn = p & 1;
            short8 af[2][FM], bg[2][FN];
            #pragma unroll
            for (int ks = 0; ks < 2; ++ks) {
                #pragma unroll
                for (int i = 0; i < FM; ++i)
                    af[ks][i] = *(const short8*)&Asp[(wm * WMR + qm * QMR + i * 16 + ln) * 64
                                                     + (((ks * 4 + kq) ^ (ln & 7)) * 8)];
                #pragma unroll
                for (int j = 0; j < FN; ++j)
                    bg[ks][j] = *(const short8*)&Bsp[(wn * WNR + qn * QNR + j * 16 + ln) * 64
                                                     + (((ks * 4 + kq) ^ (ln & 7)) * 8)];
            }
            __builtin_amdgcn_s_setprio(1);
            #pragma unroll
            for (int ks = 0; ks < 2; ++ks)
                #pragma unroll
                for (int i = 0; i < FM; ++i)
                    #pragma unroll
                    for (int j = 0; j < FN; ++j)
                        acc[qm * FM + i][qn * FN + j] = __builtin_amdgcn_mfma_f32_16x16x32_bf16(
                            af[ks][i], bg[ks][j], acc[qm * FM + i][qn * FN + j], 0, 0, 0);
            __builtin_amdgcn_s_setprio(0);
        }
    }

    // epilogue: bias add + store (C/D map: col=ln, row=kq*4+r)
    #pragma unroll
    for (int nj = 0; nj < 2 * FN; ++nj) {
        const int col = n0 + wn * WNR + nj * 16 + ln;
        const float bv = bias[col];
        #pragma unroll
        for (int mi = 0; mi < 2 * FM; ++mi) {
            const int rowb = m0 + wm * WMR + mi * 16 + kq * 4;
            #pragma unroll
            for (int r = 0; r < 4; ++r) {
                const float val = acc[mi][nj][r] + bv;
                if (OUTF32) ((float*)Cv)[(size_t)(rowb + r) * N + col] = val;
                else ((unsigned short*)Cv)[(size_t)(rowb + r) * N + col] = f2b(val);
            }
        }
    }
}

// ---------------------------------------------------------------------------
// Fused depthwise causal conv (DCONV=4) + RoPE + q/k/v split-scatter.
// ---------------------------------------------------------------------------
__device__ __forceinline__ float conv_at(
    const unsigned short* __restrict__ qb, const float* __restrict__ cw,
    const float* __restrict__ cb, int s, int c)
{
    float acc = cb[c];
    const float* w = cw + c * 4;
    #pragma unroll
    for (int t = 0; t < 4; t++) {
        int sp = s - 3 + t;
        if (sp >= 0) acc += b2f(qb[(size_t)sp * QKV_ + c]) * w[t];
    }
    return acc;
}

__global__ __launch_bounds__(256) void conv_rot(
    const unsigned short* __restrict__ qkv, const float* __restrict__ cw,
    const float* __restrict__ cb, unsigned short* __restrict__ qo,
    unsigned short* __restrict__ ko, unsigned short* __restrict__ vo)
{
    const int bs = blockIdx.x;
    const int b = bs >> 11, s = bs & 2047;
    const unsigned short* qb = qkv + (size_t)b * S_ * QKV_;

    for (int it = threadIdx.x; it < 1792; it += 256) {
        if (it < 1280) {
            const int isq = it < 1024;
            const int rel = isq ? it : it - 1024;
            const int head = rel >> 6, d = rel & 63;
            const int c1 = (isq ? head * 128 : 2048 + head * 128) + d;
            float x1 = conv_at(qb, cw, cb, s, c1);
            float x2 = conv_at(qb, cw, cb, s, c1 + 64);
            float inv = exp2f((float)d * -0.2076205059304601f);  // 10000^(-d/64)
            float ang = (float)s * inv;
            float sn, cs;
            __sincosf(ang, &sn, &cs);   // fast-math: hw v_sin/v_cos, bf16-accurate
            float r1 = x1 * cs - x2 * sn;
            float r2 = x2 * cs + x1 * sn;
            unsigned short* dst = isq
                ? qo + ((size_t)(b * H_   + head) * S_ + s) * D_
                : ko + ((size_t)(b * HKV_ + head) * S_ + s) * D_;
            dst[d]      = f2b(r1);
            dst[d + 64] = f2b(r2);
        } else {
            const int idx = it - 1280;          // 0..511
            const int g = idx >> 7, d = idx & 127;
            float vv = conv_at(qb, cw, cb, s, 2560 + idx);
            vo[((size_t)(b * HKV_ + g) * S_ + s) * D_ + d] = f2b(vv);
        }
    }
}

// ---------------------------------------------------------------------------
// Flash attention (causal, GQA rep=4). QBLK=128, 8 waves x 16 q-rows each:
// per-wave code identical to the proven 4-wave kernel (VGPR ~64), but each
// K/V LDS fragment read is amortized over 8 waves -> LDS-read traffic per
// unit work HALVED vs QBLK=64 (round-4 analysis: LDS BW was the binding
// resource, 4.4K cy/tile vs 620 MFMA). K/V double-buffered, counted
// vmcnt(4) staging (4 loads/wave/tile). LDS = 32+32+16 = 80 KB -> exactly
// 2 blocks/CU = 16 waves/CU (same occupancy as round 4).
// BALANCE (round-3 post-mortem): 512 blocks = 2/CU; CU c hosts ids {c,c+256}
// which differ only in b -> qt MUST depend on b: qt = b ? 15-qy : qy gives
// per-CU work (qy+1)+(16-qy) = 17 units, constant.
// Waves fully above the diagonal on a KV tile skip compute (uniform branch).
// T13 defer-max; T5 setprio. Reg-prefetch forbidden (round-2 spill).
// ---------------------------------------------------------------------------
__global__ __launch_bounds__(512, 4) void attn(
    const unsigned short* __restrict__ q, const unsigned short* __restrict__ k,
    const unsigned short* __restrict__ vT, unsigned short* __restrict__ ctx)
{
    __shared__ unsigned short Ks[2][64 * 128];   // 2 x 16 KB, swizzled
    __shared__ unsigned short Vs[2][128 * 64];   // 2 x 16 KB, swizzled
    __shared__ unsigned short Ps[8][16][64];     // 16 KB, per-wave, swizzled

    const int h = blockIdx.x, qy = blockIdx.y, b = blockIdx.z, g = h >> 2;
    const int qt = b ? (15 - qy) : qy;          // per-CU paired load (b differs)
    const int tid = threadIdx.x, wave = tid >> 6, lane = tid & 63;
    const int ln = lane & 15, kq = lane >> 4;

    const unsigned short* qh = q  + (size_t)(b * H_   + h) * S_ * D_;
    const unsigned short* kh = k  + (size_t)(b * HKV_ + g) * S_ * D_;
    const unsigned short* vh = vT + (size_t)(b * HKV_ + g) * D_ * S_;

    // staging geometry: 16 K-chunks + 16 V-chunks of 1 KB; 2+2 per wave
    const int rK = (lane >> 4);          // +4*chunk rows of K per chunk
    const int pK = lane & 15;            // logical granule within K row
    const int rV = (lane >> 3);          // +8*chunk rows of V per chunk
    const int pV = lane & 7;             // logical granule within V row

    const int qrow0 = qt * 128 + wave * 16;   // wave's 16 q-rows

    short8 qf[4];
    #pragma unroll
    for (int f = 0; f < 4; f++)
        qf[f] = *(const short8*)&qh[(size_t)(qrow0 + ln) * D_ + f * 32 + kq * 8];

    floatx4 o[8];
    #pragma unroll
    for (int i = 0; i < 8; i++) { o[i][0] = 0.f; o[i][1] = 0.f; o[i][2] = 0.f; o[i][3] = 0.f; }
    float mr = -INFINITY, lr = 0.f;

    const int KT = 2 * qt + 2;           // 64-row kv tiles covering the block

    // prologue: stage tile 0 into buf 0 (4 loads/wave)
    {
        #pragma unroll
        for (int c = 0; c < 2; c++) {
            const int chunk = wave * 2 + c;        // 0..15
            int r  = chunk * 4 + rK;
            int gc = pK ^ (r & 15);
            load_lds16(&kh[(size_t)r * D_ + gc * 8], &Ks[0][chunk * 512]);
            int rv = chunk * 8 + rV;
            int gv = pV ^ (rv & 7);
            load_lds16(&vh[(size_t)rv * S_ + gv * 8], &Vs[0][chunk * 512]);
        }
    }

    for (int kt = 0; kt < KT; kt++) {
        const int buf = kt & 1;
        // stage next tile into the other buffer (freed by the previous
        // iteration's trailing barrier), then counted wait for THIS tile
        if (kt + 1 < KT) {
            #pragma unroll
            for (int c = 0; c < 2; c++) {
                const int chunk = wave * 2 + c;
                int r  = chunk * 4 + rK;
                int gc = pK ^ (r & 15);
                load_lds16(&kh[(size_t)((kt + 1) * 64 + r) * D_ + gc * 8],
                           &Ks[buf ^ 1][chunk * 512]);
                int rv = chunk * 8 + rV;
                int gv = pV ^ (rv & 7);
                load_lds16(&vh[(size_t)rv * S_ + (kt + 1) * 64 + gv * 8],
                           &Vs[buf ^ 1][chunk * 512]);
            }
            waitcnt_vm<4>();    // this tile's 4 landed; next's 4 in flight
        } else {
            waitcnt_vm<0>();
        }
        __builtin_amdgcn_s_barrier();

        // waves whose q-rows are entirely above this kv tile skip compute
        // (uniform per wave: qrow0, kt both wave-uniform)
        if (kt * 64 <= qrow0 + 15) {
            // S^T = K Q^T : per lane, 16 kv values for q-row (qrow0 + ln)
            floatx4 scv[4];
            #pragma unroll
            for (int nb = 0; nb < 4; nb++) { scv[nb][0]=0.f; scv[nb][1]=0.f; scv[nb][2]=0.f; scv[nb][3]=0.f; }
            __builtin_amdgcn_s_setprio(1);
            #pragma unroll
            for (int ks = 0; ks < 4; ks++) {
                #pragma unroll
                for (int nb = 0; nb < 4; nb++) {
                    short8 kf = *(const short8*)&Ks[buf][(nb * 16 + ln) * 128 + (((ks * 4 + kq) ^ ln) * 8)];
                    scv[nb] = __builtin_amdgcn_mfma_f32_16x16x32_bf16(kf, qf[ks], scv[nb], 0, 0, 0);
                }
            }
            __builtin_amdgcn_s_setprio(0);

            // causal mask when the tile straddles this wave's diagonal
            if (kt * 64 + 63 > qrow0) {
                const int qi = qrow0 + ln;
                #pragma unroll
                for (int nb = 0; nb < 4; nb++)
                    #pragma unroll
                    for (int r = 0; r < 4; r++)
                        if (kt * 64 + nb * 16 + kq * 4 + r > qi) scv[nb][r] = -INFINITY;
            }

            // per-lane online softmax (raw-score domain; SL folds scale+log2e)
            float mx = -INFINITY;
            #pragma unroll
            for (int nb = 0; nb < 4; nb++) {
                float a0 = fmaxf(scv[nb][0], scv[nb][1]);
                float a1 = fmaxf(scv[nb][2], scv[nb][3]);
                mx = fmaxf(mx, fmaxf(a0, a1));
            }
            mx = fmaxf(mx, __shfl_xor(mx, 16));
            mx = fmaxf(mx, __shfl_xor(mx, 32));

            // T13 defer-max: skip rescale when growth bounded (P <= 2^8)
            float mt = mr, al = 1.0f;
            if (!__all(mx - mr <= DEFER_THR)) {
                mt = fmaxf(mr, mx);
                al = exp2f((mr - mt) * SL);
                mr = mt;
                float alr[4];
                #pragma unroll
                for (int r = 0; r < 4; r++) alr[r] = __shfl(al, kq * 4 + r);
                #pragma unroll
                for (int dn = 0; dn < 8; dn++)
                    #pragma unroll
                    for (int r = 0; r < 4; r++) o[dn][r] *= alr[r];
            }

            // p truncated to bf16 (denominator sums the SAME truncated values)
            float rs = 0.f;
            #pragma unroll
            for (int nb = 0; nb < 4; nb++) {
                const int gct = 2 * nb + (kq >> 1);
                const int pbase = ((gct ^ (ln & 7)) << 3) + ((kq & 1) << 2);
                #pragma unroll
                for (int rr = 0; rr < 2; rr++) {
                    unsigned int u0 = fbits(exp2f((scv[nb][2 * rr]     - mt) * SL));
                    unsigned int u1 = fbits(exp2f((scv[nb][2 * rr + 1] - mt) * SL));
                    rs += bits2f(u0 & 0xFFFF0000u) + bits2f(u1 & 0xFFFF0000u);
                    *(unsigned int*)&Ps[wave][ln][pbase + 2 * rr] =
                        (u0 >> 16) | (u1 & 0xFFFF0000u);
                }
            }
            rs += __shfl_xor(rs, 16);
            rs += __shfl_xor(rs, 32);
            lr = lr * al + rs;

            // O += P V  (Ps wave-private: lgkmcnt ordering suffices)
            short8 pa0 = *(const short8*)&Ps[wave][ln][(kq ^ (ln & 7)) << 3];
            short8 pa1 = *(const short8*)&Ps[wave][ln][((4 + kq) ^ (ln & 7)) << 3];
            __builtin_amdgcn_s_setprio(1);
            #pragma unroll
            for (int dn = 0; dn < 8; dn++) {
                short8 b0 = *(const short8*)&Vs[buf][(dn * 16 + ln) * 64 + ((kq ^ (ln & 7)) * 8)];
                o[dn] = __builtin_amdgcn_mfma_f32_16x16x32_bf16(pa0, b0, o[dn], 0, 0, 0);
                short8 b1 = *(const short8*)&Vs[buf][(dn * 16 + ln) * 64 + (((4 + kq) ^ (ln & 7)) * 8)];
                o[dn] = __builtin_amdgcn_mfma_f32_16x16x32_bf16(pa1, b1, o[dn], 0, 0, 0);
            }
            __builtin_amdgcn_s_setprio(0);
        }

        __builtin_amdgcn_s_barrier();   // all waves done reading buf before
                                        // next iteration's stage overwrites it
    }

    // epilogue: broadcast 1/l to o-layout rows, write ctx[b*S+s][h*D+d]
    float lrr[4];
    #pragma unroll
    for (int r = 0; r < 4; r++) lrr[r] = 1.0f / __shfl(lr, kq * 4 + r);
    #pragma unroll
    for (int r = 0; r < 4; r++) {
        size_t rowoff = (size_t)(b * S_ + qrow0 + kq * 4 + r) * (H_ * D_) + h * D_;
        #pragma unroll
        for (int dn = 0; dn < 8; dn++)
            ctx[rowoff + dn * 16 + ln] = f2b(o[dn][r] * lrr[r]);
    }
}

// ---------------------------------------------------------------------------
// kernel_launch — ws layout (bf16 buffers, total 88 MB):
//   WtIn [3072][2048] @0 (12MB) | WtOut [2048][2048] @12MB (8MB)
//   x16 [4096][2048] @20MB (16MB, ctx aliases after GEMM1)
//   qkv [4096][3072] @36MB (24MB) | q @60MB (16MB) | k @76MB (4MB)
//   v @80MB (4MB) | vT @84MB (4MB)
// ---------------------------------------------------------------------------
extern "C" void kernel_launch(void* const* d_in, const int* in_sizes, int n_in,
                              void* d_out, int out_size, void* d_ws, size_t ws_size,
                              hipStream_t stream)
{
    const float* x     = (const float*)d_in[0];
    const float* W_in  = (const float*)d_in[1];
    const float* b_in  = (const float*)d_in[2];
    const float* cw    = (const float*)d_in[3];
    const float* cb    = (const float*)d_in[4];
    const float* W_out = (const float*)d_in[5];
    const float* b_out = (const float*)d_in[6];
    float* out = (float*)d_out;
    char* ws = (char*)d_ws;

    const size_t MB = 1024 * 1024;
    unsigned short* WtIn  = (unsigned short*)(ws);
    unsigned short* WtOut = (unsigned short*)(ws + 12 * MB);
    unsigned short* x16   = (unsigned short*)(ws + 20 * MB);
    unsigned short* qkv   = (unsigned short*)(ws + 36 * MB);
    unsigned short* qa    = (unsigned short*)(ws + 60 * MB);
    unsigned short* ka    = (unsigned short*)(ws + 76 * MB);
    unsigned short* va    = (unsigned short*)(ws + 80 * MB);
    unsigned short* vTa   = (unsigned short*)(ws + 84 * MB);
    unsigned short* ctx   = (unsigned short*)(ws + 20 * MB);  // aliases x16

    dim3 tb(32, 8);
    hipLaunchKernelGGL(cvt_f32_bf16, dim3(8192), dim3(256), 0, stream, x, x16, 8388608);
    hipLaunchKernelGGL(transpose_f32_bf16, dim3(96, 64), tb, 0, stream, W_in,  WtIn,  2048, 3072);
    hipLaunchKernelGGL(transpose_f32_bf16, dim3(64, 64), tb, 0, stream, W_out, WtOut, 2048, 2048);
    // GEMM1: 4096x3072x2048, 256x256 tiles -> 16x12 = 192 blocks (192%8==0)
    hipLaunchKernelGGL((gemm8<256, 2, 4, 0>), dim3(192), dim3(512), 0, stream,
                       x16, WtIn, b_in, (void*)qkv, 4096, 3072, 2048);
    hipLaunchKernelGGL(conv_rot, dim3(4096), dim3(256), 0, stream, qkv, cw, cb, qa, ka, va);
    hipLaunchKernelGGL(transpose_bf16, dim3(4, 64, 8), tb, 0, stream, va, vTa, 2048, 128);
    // attn: QBLK=128, 8 waves, grid (h=16, qy=16, b=2) = 512 blocks, 2/CU
    hipLaunchKernelGGL(attn, dim3(16, 16, 2), dim3(512), 0, stream, qa, ka, vTa, ctx);
    // GEMM2: 4096x2048x2048, 256x128 tiles -> 16x16 = 256 blocks (full device)
    hipLaunchKernelGGL((gemm8<128, 4, 2, 1>), dim3(256), dim3(512), 0, stream,
                       ctx, WtOut, b_out, (void*)out, 4096, 2048, 2048);
}

// Round 6
// 359.133 us; speedup vs baseline: 1.2386x; 1.0108x over previous
//
#include <hip/hip_runtime.h>
#include <hip/hip_bf16.h>

// Problem constants
#define B_    2
#define S_    2048
#define E_    2048
#define H_    16
#define HKV_  4
#define D_    128
#define QKV_  3072   // D*(H+2*HKV)

#define LOG2E  1.4426950408889634f
#define SCALE  0.08838834764831845f   // 1/sqrt(128)
#define SL     0.127517431f           // SCALE * LOG2E (folded into q at conv_rot)
#define DEFER_THR 8.0f                // defer-max threshold in log2 domain (P <= 2^8)

typedef __attribute__((ext_vector_type(8))) short short8;   // 8 x bf16 (4 VGPRs)
typedef __attribute__((ext_vector_type(4))) float floatx4;  // MFMA 16x16 accumulator

typedef __attribute__((address_space(1))) const unsigned int gu32;
typedef __attribute__((address_space(3))) unsigned int lu32;

__device__ __forceinline__ void load_lds16(const unsigned short* g, unsigned short* l) {
    // async global->LDS, 16B/lane, dest = wave-uniform base + lane*16 (m97/m104)
    __builtin_amdgcn_global_load_lds((gu32*)g, (lu32*)l, 16, 0, 0);
}

__device__ __forceinline__ float b2f(unsigned short u) {
    union { unsigned int i; float f; } v; v.i = ((unsigned int)u) << 16; return v.f;
}
__device__ __forceinline__ unsigned short f2b(float f) {
    union { float f; unsigned int i; } v; v.f = f;
    unsigned int r = v.i + 0x7FFFu + ((v.i >> 16) & 1u);  // round-to-nearest-even
    return (unsigned short)(r >> 16);
}
__device__ __forceinline__ unsigned int fbits(float f) {
    union { float f; unsigned int i; } v; v.f = f; return v.i;
}
__device__ __forceinline__ float bits2f(unsigned int i) {
    union { unsigned int i; float f; } v; v.i = i; return v.f;
}

// counted vmcnt wait (never 0 in steady state; T4)
template<int N> __device__ __forceinline__ void waitcnt_vm() {
    static_assert(N >= 0 && N <= 8, "vmcnt out of range");
    if constexpr (N == 0) asm volatile("s_waitcnt vmcnt(0)" ::: "memory");
    else if constexpr (N == 1) asm volatile("s_waitcnt vmcnt(1)" ::: "memory");
    else if constexpr (N == 2) asm volatile("s_waitcnt vmcnt(2)" ::: "memory");
    else if constexpr (N == 3) asm volatile("s_waitcnt vmcnt(3)" ::: "memory");
    else if constexpr (N == 4) asm volatile("s_waitcnt vmcnt(4)" ::: "memory");
    else if constexpr (N == 5) asm volatile("s_waitcnt vmcnt(5)" ::: "memory");
    else if constexpr (N == 6) asm volatile("s_waitcnt vmcnt(6)" ::: "memory");
    else if constexpr (N == 7) asm volatile("s_waitcnt vmcnt(7)" ::: "memory");
    else asm volatile("s_waitcnt vmcnt(8)" ::: "memory");
}

// ---------------------------------------------------------------------------
// f32 -> bf16 convert (contiguous). 4 elems/thread.
// ---------------------------------------------------------------------------
__global__ __launch_bounds__(256) void cvt_f32_bf16(
    const float* __restrict__ src, unsigned short* __restrict__ dst, int n)
{
    int i = (blockIdx.x * 256 + threadIdx.x) * 4;
    if (i + 3 < n) {
        float4 v = *(const float4*)&src[i];
        ushort4 o;
        o.x = f2b(v.x); o.y = f2b(v.y); o.z = f2b(v.z); o.w = f2b(v.w);
        *(ushort4*)&dst[i] = o;
    }
}

// ---------------------------------------------------------------------------
// f32 -> bf16 transpose: src[R][C] f32 -> dst[C][R] bf16. block (32,8).
// ---------------------------------------------------------------------------
__global__ __launch_bounds__(256) void transpose_f32_bf16(
    const float* __restrict__ src, unsigned short* __restrict__ dst,
    int R, int C)
{
    __shared__ unsigned short tile[32][33];
    const int c0 = blockIdx.x * 32, r0 = blockIdx.y * 32;
    const int tx = threadIdx.x, ty = threadIdx.y;
    #pragma unroll
    for (int i = 0; i < 4; i++)
        tile[ty + 8 * i][tx] = f2b(src[(size_t)(r0 + ty + 8 * i) * C + c0 + tx]);
    __syncthreads();
    #pragma unroll
    for (int i = 0; i < 4; i++)
        dst[(size_t)(c0 + ty + 8 * i) * R + r0 + tx] = tile[tx][ty + 8 * i];
}

// ---------------------------------------------------------------------------
// bf16 -> bf16 batched transpose (for V): src[batch][R][C] -> dst[batch][C][R]
// ---------------------------------------------------------------------------
__global__ __launch_bounds__(256) void transpose_bf16(
    const unsigned short* __restrict__ src, unsigned short* __restrict__ dst,
    int R, int C)
{
    __shared__ unsigned short tile[32][33];
    const size_t boff = (size_t)blockIdx.z * R * C;
    src += boff; dst += boff;
    const int c0 = blockIdx.x * 32, r0 = blockIdx.y * 32;
    const int tx = threadIdx.x, ty = threadIdx.y;
    #pragma unroll
    for (int i = 0; i < 4; i++)
        tile[ty + 8 * i][tx] = src[(size_t)(r0 + ty + 8 * i) * C + c0 + tx];
    __syncthreads();
    #pragma unroll
    for (int i = 0; i < 4; i++)
        dst[(size_t)(c0 + ty + 8 * i) * R + r0 + tx] = tile[tx][ty + 8 * i];
}

// ---------------------------------------------------------------------------
// 8-phase 256-wide MFMA GEMM, m201-faithful schedule (plain HIP).
//   C[M][N] = A[M][K] @ Bt[N][K]^T + bias[N]
// BM=256 fixed; BN in {256,128}. 512 threads = 8 waves, wave grid WM x WN.
// TWO-K-TILE UNROLLED main loop -> LDS buffer pointers are COMPILE-TIME
// (round-5 theory: runtime cur^=1 forced per-tile address recompute; m201's
// unrolled loop lets LICM hoist all ds_read/stage addresses).
// Waits (derived, minimal): end-p0 vmcnt(2LA) guards B1(t) [staged t-1 p2];
// end-p1 vmcnt(LA+LB) guards A1(t) [staged t-1 p3]; end-p3 vmcnt(LA+LB)
// guards A0,B0 of t+1 [staged t p0/p1]. p2 needs nothing new. Never 0 in
// steady state; last two K-tiles peeled (tail drains once).
// ---------------------------------------------------------------------------
template<int WR, int QR, int LX>
__device__ __forceinline__ void stage_unit8(
    const unsigned short* __restrict__ G, unsigned short* ls,
    int uu, int g0, int K, int k0, int wave, int lane)
{
    #pragma unroll
    for (int l = 0; l < LX; ++l) {
        const int c    = wave * LX + l;
        const int rr   = c / (QR / 8);
        const int row0 = rr * WR + uu * QR + (c % (QR / 8)) * 8;
        const int srow = row0 + (lane >> 3);
        const int sg   = (lane & 7) ^ (lane >> 3);
        load_lds16(&G[(size_t)(g0 + srow) * K + k0 + sg * 8], &ls[row0 * 64]);
    }
}

// One K-tile: 4 phases {ds_read frags | stage unit of next tile | barrier |
// MFMA | counted wait | barrier}. ASP/BSP/SSP must be compile-time-distinct
// expressions at each expansion site (that's the point).
#define GEMM8_KTILE(ASP, BSP, SSP, K1, DO_STAGE)                                   \
  {                                                                                \
    const unsigned short* Asp_ = (ASP);                                            \
    const unsigned short* Bsp_ = (BSP);                                            \
    unsigned short* Ssp_ = (SSP);                                                  \
    const int k1_ = (K1);                                                          \
    _Pragma("unroll")                                                              \
    for (int p = 0; p < 4; ++p) {                                                  \
      const int qm = p >> 1, qn = p & 1;                                           \
      short8 af[2][FM], bg[2][FN];                                                 \
      _Pragma("unroll")                                                            \
      for (int ks = 0; ks < 2; ++ks) {                                             \
        _Pragma("unroll")                                                          \
        for (int i = 0; i < FM; ++i)                                               \
          af[ks][i] = *(const short8*)&Asp_[(wm * WMR + qm * QMR + i * 16 + ln) * 64 \
                                            + (((ks * 4 + kq) ^ (ln & 7)) * 8)];  \
        _Pragma("unroll")                                                          \
        for (int j = 0; j < FN; ++j)                                               \
          bg[ks][j] = *(const short8*)&Bsp_[(wn * WNR + qn * QNR + j * 16 + ln) * 64 \
                                            + (((ks * 4 + kq) ^ (ln & 7)) * 8)];  \
      }                                                                            \
      if (DO_STAGE) {                                                              \
        if (p == 0)      stage_unit8<WMR, QMR, LA>(A,  Ssp_,           0, m0, K, k1_, wave, lane); \
        else if (p == 1) stage_unit8<WNR, QNR, LB>(Bt, Ssp_ + BM * 64, 0, n0, K, k1_, wave, lane); \
        else if (p == 2) stage_unit8<WNR, QNR, LB>(Bt, Ssp_ + BM * 64, 1, n0, K, k1_, wave, lane); \
        else             stage_unit8<WMR, QMR, LA>(A,  Ssp_,           1, m0, K, k1_, wave, lane); \
      }                                                                            \
      __builtin_amdgcn_s_barrier();                                                \
      __builtin_amdgcn_s_setprio(1);                                               \
      _Pragma("unroll")                                                            \
      for (int ks = 0; ks < 2; ++ks)                                               \
        _Pragma("unroll")                                                          \
        for (int i = 0; i < FM; ++i)                                               \
          _Pragma("unroll")                                                        \
          for (int j = 0; j < FN; ++j)                                             \
            acc[qm * FM + i][qn * FN + j] = __builtin_amdgcn_mfma_f32_16x16x32_bf16( \
                af[ks][i], bg[ks][j], acc[qm * FM + i][qn * FN + j], 0, 0, 0);     \
      __builtin_amdgcn_s_setprio(0);                                               \
      if (p == 0)      waitcnt_vm<2 * LA>();                                       \
      else if (p == 1) waitcnt_vm<LA + LB>();                                      \
      else if (p == 3) waitcnt_vm<LA + LB>();                                      \
      __builtin_amdgcn_s_barrier();                                                \
    }                                                                              \
  }

template<int BN, int WM, int WN, int OUTF32>
__global__ __launch_bounds__(512, 2) void gemm8(
    const unsigned short* __restrict__ A, const unsigned short* __restrict__ Bt,
    const float* __restrict__ bias, void* __restrict__ Cv,
    int M, int N, int K)
{
    constexpr int BM   = 256;
    constexpr int WMR  = BM / WM, WNR = BN / WN;   // wave tile
    constexpr int QMR  = WMR / 2, QNR = WNR / 2;   // quadrant
    constexpr int FM   = QMR / 16, FN = QNR / 16;  // frags per quadrant
    constexpr int LA   = BM / 128, LB = BN / 128;  // loads per unit
    constexpr int TILE = (BM + BN) * 64;           // ushorts per buffer

    __shared__ unsigned short lds[2 * TILE];       // 128 KiB (BN=256) / 96 KiB

    const int tid  = threadIdx.x;
    const int wave = tid >> 6, lane = tid & 63;
    const int ln   = lane & 15, kq = lane >> 4;
    const int wm   = wave / WN, wn = wave % WN;

    // T1: XCD-chunked swizzle (valid: nwg % 8 == 0 for both shapes)
    const int nwg = gridDim.x;
    const int wg  = (blockIdx.x & 7) * (nwg >> 3) + (blockIdx.x >> 3);
    const int nbn = N / BN;
    const int m0  = (wg / nbn) * BM, n0 = (wg % nbn) * BN;

    floatx4 acc[2 * FM][2 * FN];
    #pragma unroll
    for (int i = 0; i < 2 * FM; ++i)
        #pragma unroll
        for (int j = 0; j < 2 * FN; ++j) {
            acc[i][j][0] = 0.f; acc[i][j][1] = 0.f;
            acc[i][j][2] = 0.f; acc[i][j][3] = 0.f;
        }

    // prologue: stage K-tile 0 into buf 0, sigma order [A0,B0,B1,A1]
    stage_unit8<WMR, QMR, LA>(A,  &lds[0],       0, m0, K, 0, wave, lane);
    stage_unit8<WNR, QNR, LB>(Bt, &lds[BM * 64], 0, n0, K, 0, wave, lane);
    stage_unit8<WNR, QNR, LB>(Bt, &lds[BM * 64], 1, n0, K, 0, wave, lane);
    stage_unit8<WMR, QMR, LA>(A,  &lds[0],       1, m0, K, 0, wave, lane);
    waitcnt_vm<LA + LB>();          // A0,B0 landed (B1,A1 guarded by p0/p1 waits)
    __builtin_amdgcn_s_barrier();

    const int NT = K >> 6;          // even, >= 4 for both call sites (32)

    // main loop: 2 K-tiles per iteration, compile-time buffers
    for (int t = 0; t < NT - 2; t += 2) {
        GEMM8_KTILE(&lds[0],    &lds[BM * 64],        &lds[TILE], (t + 1) << 6, true);
        GEMM8_KTILE(&lds[TILE], &lds[TILE + BM * 64], &lds[0],    (t + 2) << 6, true);
    }
    // peeled K-tile NT-2 (buf0): stages NT-1 into buf1 with normal waits
    GEMM8_KTILE(&lds[0], &lds[BM * 64], &lds[TILE], (NT - 1) << 6, true);
    // peeled final K-tile NT-1 (buf1): drain once, compute-only
    asm volatile("s_waitcnt vmcnt(0)" ::: "memory");
    __builtin_amdgcn_s_barrier();
    GEMM8_KTILE(&lds[TILE], &lds[TILE + BM * 64], &lds[0], 0, false);

    // epilogue: bias add + store (C/D map: col=ln, row=kq*4+r)
    #pragma unroll
    for (int nj = 0; nj < 2 * FN; ++nj) {
        const int col = n0 + wn * WNR + nj * 16 + ln;
        const float bv = bias[col];
        #pragma unroll
        for (int mi = 0; mi < 2 * FM; ++mi) {
            const int rowb = m0 + wm * WMR + mi * 16 + kq * 4;
            #pragma unroll
            for (int r = 0; r < 4; ++r) {
                const float val = acc[mi][nj][r] + bv;
                if (OUTF32) ((float*)Cv)[(size_t)(rowb + r) * N + col] = val;
                else ((unsigned short*)Cv)[(size_t)(rowb + r) * N + col] = f2b(val);
            }
        }
    }
}

// ---------------------------------------------------------------------------
// Fused depthwise causal conv (DCONV=4) + RoPE + q/k/v split-scatter.
// q outputs are pre-multiplied by SL (softmax scale folded into the QK GEMM
// operand) so attn's exp2 args need no per-element multiply.
// ---------------------------------------------------------------------------
__device__ __forceinline__ float conv_at(
    const unsigned short* __restrict__ qb, const float* __restrict__ cw,
    const float* __restrict__ cb, int s, int c)
{
    float acc = cb[c];
    const float* w = cw + c * 4;
    #pragma unroll
    for (int t = 0; t < 4; t++) {
        int sp = s - 3 + t;
        if (sp >= 0) acc += b2f(qb[(size_t)sp * QKV_ + c]) * w[t];
    }
    return acc;
}

__global__ __launch_bounds__(256) void conv_rot(
    const unsigned short* __restrict__ qkv, const float* __restrict__ cw,
    const float* __restrict__ cb, unsigned short* __restrict__ qo,
    unsigned short* __restrict__ ko, unsigned short* __restrict__ vo)
{
    const int bs = blockIdx.x;
    const int b = bs >> 11, s = bs & 2047;
    const unsigned short* qb = qkv + (size_t)b * S_ * QKV_;

    for (int it = threadIdx.x; it < 1792; it += 256) {
        if (it < 1280) {
            const int isq = it < 1024;
            const int rel = isq ? it : it - 1024;
            const int head = rel >> 6, d = rel & 63;
            const int c1 = (isq ? head * 128 : 2048 + head * 128) + d;
            float x1 = conv_at(qb, cw, cb, s, c1);
            float x2 = conv_at(qb, cw, cb, s, c1 + 64);
            float inv = exp2f((float)d * -0.2076205059304601f);  // 10000^(-d/64)
            float ang = (float)s * inv;
            float sn, cs;
            __sincosf(ang, &sn, &cs);   // fast-math: hw v_sin/v_cos, bf16-accurate
            const float sc = isq ? SL : 1.0f;   // fold softmax scale into q
            float r1 = (x1 * cs - x2 * sn) * sc;
            float r2 = (x2 * cs + x1 * sn) * sc;
            unsigned short* dst = isq
                ? qo + ((size_t)(b * H_   + head) * S_ + s) * D_
                : ko + ((size_t)(b * HKV_ + head) * S_ + s) * D_;
            dst[d]      = f2b(r1);
            dst[d + 64] = f2b(r2);
        } else {
            const int idx = it - 1280;          // 0..511
            const int g = idx >> 7, d = idx & 127;
            float vv = conv_at(qb, cw, cb, s, 2560 + idx);
            vo[((size_t)(b * HKV_ + g) * S_ + s) * D_ + d] = f2b(vv);
        }
    }
}

// ---------------------------------------------------------------------------
// Flash attention (causal, GQA rep=4). QBLK=128, 8 waves x 16 q-rows each:
// K/V LDS reads amortized over 8 waves. K/V double-buffered, counted
// vmcnt(4) staging. LDS 80KB -> 2 blocks/CU = 16 waves/CU. qt = b?15-qy:qy
// balances per-CU work (blocks {c,c+256} differ only in b). Scores arrive
// pre-scaled by SL (q folded) -> exp2 args need no multiply. T13 defer-max
// (THR=8 in log2 domain); T5 setprio. Reg-prefetch forbidden (round-2 spill).
// ---------------------------------------------------------------------------
__global__ __launch_bounds__(512, 4) void attn(
    const unsigned short* __restrict__ q, const unsigned short* __restrict__ k,
    const unsigned short* __restrict__ vT, unsigned short* __restrict__ ctx)
{
    __shared__ unsigned short Ks[2][64 * 128];   // 2 x 16 KB, swizzled
    __shared__ unsigned short Vs[2][128 * 64];   // 2 x 16 KB, swizzled
    __shared__ unsigned short Ps[8][16][64];     // 16 KB, per-wave, swizzled

    const int h = blockIdx.x, qy = blockIdx.y, b = blockIdx.z, g = h >> 2;
    const int qt = b ? (15 - qy) : qy;          // per-CU paired load (b differs)
    const int tid = threadIdx.x, wave = tid >> 6, lane = tid & 63;
    const int ln = lane & 15, kq = lane >> 4;

    const unsigned short* qh = q  + (size_t)(b * H_   + h) * S_ * D_;
    const unsigned short* kh = k  + (size_t)(b * HKV_ + g) * S_ * D_;
    const unsigned short* vh = vT + (size_t)(b * HKV_ + g) * D_ * S_;

    // staging geometry: 16 K-chunks + 16 V-chunks of 1 KB; 2+2 per wave
    const int rK = (lane >> 4);          // +4*chunk rows of K per chunk
    const int pK = lane & 15;            // logical granule within K row
    const int rV = (lane >> 3);          // +8*chunk rows of V per chunk
    const int pV = lane & 7;             // logical granule within V row

    const int qrow0 = qt * 128 + wave * 16;   // wave's 16 q-rows

    short8 qf[4];
    #pragma unroll
    for (int f = 0; f < 4; f++)
        qf[f] = *(const short8*)&qh[(size_t)(qrow0 + ln) * D_ + f * 32 + kq * 8];

    floatx4 o[8];
    #pragma unroll
    for (int i = 0; i < 8; i++) { o[i][0] = 0.f; o[i][1] = 0.f; o[i][2] = 0.f; o[i][3] = 0.f; }
    float mr = -INFINITY, lr = 0.f;

    const int KT = 2 * qt + 2;           // 64-row kv tiles covering the block

    // prologue: stage tile 0 into buf 0 (4 loads/wave)
    {
        #pragma unroll
        for (int c = 0; c < 2; c++) {
            const int chunk = wave * 2 + c;        // 0..15
            int r  = chunk * 4 + rK;
            int gc = pK ^ (r & 15);
            load_lds16(&kh[(size_t)r * D_ + gc * 8], &Ks[0][chunk * 512]);
            int rv = chunk * 8 + rV;
            int gv = pV ^ (rv & 7);
            load_lds16(&vh[(size_t)rv * S_ + gv * 8], &Vs[0][chunk * 512]);
        }
    }

    for (int kt = 0; kt < KT; kt++) {
        const int buf = kt & 1;
        // stage next tile into the other buffer (freed by the previous
        // iteration's trailing barrier), then counted wait for THIS tile
        if (kt + 1 < KT) {
            #pragma unroll
            for (int c = 0; c < 2; c++) {
                const int chunk = wave * 2 + c;
                int r  = chunk * 4 + rK;
                int gc = pK ^ (r & 15);
                load_lds16(&kh[(size_t)((kt + 1) * 64 + r) * D_ + gc * 8],
                           &Ks[buf ^ 1][chunk * 512]);
                int rv = chunk * 8 + rV;
                int gv = pV ^ (rv & 7);
                load_lds16(&vh[(size_t)rv * S_ + (kt + 1) * 64 + gv * 8],
                           &Vs[buf ^ 1][chunk * 512]);
            }
            waitcnt_vm<4>();    // this tile's 4 landed; next's 4 in flight
        } else {
            waitcnt_vm<0>();
        }
        __builtin_amdgcn_s_barrier();

        // waves whose q-rows are entirely above this kv tile skip compute
        // (uniform per wave: qrow0, kt both wave-uniform)
        if (kt * 64 <= qrow0 + 15) {
            // S^T = K Q^T : per lane, 16 kv values for q-row (qrow0 + ln)
            floatx4 scv[4];
            #pragma unroll
            for (int nb = 0; nb < 4; nb++) { scv[nb][0]=0.f; scv[nb][1]=0.f; scv[nb][2]=0.f; scv[nb][3]=0.f; }
            __builtin_amdgcn_s_setprio(1);
            #pragma unroll
            for (int ks = 0; ks < 4; ks++) {
                #pragma unroll
                for (int nb = 0; nb < 4; nb++) {
                    short8 kf = *(const short8*)&Ks[buf][(nb * 16 + ln) * 128 + (((ks * 4 + kq) ^ ln) * 8)];
                    scv[nb] = __builtin_amdgcn_mfma_f32_16x16x32_bf16(kf, qf[ks], scv[nb], 0, 0, 0);
                }
            }
            __builtin_amdgcn_s_setprio(0);

            // causal mask when the tile straddles this wave's diagonal
            if (kt * 64 + 63 > qrow0) {
                const int qi = qrow0 + ln;
                #pragma unroll
                for (int nb = 0; nb < 4; nb++)
                    #pragma unroll
                    for (int r = 0; r < 4; r++)
                        if (kt * 64 + nb * 16 + kq * 4 + r > qi) scv[nb][r] = -INFINITY;
            }

            // per-lane online softmax (scores already in log2 domain)
            float mx = -INFINITY;
            #pragma unroll
            for (int nb = 0; nb < 4; nb++) {
                float a0 = fmaxf(scv[nb][0], scv[nb][1]);
                float a1 = fmaxf(scv[nb][2], scv[nb][3]);
                mx = fmaxf(mx, fmaxf(a0, a1));
            }
            mx = fmaxf(mx, __shfl_xor(mx, 16));
            mx = fmaxf(mx, __shfl_xor(mx, 32));

            // T13 defer-max: skip rescale when growth bounded (P <= 2^8)
            float mt = mr, al = 1.0f;
            if (!__all(mx - mr <= DEFER_THR)) {
                mt = fmaxf(mr, mx);
                al = exp2f(mr - mt);
                mr = mt;
                float alr[4];
                #pragma unroll
                for (int r = 0; r < 4; r++) alr[r] = __shfl(al, kq * 4 + r);
                #pragma unroll
                for (int dn = 0; dn < 8; dn++)
                    #pragma unroll
                    for (int r = 0; r < 4; r++) o[dn][r] *= alr[r];
            }

            // p truncated to bf16 (denominator sums the SAME truncated values)
            float rs = 0.f;
            #pragma unroll
            for (int nb = 0; nb < 4; nb++) {
                const int gct = 2 * nb + (kq >> 1);
                const int pbase = ((gct ^ (ln & 7)) << 3) + ((kq & 1) << 2);
                #pragma unroll
                for (int rr = 0; rr < 2; rr++) {
                    unsigned int u0 = fbits(exp2f(scv[nb][2 * rr]     - mt));
                    unsigned int u1 = fbits(exp2f(scv[nb][2 * rr + 1] - mt));
                    rs += bits2f(u0 & 0xFFFF0000u) + bits2f(u1 & 0xFFFF0000u);
                    *(unsigned int*)&Ps[wave][ln][pbase + 2 * rr] =
                        (u0 >> 16) | (u1 & 0xFFFF0000u);
                }
            }
            rs += __shfl_xor(rs, 16);
            rs += __shfl_xor(rs, 32);
            lr = lr * al + rs;

            // O += P V  (Ps wave-private: lgkmcnt ordering suffices)
            short8 pa0 = *(const short8*)&Ps[wave][ln][(kq ^ (ln & 7)) << 3];
            short8 pa1 = *(const short8*)&Ps[wave][ln][((4 + kq) ^ (ln & 7)) << 3];
            __builtin_amdgcn_s_setprio(1);
            #pragma unroll
            for (int dn = 0; dn < 8; dn++) {
                short8 b0 = *(const short8*)&Vs[buf][(dn * 16 + ln) * 64 + ((kq ^ (ln & 7)) * 8)];
                o[dn] = __builtin_amdgcn_mfma_f32_16x16x32_bf16(pa0, b0, o[dn], 0, 0, 0);
                short8 b1 = *(const short8*)&Vs[buf][(dn * 16 + ln) * 64 + (((4 + kq) ^ (ln & 7)) * 8)];
                o[dn] = __builtin_amdgcn_mfma_f32_16x16x32_bf16(pa1, b1, o[dn], 0, 0, 0);
            }
            __builtin_amdgcn_s_setprio(0);
        }

        __builtin_amdgcn_s_barrier();   // all waves done reading buf before
                                        // next iteration's stage overwrites it
    }

    // epilogue: broadcast 1/l to o-layout rows, write ctx[b*S+s][h*D+d]
    float lrr[4];
    #pragma unroll
    for (int r = 0; r < 4; r++) lrr[r] = 1.0f / __shfl(lr, kq * 4 + r);
    #pragma unroll
    for (int r = 0; r < 4; r++) {
        size_t rowoff = (size_t)(b * S_ + qrow0 + kq * 4 + r) * (H_ * D_) + h * D_;
        #pragma unroll
        for (int dn = 0; dn < 8; dn++)
            ctx[rowoff + dn * 16 + ln] = f2b(o[dn][r] * lrr[r]);
    }
}

// ---------------------------------------------------------------------------
// kernel_launch — ws layout (bf16 buffers, total 88 MB):
//   WtIn [3072][2048] @0 (12MB) | WtOut [2048][2048] @12MB (8MB)
//   x16 [4096][2048] @20MB (16MB, ctx aliases after GEMM1)
//   qkv [4096][3072] @36MB (24MB) | q @60MB (16MB) | k @76MB (4MB)
//   v @80MB (4MB) | vT @84MB (4MB)
// ---------------------------------------------------------------------------
extern "C" void kernel_launch(void* const* d_in, const int* in_sizes, int n_in,
                              void* d_out, int out_size, void* d_ws, size_t ws_size,
                              hipStream_t stream)
{
    const float* x     = (const float*)d_in[0];
    const float* W_in  = (const float*)d_in[1];
    const float* b_in  = (const float*)d_in[2];
    const float* cw    = (const float*)d_in[3];
    const float* cb    = (const float*)d_in[4];
    const float* W_out = (const float*)d_in[5];
    const float* b_out = (const float*)d_in[6];
    float* out = (float*)d_out;
    char* ws = (char*)d_ws;

    const size_t MB = 1024 * 1024;
    unsigned short* WtIn  = (unsigned short*)(ws);
    unsigned short* WtOut = (unsigned short*)(ws + 12 * MB);
    unsigned short* x16   = (unsigned short*)(ws + 20 * MB);
    unsigned short* qkv   = (unsigned short*)(ws + 36 * MB);
    unsigned short* qa    = (unsigned short*)(ws + 60 * MB);
    unsigned short* ka    = (unsigned short*)(ws + 76 * MB);
    unsigned short* va    = (unsigned short*)(ws + 80 * MB);
    unsigned short* vTa   = (unsigned short*)(ws + 84 * MB);
    unsigned short* ctx   = (unsigned short*)(ws + 20 * MB);  // aliases x16

    dim3 tb(32, 8);
    hipLaunchKernelGGL(cvt_f32_bf16, dim3(8192), dim3(256), 0, stream, x, x16, 8388608);
    hipLaunchKernelGGL(transpose_f32_bf16, dim3(96, 64), tb, 0, stream, W_in,  WtIn,  2048, 3072);
    hipLaunchKernelGGL(transpose_f32_bf16, dim3(64, 64), tb, 0, stream, W_out, WtOut, 2048, 2048);
    // GEMM1: 4096x3072x2048, 256x256 tiles -> 16x12 = 192 blocks (192%8==0)
    hipLaunchKernelGGL((gemm8<256, 2, 4, 0>), dim3(192), dim3(512), 0, stream,
                       x16, WtIn, b_in, (void*)qkv, 4096, 3072, 2048);
    hipLaunchKernelGGL(conv_rot, dim3(4096), dim3(256), 0, stream, qkv, cw, cb, qa, ka, va);
    hipLaunchKernelGGL(transpose_bf16, dim3(4, 64, 8), tb, 0, stream, va, vTa, 2048, 128);
    // attn: QBLK=128, 8 waves, grid (h=16, qy=16, b=2) = 512 blocks, 2/CU
    hipLaunchKernelGGL(attn, dim3(16, 16, 2), dim3(512), 0, stream, qa, ka, vTa, ctx);
    // GEMM2: 4096x2048x2048, 256x128 tiles -> 16x16 = 256 blocks (full device)
    hipLaunchKernelGGL((gemm8<128, 4, 2, 1>), dim3(256), dim3(512), 0, stream,
                       ctx, WtOut, b_out, (void*)out, 4096, 2048, 2048);
}

// Round 7
// 346.073 us; speedup vs baseline: 1.2854x; 1.0377x over previous
//
#include <hip/hip_runtime.h>
#include <hip/hip_bf16.h>

// Problem constants
#define B_    2
#define S_    2048
#define E_    2048
#define H_    16
#define HKV_  4
#define D_    128
#define QKV_  3072   // D*(H+2*HKV)

#define LOG2E  1.4426950408889634f
#define SCALE  0.08838834764831845f   // 1/sqrt(128)
#define SL     0.127517431f           // SCALE * LOG2E (folded into q at conv_rot)
#define DEFER_THR 8.0f                // defer-max threshold in log2 domain (P <= 2^8)

typedef __attribute__((ext_vector_type(8))) short short8;   // 8 x bf16 (4 VGPRs)
typedef __attribute__((ext_vector_type(4))) float floatx4;  // MFMA 16x16 accumulator

typedef __attribute__((address_space(1))) const unsigned int gu32;
typedef __attribute__((address_space(3))) unsigned int lu32;

__device__ __forceinline__ void load_lds16(const unsigned short* g, unsigned short* l) {
    // async global->LDS, 16B/lane, dest = wave-uniform base + lane*16 (m97/m104)
    __builtin_amdgcn_global_load_lds((gu32*)g, (lu32*)l, 16, 0, 0);
}

__device__ __forceinline__ float b2f(unsigned short u) {
    union { unsigned int i; float f; } v; v.i = ((unsigned int)u) << 16; return v.f;
}
__device__ __forceinline__ unsigned short f2b(float f) {
    union { float f; unsigned int i; } v; v.f = f;
    unsigned int r = v.i + 0x7FFFu + ((v.i >> 16) & 1u);  // round-to-nearest-even
    return (unsigned short)(r >> 16);
}
__device__ __forceinline__ unsigned int fbits(float f) {
    union { float f; unsigned int i; } v; v.f = f; return v.i;
}
__device__ __forceinline__ float bits2f(unsigned int i) {
    union { unsigned int i; float f; } v; v.i = i; return v.f;
}

// counted vmcnt wait (never 0 in steady state; T4)
template<int N> __device__ __forceinline__ void waitcnt_vm() {
    static_assert(N >= 0 && N <= 8, "vmcnt out of range");
    if constexpr (N == 0) asm volatile("s_waitcnt vmcnt(0)" ::: "memory");
    else if constexpr (N == 1) asm volatile("s_waitcnt vmcnt(1)" ::: "memory");
    else if constexpr (N == 2) asm volatile("s_waitcnt vmcnt(2)" ::: "memory");
    else if constexpr (N == 3) asm volatile("s_waitcnt vmcnt(3)" ::: "memory");
    else if constexpr (N == 4) asm volatile("s_waitcnt vmcnt(4)" ::: "memory");
    else if constexpr (N == 5) asm volatile("s_waitcnt vmcnt(5)" ::: "memory");
    else if constexpr (N == 6) asm volatile("s_waitcnt vmcnt(6)" ::: "memory");
    else if constexpr (N == 7) asm volatile("s_waitcnt vmcnt(7)" ::: "memory");
    else asm volatile("s_waitcnt vmcnt(8)" ::: "memory");
}

// ---------------------------------------------------------------------------
// f32 -> bf16 convert (contiguous). 4 elems/thread.
// ---------------------------------------------------------------------------
__global__ __launch_bounds__(256) void cvt_f32_bf16(
    const float* __restrict__ src, unsigned short* __restrict__ dst, int n)
{
    int i = (blockIdx.x * 256 + threadIdx.x) * 4;
    if (i + 3 < n) {
        float4 v = *(const float4*)&src[i];
        ushort4 o;
        o.x = f2b(v.x); o.y = f2b(v.y); o.z = f2b(v.z); o.w = f2b(v.w);
        *(ushort4*)&dst[i] = o;
    }
}

// ---------------------------------------------------------------------------
// f32 -> bf16 transpose: src[R][C] f32 -> dst[C][R] bf16. block (32,8).
// ---------------------------------------------------------------------------
__global__ __launch_bounds__(256) void transpose_f32_bf16(
    const float* __restrict__ src, unsigned short* __restrict__ dst,
    int R, int C)
{
    __shared__ unsigned short tile[32][33];
    const int c0 = blockIdx.x * 32, r0 = blockIdx.y * 32;
    const int tx = threadIdx.x, ty = threadIdx.y;
    #pragma unroll
    for (int i = 0; i < 4; i++)
        tile[ty + 8 * i][tx] = f2b(src[(size_t)(r0 + ty + 8 * i) * C + c0 + tx]);
    __syncthreads();
    #pragma unroll
    for (int i = 0; i < 4; i++)
        dst[(size_t)(c0 + ty + 8 * i) * R + r0 + tx] = tile[tx][ty + 8 * i];
}

// ---------------------------------------------------------------------------
// bf16 -> bf16 batched transpose (for V): src[batch][R][C] -> dst[batch][C][R]
// ---------------------------------------------------------------------------
__global__ __launch_bounds__(256) void transpose_bf16(
    const unsigned short* __restrict__ src, unsigned short* __restrict__ dst,
    int R, int C)
{
    __shared__ unsigned short tile[32][33];
    const size_t boff = (size_t)blockIdx.z * R * C;
    src += boff; dst += boff;
    const int c0 = blockIdx.x * 32, r0 = blockIdx.y * 32;
    const int tx = threadIdx.x, ty = threadIdx.y;
    #pragma unroll
    for (int i = 0; i < 4; i++)
        tile[ty + 8 * i][tx] = src[(size_t)(r0 + ty + 8 * i) * C + c0 + tx];
    __syncthreads();
    #pragma unroll
    for (int i = 0; i < 4; i++)
        dst[(size_t)(c0 + ty + 8 * i) * R + r0 + tx] = tile[tx][ty + 8 * i];
}

// ---------------------------------------------------------------------------
// Shared GEMM staging helpers.
// stage_unit8: quadrant-band unit (rows rr*WR + uu*QR + [0,QR) for all rr),
// LX loads/thread. stage_b64: one linear 64-row slab (1 load/thread).
// Both: linear LDS dest + inverse-swizzled global source (rule #21).
// ---------------------------------------------------------------------------
template<int WR, int QR, int LX>
__device__ __forceinline__ void stage_unit8(
    const unsigned short* __restrict__ G, unsigned short* ls,
    int uu, int g0, int K, int k0, int wave, int lane)
{
    #pragma unroll
    for (int l = 0; l < LX; ++l) {
        const int c    = wave * LX + l;
        const int rr   = c / (QR / 8);
        const int row0 = rr * WR + uu * QR + (c % (QR / 8)) * 8;
        const int srow = row0 + (lane >> 3);
        const int sg   = (lane & 7) ^ (lane >> 3);
        load_lds16(&G[(size_t)(g0 + srow) * K + k0 + sg * 8], &ls[row0 * 64]);
    }
}

__device__ __forceinline__ void stage_b64(
    const unsigned short* __restrict__ G, unsigned short* ls,
    int u, int g0, int K, int k0, int wave, int lane)
{
    const int row0 = u * 64 + wave * 8;
    const int srow = row0 + (lane >> 3);
    const int sg   = (lane & 7) ^ (lane >> 3);
    load_lds16(&G[(size_t)(g0 + srow) * K + k0 + sg * 8], &ls[row0 * 64]);
}

// ---------------------------------------------------------------------------
// GEMM1: 256x192 tile -> grid 16x16 = 256 blocks = EXACTLY 1/CU (the 256x256
// tiling gave only 192 blocks -> 64 CUs idle, round-6 counters).
// 8 waves (WM=4 x WN=2), wave tile 64x96, quadrant 32x48 (FM=2, FN=3).
// LDS (256+192)*64*2*2 = 114688 B. Pipe balance per wave per K-tile:
// LDS (64+96)*128B ~ 1880cy vs MFMA 384*4.85 ~ 1860cy (better than 256^2).
// Stage schedule (tile t stages t+1): p0/p1/p2 -> B slab 0/1/2 (1 load each),
// p3 -> A unit 0 + unit 1 (2+2 loads). Every qn-phase reads ALL B slabs, so
// waits collapse to TWO per K-tile: end-p1 vmcnt(2) [A-qm1(t): last 2 of the
// 4 A-loads issued at t-1 p3]; end-p3 vmcnt(2) [B+A-qm0 of t+1 in, A-qm1
// still in flight]. Verified against issue order for prologue/steady/tail.
// ---------------------------------------------------------------------------
#define G192_KTILE(ASP, BSP, SA, SB, K1, DO_STAGE)                                 \
  {                                                                                \
    const unsigned short* Asp_ = (ASP);                                            \
    const unsigned short* Bsp_ = (BSP);                                            \
    unsigned short* SA_ = (SA);                                                    \
    unsigned short* SB_ = (SB);                                                    \
    const int k1_ = (K1);                                                          \
    _Pragma("unroll")                                                              \
    for (int p = 0; p < 4; ++p) {                                                  \
      const int qm = p >> 1, qn = p & 1;                                           \
      short8 af[2][2], bg[2][3];                                                   \
      _Pragma("unroll")                                                            \
      for (int ks = 0; ks < 2; ++ks) {                                             \
        _Pragma("unroll")                                                          \
        for (int i = 0; i < 2; ++i)                                                \
          af[ks][i] = *(const short8*)&Asp_[(wm * 64 + qm * 32 + i * 16 + ln) * 64 \
                                            + (((ks * 4 + kq) ^ (ln & 7)) * 8)];  \
        _Pragma("unroll")                                                          \
        for (int j = 0; j < 3; ++j)                                               \
          bg[ks][j] = *(const short8*)&Bsp_[(wn * 96 + qn * 48 + j * 16 + ln) * 64 \
                                            + (((ks * 4 + kq) ^ (ln & 7)) * 8)];  \
      }                                                                            \
      if (DO_STAGE) {                                                              \
        if (p < 3) stage_b64(Bt, SB_, p, n0, K, k1_, wave, lane);                  \
        else {                                                                     \
          stage_unit8<64, 32, 2>(A, SA_, 0, m0, K, k1_, wave, lane);               \
          stage_unit8<64, 32, 2>(A, SA_, 1, m0, K, k1_, wave, lane);               \
        }                                                                          \
      }                                                                            \
      __builtin_amdgcn_s_barrier();                                                \
      __builtin_amdgcn_s_setprio(1);                                               \
      _Pragma("unroll")                                                            \
      for (int ks = 0; ks < 2; ++ks)                                               \
        _Pragma("unroll")                                                          \
        for (int i = 0; i < 2; ++i)                                                \
          _Pragma("unroll")                                                        \
          for (int j = 0; j < 3; ++j)                                              \
            acc[qm * 2 + i][qn * 3 + j] = __builtin_amdgcn_mfma_f32_16x16x32_bf16( \
                af[ks][i], bg[ks][j], acc[qm * 2 + i][qn * 3 + j], 0, 0, 0);       \
      __builtin_amdgcn_s_setprio(0);                                               \
      if (DO_STAGE) {                                                              \
        if (p == 1)      waitcnt_vm<2>();                                          \
        else if (p == 3) waitcnt_vm<2>();                                          \
      }                                                                            \
      __builtin_amdgcn_s_barrier();                                                \
    }                                                                              \
  }

__global__ __launch_bounds__(512, 2) void gemm1_192(
    const unsigned short* __restrict__ A, const unsigned short* __restrict__ Bt,
    const float* __restrict__ bias, unsigned short* __restrict__ C,
    int M, int N, int K)
{
    constexpr int BM = 256, BN = 192;
    constexpr int TILE = (BM + BN) * 64;            // 28672 ushorts / buffer

    __shared__ unsigned short lds[2 * TILE];        // 114688 B

    const int tid  = threadIdx.x;
    const int wave = tid >> 6, lane = tid & 63;
    const int ln   = lane & 15, kq = lane >> 4;
    const int wm   = wave >> 1, wn = wave & 1;      // WM=4 x WN=2

    // T1: XCD-chunked swizzle (nwg = 256, %8 == 0)
    const int nwg = gridDim.x;
    const int wg  = (blockIdx.x & 7) * (nwg >> 3) + (blockIdx.x >> 3);
    const int nbn = N / BN;                         // 16
    const int m0  = (wg / nbn) * BM, n0 = (wg % nbn) * BN;

    floatx4 acc[4][6];
    #pragma unroll
    for (int i = 0; i < 4; ++i)
        #pragma unroll
        for (int j = 0; j < 6; ++j) {
            acc[i][j][0] = 0.f; acc[i][j][1] = 0.f;
            acc[i][j][2] = 0.f; acc[i][j][3] = 0.f;
        }

    // prologue: stage K-tile 0 into buf 0, order [B0,B1,B2,A0,A1]
    stage_b64(Bt, &lds[BM * 64], 0, n0, K, 0, wave, lane);
    stage_b64(Bt, &lds[BM * 64], 1, n0, K, 0, wave, lane);
    stage_b64(Bt, &lds[BM * 64], 2, n0, K, 0, wave, lane);
    stage_unit8<64, 32, 2>(A, &lds[0], 0, m0, K, 0, wave, lane);
    stage_unit8<64, 32, 2>(A, &lds[0], 1, m0, K, 0, wave, lane);
    waitcnt_vm<2>();                 // B all + A-qm0 in; A-qm1 in flight
    __builtin_amdgcn_s_barrier();

    const int NT = K >> 6;           // 32

    // main loop: 2 K-tiles per iteration, compile-time buffers
    for (int t = 0; t < NT - 2; t += 2) {
        G192_KTILE(&lds[0],    &lds[BM * 64],        &lds[TILE], &lds[TILE + BM * 64], (t + 1) << 6, true);
        G192_KTILE(&lds[TILE], &lds[TILE + BM * 64], &lds[0],    &lds[BM * 64],        (t + 2) << 6, true);
    }
    // peeled K-tile NT-2 (buf0): stages NT-1 into buf1 with normal waits
    G192_KTILE(&lds[0], &lds[BM * 64], &lds[TILE], &lds[TILE + BM * 64], (NT - 1) << 6, true);
    // peeled final K-tile NT-1 (buf1): drain once, compute-only
    asm volatile("s_waitcnt vmcnt(0)" ::: "memory");
    __builtin_amdgcn_s_barrier();
    G192_KTILE(&lds[TILE], &lds[TILE + BM * 64], &lds[0], &lds[BM * 64], 0, false);

    // epilogue: bias add + bf16 store (C/D map: col=ln, row=kq*4+r)
    #pragma unroll
    for (int nj = 0; nj < 6; ++nj) {
        const int col = n0 + wn * 96 + nj * 16 + ln;
        const float bv = bias[col];
        #pragma unroll
        for (int mi = 0; mi < 4; ++mi) {
            const int rowb = m0 + wm * 64 + mi * 16 + kq * 4;
            #pragma unroll
            for (int r = 0; r < 4; ++r)
                C[(size_t)(rowb + r) * N + col] = f2b(acc[mi][nj][r] + bv);
        }
    }
}

// ---------------------------------------------------------------------------
// GEMM2 template (m201 schedule, round-6 proven): BM=256, BN=128, 256 blocks.
// ---------------------------------------------------------------------------
#define GEMM8_KTILE(ASP, BSP, SSP, K1, DO_STAGE)                                   \
  {                                                                                \
    const unsigned short* Asp_ = (ASP);                                            \
    const unsigned short* Bsp_ = (BSP);                                            \
    unsigned short* Ssp_ = (SSP);                                                  \
    const int k1_ = (K1);                                                          \
    _Pragma("unroll")                                                              \
    for (int p = 0; p < 4; ++p) {                                                  \
      const int qm = p >> 1, qn = p & 1;                                           \
      short8 af[2][FM], bg[2][FN];                                                 \
      _Pragma("unroll")                                                            \
      for (int ks = 0; ks < 2; ++ks) {                                             \
        _Pragma("unroll")                                                          \
        for (int i = 0; i < FM; ++i)                                               \
          af[ks][i] = *(const short8*)&Asp_[(wm * WMR + qm * QMR + i * 16 + ln) * 64 \
                                            + (((ks * 4 + kq) ^ (ln & 7)) * 8)];  \
        _Pragma("unroll")                                                          \
        for (int j = 0; j < FN; ++j)                                               \
          bg[ks][j] = *(const short8*)&Bsp_[(wn * WNR + qn * QNR + j * 16 + ln) * 64 \
                                            + (((ks * 4 + kq) ^ (ln & 7)) * 8)];  \
      }                                                                            \
      if (DO_STAGE) {                                                              \
        if (p == 0)      stage_unit8<WMR, QMR, LA>(A,  Ssp_,           0, m0, K, k1_, wave, lane); \
        else if (p == 1) stage_unit8<WNR, QNR, LB>(Bt, Ssp_ + BM * 64, 0, n0, K, k1_, wave, lane); \
        else if (p == 2) stage_unit8<WNR, QNR, LB>(Bt, Ssp_ + BM * 64, 1, n0, K, k1_, wave, lane); \
        else             stage_unit8<WMR, QMR, LA>(A,  Ssp_,           1, m0, K, k1_, wave, lane); \
      }                                                                            \
      __builtin_amdgcn_s_barrier();                                                \
      __builtin_amdgcn_s_setprio(1);                                               \
      _Pragma("unroll")                                                            \
      for (int ks = 0; ks < 2; ++ks)                                               \
        _Pragma("unroll")                                                          \
        for (int i = 0; i < FM; ++i)                                               \
          _Pragma("unroll")                                                        \
          for (int j = 0; j < FN; ++j)                                             \
            acc[qm * FM + i][qn * FN + j] = __builtin_amdgcn_mfma_f32_16x16x32_bf16( \
                af[ks][i], bg[ks][j], acc[qm * FM + i][qn * FN + j], 0, 0, 0);     \
      __builtin_amdgcn_s_setprio(0);                                               \
      if (p == 0)      waitcnt_vm<2 * LA>();                                       \
      else if (p == 1) waitcnt_vm<LA + LB>();                                      \
      else if (p == 3) waitcnt_vm<LA + LB>();                                      \
      __builtin_amdgcn_s_barrier();                                                \
    }                                                                              \
  }

template<int BN, int WM, int WN, int OUTF32>
__global__ __launch_bounds__(512, 2) void gemm8(
    const unsigned short* __restrict__ A, const unsigned short* __restrict__ Bt,
    const float* __restrict__ bias, void* __restrict__ Cv,
    int M, int N, int K)
{
    constexpr int BM   = 256;
    constexpr int WMR  = BM / WM, WNR = BN / WN;   // wave tile
    constexpr int QMR  = WMR / 2, QNR = WNR / 2;   // quadrant
    constexpr int FM   = QMR / 16, FN = QNR / 16;  // frags per quadrant
    constexpr int LA   = BM / 128, LB = BN / 128;  // loads per unit
    constexpr int TILE = (BM + BN) * 64;           // ushorts per buffer

    __shared__ unsigned short lds[2 * TILE];

    const int tid  = threadIdx.x;
    const int wave = tid >> 6, lane = tid & 63;
    const int ln   = lane & 15, kq = lane >> 4;
    const int wm   = wave / WN, wn = wave % WN;

    const int nwg = gridDim.x;
    const int wg  = (blockIdx.x & 7) * (nwg >> 3) + (blockIdx.x >> 3);
    const int nbn = N / BN;
    const int m0  = (wg / nbn) * BM, n0 = (wg % nbn) * BN;

    floatx4 acc[2 * FM][2 * FN];
    #pragma unroll
    for (int i = 0; i < 2 * FM; ++i)
        #pragma unroll
        for (int j = 0; j < 2 * FN; ++j) {
            acc[i][j][0] = 0.f; acc[i][j][1] = 0.f;
            acc[i][j][2] = 0.f; acc[i][j][3] = 0.f;
        }

    // prologue: stage K-tile 0 into buf 0, order [A0,B0,B1,A1]
    stage_unit8<WMR, QMR, LA>(A,  &lds[0],       0, m0, K, 0, wave, lane);
    stage_unit8<WNR, QNR, LB>(Bt, &lds[BM * 64], 0, n0, K, 0, wave, lane);
    stage_unit8<WNR, QNR, LB>(Bt, &lds[BM * 64], 1, n0, K, 0, wave, lane);
    stage_unit8<WMR, QMR, LA>(A,  &lds[0],       1, m0, K, 0, wave, lane);
    waitcnt_vm<LA + LB>();
    __builtin_amdgcn_s_barrier();

    const int NT = K >> 6;

    for (int t = 0; t < NT - 2; t += 2) {
        GEMM8_KTILE(&lds[0],    &lds[BM * 64],        &lds[TILE], (t + 1) << 6, true);
        GEMM8_KTILE(&lds[TILE], &lds[TILE + BM * 64], &lds[0],    (t + 2) << 6, true);
    }
    GEMM8_KTILE(&lds[0], &lds[BM * 64], &lds[TILE], (NT - 1) << 6, true);
    asm volatile("s_waitcnt vmcnt(0)" ::: "memory");
    __builtin_amdgcn_s_barrier();
    GEMM8_KTILE(&lds[TILE], &lds[TILE + BM * 64], &lds[0], 0, false);

    // epilogue: bias add + store (C/D map: col=ln, row=kq*4+r)
    #pragma unroll
    for (int nj = 0; nj < 2 * FN; ++nj) {
        const int col = n0 + wn * WNR + nj * 16 + ln;
        const float bv = bias[col];
        #pragma unroll
        for (int mi = 0; mi < 2 * FM; ++mi) {
            const int rowb = m0 + wm * WMR + mi * 16 + kq * 4;
            #pragma unroll
            for (int r = 0; r < 4; ++r) {
                const float val = acc[mi][nj][r] + bv;
                if (OUTF32) ((float*)Cv)[(size_t)(rowb + r) * N + col] = val;
                else ((unsigned short*)Cv)[(size_t)(rowb + r) * N + col] = f2b(val);
            }
        }
    }
}

// ---------------------------------------------------------------------------
// Fused depthwise causal conv (DCONV=4) + RoPE + q/k/v split-scatter.
// q outputs are pre-multiplied by SL (softmax scale folded into the QK GEMM
// operand) so attn's exp2 args need no per-element multiply.
// ---------------------------------------------------------------------------
__device__ __forceinline__ float conv_at(
    const unsigned short* __restrict__ qb, const float* __restrict__ cw,
    const float* __restrict__ cb, int s, int c)
{
    float acc = cb[c];
    const float* w = cw + c * 4;
    #pragma unroll
    for (int t = 0; t < 4; t++) {
        int sp = s - 3 + t;
        if (sp >= 0) acc += b2f(qb[(size_t)sp * QKV_ + c]) * w[t];
    }
    return acc;
}

__global__ __launch_bounds__(256) void conv_rot(
    const unsigned short* __restrict__ qkv, const float* __restrict__ cw,
    const float* __restrict__ cb, unsigned short* __restrict__ qo,
    unsigned short* __restrict__ ko, unsigned short* __restrict__ vo)
{
    const int bs = blockIdx.x;
    const int b = bs >> 11, s = bs & 2047;
    const unsigned short* qb = qkv + (size_t)b * S_ * QKV_;

    for (int it = threadIdx.x; it < 1792; it += 256) {
        if (it < 1280) {
            const int isq = it < 1024;
            const int rel = isq ? it : it - 1024;
            const int head = rel >> 6, d = rel & 63;
            const int c1 = (isq ? head * 128 : 2048 + head * 128) + d;
            float x1 = conv_at(qb, cw, cb, s, c1);
            float x2 = conv_at(qb, cw, cb, s, c1 + 64);
            float inv = exp2f((float)d * -0.2076205059304601f);  // 10000^(-d/64)
            float ang = (float)s * inv;
            float sn, cs;
            __sincosf(ang, &sn, &cs);   // fast-math: hw v_sin/v_cos, bf16-accurate
            const float sc = isq ? SL : 1.0f;   // fold softmax scale into q
            float r1 = (x1 * cs - x2 * sn) * sc;
            float r2 = (x2 * cs + x1 * sn) * sc;
            unsigned short* dst = isq
                ? qo + ((size_t)(b * H_   + head) * S_ + s) * D_
                : ko + ((size_t)(b * HKV_ + head) * S_ + s) * D_;
            dst[d]      = f2b(r1);
            dst[d + 64] = f2b(r2);
        } else {
            const int idx = it - 1280;          // 0..511
            const int g = idx >> 7, d = idx & 127;
            float vv = conv_at(qb, cw, cb, s, 2560 + idx);
            vo[((size_t)(b * HKV_ + g) * S_ + s) * D_ + d] = f2b(vv);
        }
    }
}

// ---------------------------------------------------------------------------
// Flash attention (causal, GQA rep=4). QBLK=128, 8 waves x 16 q-rows each:
// K/V LDS reads amortized over 8 waves. K/V double-buffered, counted
// vmcnt(4) staging. LDS 80KB -> 2 blocks/CU = 16 waves/CU. qt = b?15-qy:qy
// balances per-CU work (blocks {c,c+256} differ only in b). Scores arrive
// pre-scaled by SL (q folded) -> exp2 args need no multiply. T13 defer-max
// (THR=8 in log2 domain); T5 setprio. Reg-prefetch forbidden (round-2 spill).
// ---------------------------------------------------------------------------
__global__ __launch_bounds__(512, 4) void attn(
    const unsigned short* __restrict__ q, const unsigned short* __restrict__ k,
    const unsigned short* __restrict__ vT, unsigned short* __restrict__ ctx)
{
    __shared__ unsigned short Ks[2][64 * 128];   // 2 x 16 KB, swizzled
    __shared__ unsigned short Vs[2][128 * 64];   // 2 x 16 KB, swizzled
    __shared__ unsigned short Ps[8][16][64];     // 16 KB, per-wave, swizzled

    const int h = blockIdx.x, qy = blockIdx.y, b = blockIdx.z, g = h >> 2;
    const int qt = b ? (15 - qy) : qy;          // per-CU paired load (b differs)
    const int tid = threadIdx.x, wave = tid >> 6, lane = tid & 63;
    const int ln = lane & 15, kq = lane >> 4;

    const unsigned short* qh = q  + (size_t)(b * H_   + h) * S_ * D_;
    const unsigned short* kh = k  + (size_t)(b * HKV_ + g) * S_ * D_;
    const unsigned short* vh = vT + (size_t)(b * HKV_ + g) * D_ * S_;

    // staging geometry: 16 K-chunks + 16 V-chunks of 1 KB; 2+2 per wave
    const int rK = (lane >> 4);          // +4*chunk rows of K per chunk
    const int pK = lane & 15;            // logical granule within K row
    const int rV = (lane >> 3);          // +8*chunk rows of V per chunk
    const int pV = lane & 7;             // logical granule within V row

    const int qrow0 = qt * 128 + wave * 16;   // wave's 16 q-rows

    short8 qf[4];
    #pragma unroll
    for (int f = 0; f < 4; f++)
        qf[f] = *(const short8*)&qh[(size_t)(qrow0 + ln) * D_ + f * 32 + kq * 8];

    floatx4 o[8];
    #pragma unroll
    for (int i = 0; i < 8; i++) { o[i][0] = 0.f; o[i][1] = 0.f; o[i][2] = 0.f; o[i][3] = 0.f; }
    float mr = -INFINITY, lr = 0.f;

    const int KT = 2 * qt + 2;           // 64-row kv tiles covering the block

    // prologue: stage tile 0 into buf 0 (4 loads/wave)
    {
        #pragma unroll
        for (int c = 0; c < 2; c++) {
            const int chunk = wave * 2 + c;        // 0..15
            int r  = chunk * 4 + rK;
            int gc = pK ^ (r & 15);
            load_lds16(&kh[(size_t)r * D_ + gc * 8], &Ks[0][chunk * 512]);
            int rv = chunk * 8 + rV;
            int gv = pV ^ (rv & 7);
            load_lds16(&vh[(size_t)rv * S_ + gv * 8], &Vs[0][chunk * 512]);
        }
    }

    for (int kt = 0; kt < KT; kt++) {
        const int buf = kt & 1;
        // stage next tile into the other buffer (freed by the previous
        // iteration's trailing barrier), then counted wait for THIS tile
        if (kt + 1 < KT) {
            #pragma unroll
            for (int c = 0; c < 2; c++) {
                const int chunk = wave * 2 + c;
                int r  = chunk * 4 + rK;
                int gc = pK ^ (r & 15);
                load_lds16(&kh[(size_t)((kt + 1) * 64 + r) * D_ + gc * 8],
                           &Ks[buf ^ 1][chunk * 512]);
                int rv = chunk * 8 + rV;
                int gv = pV ^ (rv & 7);
                load_lds16(&vh[(size_t)rv * S_ + (kt + 1) * 64 + gv * 8],
                           &Vs[buf ^ 1][chunk * 512]);
            }
            waitcnt_vm<4>();    // this tile's 4 landed; next's 4 in flight
        } else {
            waitcnt_vm<0>();
        }
        __builtin_amdgcn_s_barrier();

        // waves whose q-rows are entirely above this kv tile skip compute
        // (uniform per wave: qrow0, kt both wave-uniform)
        if (kt * 64 <= qrow0 + 15) {
            // S^T = K Q^T : per lane, 16 kv values for q-row (qrow0 + ln)
            floatx4 scv[4];
            #pragma unroll
            for (int nb = 0; nb < 4; nb++) { scv[nb][0]=0.f; scv[nb][1]=0.f; scv[nb][2]=0.f; scv[nb][3]=0.f; }
            __builtin_amdgcn_s_setprio(1);
            #pragma unroll
            for (int ks = 0; ks < 4; ks++) {
                #pragma unroll
                for (int nb = 0; nb < 4; nb++) {
                    short8 kf = *(const short8*)&Ks[buf][(nb * 16 + ln) * 128 + (((ks * 4 + kq) ^ ln) * 8)];
                    scv[nb] = __builtin_amdgcn_mfma_f32_16x16x32_bf16(kf, qf[ks], scv[nb], 0, 0, 0);
                }
            }
            __builtin_amdgcn_s_setprio(0);

            // causal mask when the tile straddles this wave's diagonal
            if (kt * 64 + 63 > qrow0) {
                const int qi = qrow0 + ln;
                #pragma unroll
                for (int nb = 0; nb < 4; nb++)
                    #pragma unroll
                    for (int r = 0; r < 4; r++)
                        if (kt * 64 + nb * 16 + kq * 4 + r > qi) scv[nb][r] = -INFINITY;
            }

            // per-lane online softmax (scores already in log2 domain)
            float mx = -INFINITY;
            #pragma unroll
            for (int nb = 0; nb < 4; nb++) {
                float a0 = fmaxf(scv[nb][0], scv[nb][1]);
                float a1 = fmaxf(scv[nb][2], scv[nb][3]);
                mx = fmaxf(mx, fmaxf(a0, a1));
            }
            mx = fmaxf(mx, __shfl_xor(mx, 16));
            mx = fmaxf(mx, __shfl_xor(mx, 32));

            // T13 defer-max: skip rescale when growth bounded (P <= 2^8)
            float mt = mr, al = 1.0f;
            if (!__all(mx - mr <= DEFER_THR)) {
                mt = fmaxf(mr, mx);
                al = exp2f(mr - mt);
                mr = mt;
                float alr[4];
                #pragma unroll
                for (int r = 0; r < 4; r++) alr[r] = __shfl(al, kq * 4 + r);
                #pragma unroll
                for (int dn = 0; dn < 8; dn++)
                    #pragma unroll
                    for (int r = 0; r < 4; r++) o[dn][r] *= alr[r];
            }

            // p truncated to bf16 (denominator sums the SAME truncated values)
            float rs = 0.f;
            #pragma unroll
            for (int nb = 0; nb < 4; nb++) {
                const int gct = 2 * nb + (kq >> 1);
                const int pbase = ((gct ^ (ln & 7)) << 3) + ((kq & 1) << 2);
                #pragma unroll
                for (int rr = 0; rr < 2; rr++) {
                    unsigned int u0 = fbits(exp2f(scv[nb][2 * rr]     - mt));
                    unsigned int u1 = fbits(exp2f(scv[nb][2 * rr + 1] - mt));
                    rs += bits2f(u0 & 0xFFFF0000u) + bits2f(u1 & 0xFFFF0000u);
                    *(unsigned int*)&Ps[wave][ln][pbase + 2 * rr] =
                        (u0 >> 16) | (u1 & 0xFFFF0000u);
                }
            }
            rs += __shfl_xor(rs, 16);
            rs += __shfl_xor(rs, 32);
            lr = lr * al + rs;

            // O += P V  (Ps wave-private: lgkmcnt ordering suffices)
            short8 pa0 = *(const short8*)&Ps[wave][ln][(kq ^ (ln & 7)) << 3];
            short8 pa1 = *(const short8*)&Ps[wave][ln][((4 + kq) ^ (ln & 7)) << 3];
            __builtin_amdgcn_s_setprio(1);
            #pragma unroll
            for (int dn = 0; dn < 8; dn++) {
                short8 b0 = *(const short8*)&Vs[buf][(dn * 16 + ln) * 64 + ((kq ^ (ln & 7)) * 8)];
                o[dn] = __builtin_amdgcn_mfma_f32_16x16x32_bf16(pa0, b0, o[dn], 0, 0, 0);
                short8 b1 = *(const short8*)&Vs[buf][(dn * 16 + ln) * 64 + (((4 + kq) ^ (ln & 7)) * 8)];
                o[dn] = __builtin_amdgcn_mfma_f32_16x16x32_bf16(pa1, b1, o[dn], 0, 0, 0);
            }
            __builtin_amdgcn_s_setprio(0);
        }

        __builtin_amdgcn_s_barrier();   // all waves done reading buf before
                                        // next iteration's stage overwrites it
    }

    // epilogue: broadcast 1/l to o-layout rows, write ctx[b*S+s][h*D+d]
    float lrr[4];
    #pragma unroll
    for (int r = 0; r < 4; r++) lrr[r] = 1.0f / __shfl(lr, kq * 4 + r);
    #pragma unroll
    for (int r = 0; r < 4; r++) {
        size_t rowoff = (size_t)(b * S_ + qrow0 + kq * 4 + r) * (H_ * D_) + h * D_;
        #pragma unroll
        for (int dn = 0; dn < 8; dn++)
            ctx[rowoff + dn * 16 + ln] = f2b(o[dn][r] * lrr[r]);
    }
}

// ---------------------------------------------------------------------------
// kernel_launch — ws layout (bf16 buffers, total 88 MB):
//   WtIn [3072][2048] @0 (12MB) | WtOut [2048][2048] @12MB (8MB)
//   x16 [4096][2048] @20MB (16MB, ctx aliases after GEMM1)
//   qkv [4096][3072] @36MB (24MB) | q @60MB (16MB) | k @76MB (4MB)
//   v @80MB (4MB) | vT @84MB (4MB)
// ---------------------------------------------------------------------------
extern "C" void kernel_launch(void* const* d_in, const int* in_sizes, int n_in,
                              void* d_out, int out_size, void* d_ws, size_t ws_size,
                              hipStream_t stream)
{
    const float* x     = (const float*)d_in[0];
    const float* W_in  = (const float*)d_in[1];
    const float* b_in  = (const float*)d_in[2];
    const float* cw    = (const float*)d_in[3];
    const float* cb    = (const float*)d_in[4];
    const float* W_out = (const float*)d_in[5];
    const float* b_out = (const float*)d_in[6];
    float* out = (float*)d_out;
    char* ws = (char*)d_ws;

    const size_t MB = 1024 * 1024;
    unsigned short* WtIn  = (unsigned short*)(ws);
    unsigned short* WtOut = (unsigned short*)(ws + 12 * MB);
    unsigned short* x16   = (unsigned short*)(ws + 20 * MB);
    unsigned short* qkv   = (unsigned short*)(ws + 36 * MB);
    unsigned short* qa    = (unsigned short*)(ws + 60 * MB);
    unsigned short* ka    = (unsigned short*)(ws + 76 * MB);
    unsigned short* va    = (unsigned short*)(ws + 80 * MB);
    unsigned short* vTa   = (unsigned short*)(ws + 84 * MB);
    unsigned short* ctx   = (unsigned short*)(ws + 20 * MB);  // aliases x16

    dim3 tb(32, 8);
    hipLaunchKernelGGL(cvt_f32_bf16, dim3(8192), dim3(256), 0, stream, x, x16, 8388608);
    hipLaunchKernelGGL(transpose_f32_bf16, dim3(96, 64), tb, 0, stream, W_in,  WtIn,  2048, 3072);
    hipLaunchKernelGGL(transpose_f32_bf16, dim3(64, 64), tb, 0, stream, W_out, WtOut, 2048, 2048);
    // GEMM1: 4096x3072x2048, 256x192 tiles -> 16x16 = 256 blocks (full device)
    hipLaunchKernelGGL(gemm1_192, dim3(256), dim3(512), 0, stream,
                       x16, WtIn, b_in, qkv, 4096, 3072, 2048);
    hipLaunchKernelGGL(conv_rot, dim3(4096), dim3(256), 0, stream, qkv, cw, cb, qa, ka, va);
    hipLaunchKernelGGL(transpose_bf16, dim3(4, 64, 8), tb, 0, stream, va, vTa, 2048, 128);
    // attn: QBLK=128, 8 waves, grid (h=16, qy=16, b=2) = 512 blocks, 2/CU
    hipLaunchKernelGGL(attn, dim3(16, 16, 2), dim3(512), 0, stream, qa, ka, vTa, ctx);
    // GEMM2: 4096x2048x2048, 256x128 tiles -> 16x16 = 256 blocks (full device)
    hipLaunchKernelGGL((gemm8<128, 4, 2, 1>), dim3(256), dim3(512), 0, stream,
                       ctx, WtOut, b_out, (void*)out, 4096, 2048, 2048);
}

// Round 8
// 332.259 us; speedup vs baseline: 1.3388x; 1.0416x over previous
//
#include <hip/hip_runtime.h>
#include <hip/hip_bf16.h>

// Problem constants
#define B_    2
#define S_    2048
#define E_    2048
#define H_    16
#define HKV_  4
#define D_    128
#define QKV_  3072   // D*(H+2*HKV)

#define LOG2E  1.4426950408889634f
#define SCALE  0.08838834764831845f   // 1/sqrt(128)
#define SL     0.127517431f           // SCALE * LOG2E (folded into q at conv_rot)
#define DEFER_THR 8.0f                // defer-max threshold in log2 domain (P <= 2^8)

typedef __attribute__((ext_vector_type(8))) short short8;   // 8 x bf16 (4 VGPRs)
typedef __attribute__((ext_vector_type(4))) float floatx4;  // MFMA 16x16 accumulator

typedef __attribute__((address_space(1))) const unsigned int gu32;
typedef __attribute__((address_space(3))) unsigned int lu32;

__device__ __forceinline__ void load_lds16(const unsigned short* g, unsigned short* l) {
    // async global->LDS, 16B/lane, dest = wave-uniform base + lane*16 (m97/m104)
    __builtin_amdgcn_global_load_lds((gu32*)g, (lu32*)l, 16, 0, 0);
}

__device__ __forceinline__ float b2f(unsigned short u) {
    union { unsigned int i; float f; } v; v.i = ((unsigned int)u) << 16; return v.f;
}
__device__ __forceinline__ unsigned short f2b(float f) {
    union { float f; unsigned int i; } v; v.f = f;
    unsigned int r = v.i + 0x7FFFu + ((v.i >> 16) & 1u);  // round-to-nearest-even
    return (unsigned short)(r >> 16);
}
__device__ __forceinline__ unsigned int fbits(float f) {
    union { float f; unsigned int i; } v; v.f = f; return v.i;
}

// counted vmcnt wait (never 0 in steady state; T4)
template<int N> __device__ __forceinline__ void waitcnt_vm() {
    static_assert(N >= 0 && N <= 8, "vmcnt out of range");
    if constexpr (N == 0) asm volatile("s_waitcnt vmcnt(0)" ::: "memory");
    else if constexpr (N == 1) asm volatile("s_waitcnt vmcnt(1)" ::: "memory");
    else if constexpr (N == 2) asm volatile("s_waitcnt vmcnt(2)" ::: "memory");
    else if constexpr (N == 3) asm volatile("s_waitcnt vmcnt(3)" ::: "memory");
    else if constexpr (N == 4) asm volatile("s_waitcnt vmcnt(4)" ::: "memory");
    else if constexpr (N == 5) asm volatile("s_waitcnt vmcnt(5)" ::: "memory");
    else if constexpr (N == 6) asm volatile("s_waitcnt vmcnt(6)" ::: "memory");
    else if constexpr (N == 7) asm volatile("s_waitcnt vmcnt(7)" ::: "memory");
    else asm volatile("s_waitcnt vmcnt(8)" ::: "memory");
}

// ---------------------------------------------------------------------------
// f32 -> bf16 convert (contiguous). 4 elems/thread.
// ---------------------------------------------------------------------------
__global__ __launch_bounds__(256) void cvt_f32_bf16(
    const float* __restrict__ src, unsigned short* __restrict__ dst, int n)
{
    int i = (blockIdx.x * 256 + threadIdx.x) * 4;
    if (i + 3 < n) {
        float4 v = *(const float4*)&src[i];
        ushort4 o;
        o.x = f2b(v.x); o.y = f2b(v.y); o.z = f2b(v.z); o.w = f2b(v.w);
        *(ushort4*)&dst[i] = o;
    }
}

// ---------------------------------------------------------------------------
// f32 -> bf16 transpose: src[R][C] f32 -> dst[C][R] bf16. block (32,8).
// ---------------------------------------------------------------------------
__global__ __launch_bounds__(256) void transpose_f32_bf16(
    const float* __restrict__ src, unsigned short* __restrict__ dst,
    int R, int C)
{
    __shared__ unsigned short tile[32][33];
    const int c0 = blockIdx.x * 32, r0 = blockIdx.y * 32;
    const int tx = threadIdx.x, ty = threadIdx.y;
    #pragma unroll
    for (int i = 0; i < 4; i++)
        tile[ty + 8 * i][tx] = f2b(src[(size_t)(r0 + ty + 8 * i) * C + c0 + tx]);
    __syncthreads();
    #pragma unroll
    for (int i = 0; i < 4; i++)
        dst[(size_t)(c0 + ty + 8 * i) * R + r0 + tx] = tile[tx][ty + 8 * i];
}

// ---------------------------------------------------------------------------
// bf16 -> bf16 batched transpose (for V): src[batch][R][C] -> dst[batch][C][R]
// ---------------------------------------------------------------------------
__global__ __launch_bounds__(256) void transpose_bf16(
    const unsigned short* __restrict__ src, unsigned short* __restrict__ dst,
    int R, int C)
{
    __shared__ unsigned short tile[32][33];
    const size_t boff = (size_t)blockIdx.z * R * C;
    src += boff; dst += boff;
    const int c0 = blockIdx.x * 32, r0 = blockIdx.y * 32;
    const int tx = threadIdx.x, ty = threadIdx.y;
    #pragma unroll
    for (int i = 0; i < 4; i++)
        tile[ty + 8 * i][tx] = src[(size_t)(r0 + ty + 8 * i) * C + c0 + tx];
    __syncthreads();
    #pragma unroll
    for (int i = 0; i < 4; i++)
        dst[(size_t)(c0 + ty + 8 * i) * R + r0 + tx] = tile[tx][ty + 8 * i];
}

// ---------------------------------------------------------------------------
// Shared GEMM staging helpers (linear LDS dest + inverse-swizzled source).
// ---------------------------------------------------------------------------
template<int WR, int QR, int LX>
__device__ __forceinline__ void stage_unit8(
    const unsigned short* __restrict__ G, unsigned short* ls,
    int uu, int g0, int K, int k0, int wave, int lane)
{
    #pragma unroll
    for (int l = 0; l < LX; ++l) {
        const int c    = wave * LX + l;
        const int rr   = c / (QR / 8);
        const int row0 = rr * WR + uu * QR + (c % (QR / 8)) * 8;
        const int srow = row0 + (lane >> 3);
        const int sg   = (lane & 7) ^ (lane >> 3);
        load_lds16(&G[(size_t)(g0 + srow) * K + k0 + sg * 8], &ls[row0 * 64]);
    }
}

__device__ __forceinline__ void stage_b64(
    const unsigned short* __restrict__ G, unsigned short* ls,
    int u, int g0, int K, int k0, int wave, int lane)
{
    const int row0 = u * 64 + wave * 8;
    const int srow = row0 + (lane >> 3);
    const int sg   = (lane & 7) ^ (lane >> 3);
    load_lds16(&G[(size_t)(g0 + srow) * K + k0 + sg * 8], &ls[row0 * 64]);
}

// ---------------------------------------------------------------------------
// GEMM K-tile, 2-phase schedule (round-8): phases split by A-quadrant qm;
// B fragments read ONCE per K-tile and held in registers across both phases.
// ds_read per wave per K-tile: GEMM1 20 b128 / 48 MFMA (0.42), GEMM2 16/32
// (0.5) — vs 40/48 and 32/32 in the 4-phase version. Barriers 4/K-tile
// (was 8). Stage: P0 -> B units of t+1, P1 -> A units of t+1.
// Counted waits (derived, in-order retirement):
//  GEMM1 (B=3x1 loads, A=2x2): end-P0 vmcnt(3) [A1(t) landed, B(t+1) in
//  flight]; end-P1 vmcnt(2) [B(t+1)+A0(t+1) landed, A1(t+1) in flight].
//  GEMM2 (B=2x1, A=2x2): end-P0 vmcnt(2); end-P1 vmcnt(2).
// Final tile (no stage): end-P0 vmcnt(0) guards A1, nothing after.
// ---------------------------------------------------------------------------

// ---- GEMM1: 4096x3072x2048, BM=256 BN=192, grid 16x16=256 blocks (1/CU) ----
// 8 waves WM=4 x WN=2; wave 64x96; A rows wm*64+qm*32+i*16; B cols jj*16.
#define G1_KT(ASP, BSP, SA, SB, K1, DO_STAGE)                                      \
  {                                                                                \
    const unsigned short* Asp_ = (ASP);                                            \
    const unsigned short* Bsp_ = (BSP);                                            \
    unsigned short* SA_ = (SA);                                                    \
    unsigned short* SB_ = (SB);                                                    \
    const int k1_ = (K1);                                                          \
    short8 bg[2][6];                                                               \
    _Pragma("unroll")                                                              \
    for (int ks = 0; ks < 2; ++ks)                                                 \
      _Pragma("unroll")                                                            \
      for (int jj = 0; jj < 6; ++jj)                                               \
        bg[ks][jj] = *(const short8*)&Bsp_[(wn * 96 + jj * 16 + ln) * 64           \
                                           + (((ks * 4 + kq) ^ (ln & 7)) * 8)];    \
    _Pragma("unroll")                                                              \
    for (int qm = 0; qm < 2; ++qm) {                                               \
      short8 af[2][2];                                                             \
      _Pragma("unroll")                                                            \
      for (int ks = 0; ks < 2; ++ks)                                               \
        _Pragma("unroll")                                                          \
        for (int i = 0; i < 2; ++i)                                                \
          af[ks][i] = *(const short8*)&Asp_[(wm * 64 + qm * 32 + i * 16 + ln) * 64 \
                                            + (((ks * 4 + kq) ^ (ln & 7)) * 8)];   \
      if (DO_STAGE) {                                                              \
        if (qm == 0) {                                                             \
          stage_b64(Bt, SB_, 0, n0, K, k1_, wave, lane);                           \
          stage_b64(Bt, SB_, 1, n0, K, k1_, wave, lane);                           \
          stage_b64(Bt, SB_, 2, n0, K, k1_, wave, lane);                           \
        } else {                                                                   \
          stage_unit8<64, 32, 2>(A, SA_, 0, m0, K, k1_, wave, lane);               \
          stage_unit8<64, 32, 2>(A, SA_, 1, m0, K, k1_, wave, lane);               \
        }                                                                          \
      }                                                                            \
      __builtin_amdgcn_s_barrier();                                                \
      __builtin_amdgcn_s_setprio(1);                                               \
      _Pragma("unroll")                                                            \
      for (int ks = 0; ks < 2; ++ks)                                               \
        _Pragma("unroll")                                                          \
        for (int i = 0; i < 2; ++i)                                                \
          _Pragma("unroll")                                                        \
          for (int jj = 0; jj < 6; ++jj)                                           \
            acc[qm * 2 + i][jj] = __builtin_amdgcn_mfma_f32_16x16x32_bf16(         \
                af[ks][i], bg[ks][jj], acc[qm * 2 + i][jj], 0, 0, 0);              \
      __builtin_amdgcn_s_setprio(0);                                               \
      if (DO_STAGE) { if (qm == 0) waitcnt_vm<3>(); else waitcnt_vm<2>(); }        \
      else if (qm == 0) waitcnt_vm<0>();                                           \
      __builtin_amdgcn_s_barrier();                                                \
    }                                                                              \
  }

__global__ __launch_bounds__(512, 2) void gemm1_192(
    const unsigned short* __restrict__ A, const unsigned short* __restrict__ Bt,
    const float* __restrict__ bias, unsigned short* __restrict__ C,
    int M, int N, int K)
{
    constexpr int BM = 256, BN = 192;
    constexpr int TILE = (BM + BN) * 64;            // 28672 ushorts / buffer

    __shared__ unsigned short lds[2 * TILE];        // 114688 B

    const int tid  = threadIdx.x;
    const int wave = tid >> 6, lane = tid & 63;
    const int ln   = lane & 15, kq = lane >> 4;
    const int wm   = wave >> 1, wn = wave & 1;      // WM=4 x WN=2

    // T1: XCD-chunked swizzle (nwg = 256, %8 == 0)
    const int nwg = gridDim.x;
    const int wg  = (blockIdx.x & 7) * (nwg >> 3) + (blockIdx.x >> 3);
    const int nbn = N / BN;                         // 16
    const int m0  = (wg / nbn) * BM, n0 = (wg % nbn) * BN;

    floatx4 acc[4][6];
    #pragma unroll
    for (int i = 0; i < 4; ++i)
        #pragma unroll
        for (int j = 0; j < 6; ++j) {
            acc[i][j][0] = 0.f; acc[i][j][1] = 0.f;
            acc[i][j][2] = 0.f; acc[i][j][3] = 0.f;
        }

    // prologue: stage K-tile 0 into buf 0, order [B0,B1,B2,A0,A1]
    stage_b64(Bt, &lds[BM * 64], 0, n0, K, 0, wave, lane);
    stage_b64(Bt, &lds[BM * 64], 1, n0, K, 0, wave, lane);
    stage_b64(Bt, &lds[BM * 64], 2, n0, K, 0, wave, lane);
    stage_unit8<64, 32, 2>(A, &lds[0], 0, m0, K, 0, wave, lane);
    stage_unit8<64, 32, 2>(A, &lds[0], 1, m0, K, 0, wave, lane);
    waitcnt_vm<2>();                 // B all + A0 in; A1 (2 loads) in flight
    __builtin_amdgcn_s_barrier();

    const int NT = K >> 6;           // 32

    for (int t = 0; t < NT - 2; t += 2) {
        G1_KT(&lds[0],    &lds[BM * 64],        &lds[TILE], &lds[TILE + BM * 64], (t + 1) << 6, true);
        G1_KT(&lds[TILE], &lds[TILE + BM * 64], &lds[0],    &lds[BM * 64],        (t + 2) << 6, true);
    }
    G1_KT(&lds[0], &lds[BM * 64], &lds[TILE], &lds[TILE + BM * 64], (NT - 1) << 6, true);
    G1_KT(&lds[TILE], &lds[TILE + BM * 64], &lds[0], &lds[BM * 64], 0, false);

    // epilogue: bias add + bf16 store (C/D map: col=ln, row=kq*4+r)
    #pragma unroll
    for (int nj = 0; nj < 6; ++nj) {
        const int col = n0 + wn * 96 + nj * 16 + ln;
        const float bv = bias[col];
        #pragma unroll
        for (int mi = 0; mi < 4; ++mi) {
            const int rowb = m0 + wm * 64 + mi * 16 + kq * 4;
            #pragma unroll
            for (int r = 0; r < 4; ++r)
                C[(size_t)(rowb + r) * N + col] = f2b(acc[mi][nj][r] + bv);
        }
    }
}

// ---- GEMM2: 4096x2048x2048, BM=256 BN=128, grid 16x16=256 blocks (1/CU) ----
// 8 waves WM=4 x WN=2; wave 64x64; f32 output.
#define G2_KT(ASP, BSP, SA, SB, K1, DO_STAGE)                                      \
  {                                                                                \
    const unsigned short* Asp_ = (ASP);                                            \
    const unsigned short* Bsp_ = (BSP);                                            \
    unsigned short* SA_ = (SA);                                                    \
    unsigned short* SB_ = (SB);                                                    \
    const int k1_ = (K1);                                                          \
    short8 bg[2][4];                                                               \
    _Pragma("unroll")                                                              \
    for (int ks = 0; ks < 2; ++ks)                                                 \
      _Pragma("unroll")                                                            \
      for (int jj = 0; jj < 4; ++jj)                                               \
        bg[ks][jj] = *(const short8*)&Bsp_[(wn * 64 + jj * 16 + ln) * 64           \
                                           + (((ks * 4 + kq) ^ (ln & 7)) * 8)];    \
    _Pragma("unroll")                                                              \
    for (int qm = 0; qm < 2; ++qm) {                                               \
      short8 af[2][2];                                                             \
      _Pragma("unroll")                                                            \
      for (int ks = 0; ks < 2; ++ks)                                               \
        _Pragma("unroll")                                                          \
        for (int i = 0; i < 2; ++i)                                                \
          af[ks][i] = *(const short8*)&Asp_[(wm * 64 + qm * 32 + i * 16 + ln) * 64 \
                                            + (((ks * 4 + kq) ^ (ln & 7)) * 8)];   \
      if (DO_STAGE) {                                                              \
        if (qm == 0) {                                                             \
          stage_unit8<64, 32, 1>(Bt, SB_, 0, n0, K, k1_, wave, lane);              \
          stage_unit8<64, 32, 1>(Bt, SB_, 1, n0, K, k1_, wave, lane);              \
        } else {                                                                   \
          stage_unit8<64, 32, 2>(A, SA_, 0, m0, K, k1_, wave, lane);               \
          stage_unit8<64, 32, 2>(A, SA_, 1, m0, K, k1_, wave, lane);               \
        }                                                                          \
      }                                                                            \
      __builtin_amdgcn_s_barrier();                                                \
      __builtin_amdgcn_s_setprio(1);                                               \
      _Pragma("unroll")                                                            \
      for (int ks = 0; ks < 2; ++ks)                                               \
        _Pragma("unroll")                                                          \
        for (int i = 0; i < 2; ++i)                                                \
          _Pragma("unroll")                                                        \
          for (int jj = 0; jj < 4; ++jj)                                           \
            acc[qm * 2 + i][jj] = __builtin_amdgcn_mfma_f32_16x16x32_bf16(         \
                af[ks][i], bg[ks][jj], acc[qm * 2 + i][jj], 0, 0, 0);              \
      __builtin_amdgcn_s_setprio(0);                                               \
      if (DO_STAGE) waitcnt_vm<2>();                                               \
      else if (qm == 0) waitcnt_vm<0>();                                           \
      __builtin_amdgcn_s_barrier();                                                \
    }                                                                              \
  }

__global__ __launch_bounds__(512, 2) void gemm2_128(
    const unsigned short* __restrict__ A, const unsigned short* __restrict__ Bt,
    const float* __restrict__ bias, float* __restrict__ C,
    int M, int N, int K)
{
    constexpr int BM = 256, BN = 128;
    constexpr int TILE = (BM + BN) * 64;            // 24576 ushorts / buffer

    __shared__ unsigned short lds[2 * TILE];        // 98304 B

    const int tid  = threadIdx.x;
    const int wave = tid >> 6, lane = tid & 63;
    const int ln   = lane & 15, kq = lane >> 4;
    const int wm   = wave >> 1, wn = wave & 1;      // WM=4 x WN=2

    const int nwg = gridDim.x;
    const int wg  = (blockIdx.x & 7) * (nwg >> 3) + (blockIdx.x >> 3);
    const int nbn = N / BN;                         // 16
    const int m0  = (wg / nbn) * BM, n0 = (wg % nbn) * BN;

    floatx4 acc[4][4];
    #pragma unroll
    for (int i = 0; i < 4; ++i)
        #pragma unroll
        for (int j = 0; j < 4; ++j) {
            acc[i][j][0] = 0.f; acc[i][j][1] = 0.f;
            acc[i][j][2] = 0.f; acc[i][j][3] = 0.f;
        }

    // prologue: stage K-tile 0 into buf 0, order [B0,B1,A0,A1]
    stage_unit8<64, 32, 1>(Bt, &lds[BM * 64], 0, n0, K, 0, wave, lane);
    stage_unit8<64, 32, 1>(Bt, &lds[BM * 64], 1, n0, K, 0, wave, lane);
    stage_unit8<64, 32, 2>(A, &lds[0], 0, m0, K, 0, wave, lane);
    stage_unit8<64, 32, 2>(A, &lds[0], 1, m0, K, 0, wave, lane);
    waitcnt_vm<2>();                 // B + A0 in; A1 in flight
    __builtin_amdgcn_s_barrier();

    const int NT = K >> 6;           // 32

    for (int t = 0; t < NT - 2; t += 2) {
        G2_KT(&lds[0],    &lds[BM * 64],        &lds[TILE], &lds[TILE + BM * 64], (t + 1) << 6, true);
        G2_KT(&lds[TILE], &lds[TILE + BM * 64], &lds[0],    &lds[BM * 64],        (t + 2) << 6, true);
    }
    G2_KT(&lds[0], &lds[BM * 64], &lds[TILE], &lds[TILE + BM * 64], (NT - 1) << 6, true);
    G2_KT(&lds[TILE], &lds[TILE + BM * 64], &lds[0], &lds[BM * 64], 0, false);

    // epilogue: bias add + f32 store (C/D map: col=ln, row=kq*4+r)
    #pragma unroll
    for (int nj = 0; nj < 4; ++nj) {
        const int col = n0 + wn * 64 + nj * 16 + ln;
        const float bv = bias[col];
        #pragma unroll
        for (int mi = 0; mi < 4; ++mi) {
            const int rowb = m0 + wm * 64 + mi * 16 + kq * 4;
            #pragma unroll
            for (int r = 0; r < 4; ++r)
                C[(size_t)(rowb + r) * N + col] = acc[mi][nj][r] + bv;
        }
    }
}

// ---------------------------------------------------------------------------
// Fused depthwise causal conv (DCONV=4) + RoPE + q/k/v split-scatter.
// q outputs are pre-multiplied by SL (softmax scale folded into the QK GEMM
// operand) so attn's exp2 args need no per-element multiply.
// ---------------------------------------------------------------------------
__device__ __forceinline__ float conv_at(
    const unsigned short* __restrict__ qb, const float* __restrict__ cw,
    const float* __restrict__ cb, int s, int c)
{
    float acc = cb[c];
    const float* w = cw + c * 4;
    #pragma unroll
    for (int t = 0; t < 4; t++) {
        int sp = s - 3 + t;
        if (sp >= 0) acc += b2f(qb[(size_t)sp * QKV_ + c]) * w[t];
    }
    return acc;
}

__global__ __launch_bounds__(256) void conv_rot(
    const unsigned short* __restrict__ qkv, const float* __restrict__ cw,
    const float* __restrict__ cb, unsigned short* __restrict__ qo,
    unsigned short* __restrict__ ko, unsigned short* __restrict__ vo)
{
    const int bs = blockIdx.x;
    const int b = bs >> 11, s = bs & 2047;
    const unsigned short* qb = qkv + (size_t)b * S_ * QKV_;

    for (int it = threadIdx.x; it < 1792; it += 256) {
        if (it < 1280) {
            const int isq = it < 1024;
            const int rel = isq ? it : it - 1024;
            const int head = rel >> 6, d = rel & 63;
            const int c1 = (isq ? head * 128 : 2048 + head * 128) + d;
            float x1 = conv_at(qb, cw, cb, s, c1);
            float x2 = conv_at(qb, cw, cb, s, c1 + 64);
            float inv = exp2f((float)d * -0.2076205059304601f);  // 10000^(-d/64)
            float ang = (float)s * inv;
            float sn, cs;
            __sincosf(ang, &sn, &cs);   // fast-math: hw v_sin/v_cos, bf16-accurate
            const float sc = isq ? SL : 1.0f;   // fold softmax scale into q
            float r1 = (x1 * cs - x2 * sn) * sc;
            float r2 = (x2 * cs + x1 * sn) * sc;
            unsigned short* dst = isq
                ? qo + ((size_t)(b * H_   + head) * S_ + s) * D_
                : ko + ((size_t)(b * HKV_ + head) * S_ + s) * D_;
            dst[d]      = f2b(r1);
            dst[d + 64] = f2b(r2);
        } else {
            const int idx = it - 1280;          // 0..511
            const int g = idx >> 7, d = idx & 127;
            float vv = conv_at(qb, cw, cb, s, 2560 + idx);
            vo[((size_t)(b * HKV_ + g) * S_ + s) * D_ + d] = f2b(vv);
        }
    }
}

// ---------------------------------------------------------------------------
// Flash attention (causal, GQA rep=4). QBLK=128, 8 waves x 16 q-rows.
// Round-8: denominator via ones-column MFMA (oe = P @ 1) — sums the STORED
// bf16 P exactly (consistent with PV numerator); lr kept in o-layout
// (floatx4 per lane) -> all lr shuffles and the bits-masking adds removed.
// Everything else as round-7 (proven): double-buffered K/V, counted vmcnt(4),
// qt=b?15-qy:qy balance, defer-max THR=8, setprio, no reg-prefetch.
// ---------------------------------------------------------------------------
__global__ __launch_bounds__(512, 4) void attn(
    const unsigned short* __restrict__ q, const unsigned short* __restrict__ k,
    const unsigned short* __restrict__ vT, unsigned short* __restrict__ ctx)
{
    __shared__ unsigned short Ks[2][64 * 128];   // 2 x 16 KB, swizzled
    __shared__ unsigned short Vs[2][128 * 64];   // 2 x 16 KB, swizzled
    __shared__ unsigned short Ps[8][16][64];     // 16 KB, per-wave, swizzled

    const int h = blockIdx.x, qy = blockIdx.y, b = blockIdx.z, g = h >> 2;
    const int qt = b ? (15 - qy) : qy;          // per-CU paired load (b differs)
    const int tid = threadIdx.x, wave = tid >> 6, lane = tid & 63;
    const int ln = lane & 15, kq = lane >> 4;

    const unsigned short* qh = q  + (size_t)(b * H_   + h) * S_ * D_;
    const unsigned short* kh = k  + (size_t)(b * HKV_ + g) * S_ * D_;
    const unsigned short* vh = vT + (size_t)(b * HKV_ + g) * D_ * S_;

    // staging geometry: 16 K-chunks + 16 V-chunks of 1 KB; 2+2 per wave
    const int rK = (lane >> 4);          // +4*chunk rows of K per chunk
    const int pK = lane & 15;            // logical granule within K row
    const int rV = (lane >> 3);          // +8*chunk rows of V per chunk
    const int pV = lane & 7;             // logical granule within V row

    const int qrow0 = qt * 128 + wave * 16;   // wave's 16 q-rows

    short8 qf[4];
    #pragma unroll
    for (int f = 0; f < 4; f++)
        qf[f] = *(const short8*)&qh[(size_t)(qrow0 + ln) * D_ + f * 32 + kq * 8];

    short8 ones;                          // bf16 1.0 x8 (denominator column)
    #pragma unroll
    for (int j = 0; j < 8; j++) ones[j] = (short)0x3F80;

    floatx4 o[8];
    #pragma unroll
    for (int i = 0; i < 8; i++) { o[i][0] = 0.f; o[i][1] = 0.f; o[i][2] = 0.f; o[i][3] = 0.f; }
    floatx4 lrv; lrv[0] = 0.f; lrv[1] = 0.f; lrv[2] = 0.f; lrv[3] = 0.f;
    float mr = -INFINITY;

    const int KT = 2 * qt + 2;           // 64-row kv tiles covering the block

    // prologue: stage tile 0 into buf 0 (4 loads/wave)
    {
        #pragma unroll
        for (int c = 0; c < 2; c++) {
            const int chunk = wave * 2 + c;        // 0..15
            int r  = chunk * 4 + rK;
            int gc = pK ^ (r & 15);
            load_lds16(&kh[(size_t)r * D_ + gc * 8], &Ks[0][chunk * 512]);
            int rv = chunk * 8 + rV;
            int gv = pV ^ (rv & 7);
            load_lds16(&vh[(size_t)rv * S_ + gv * 8], &Vs[0][chunk * 512]);
        }
    }

    for (int kt = 0; kt < KT; kt++) {
        const int buf = kt & 1;
        if (kt + 1 < KT) {
            #pragma unroll
            for (int c = 0; c < 2; c++) {
                const int chunk = wave * 2 + c;
                int r  = chunk * 4 + rK;
                int gc = pK ^ (r & 15);
                load_lds16(&kh[(size_t)((kt + 1) * 64 + r) * D_ + gc * 8],
                           &Ks[buf ^ 1][chunk * 512]);
                int rv = chunk * 8 + rV;
                int gv = pV ^ (rv & 7);
                load_lds16(&vh[(size_t)rv * S_ + (kt + 1) * 64 + gv * 8],
                           &Vs[buf ^ 1][chunk * 512]);
            }
            waitcnt_vm<4>();    // this tile's 4 landed; next's 4 in flight
        } else {
            waitcnt_vm<0>();
        }
        __builtin_amdgcn_s_barrier();

        // waves whose q-rows are entirely above this kv tile skip compute
        if (kt * 64 <= qrow0 + 15) {
            // S^T = K Q^T : per lane, 16 kv values for q-row (qrow0 + ln)
            floatx4 scv[4];
            #pragma unroll
            for (int nb = 0; nb < 4; nb++) { scv[nb][0]=0.f; scv[nb][1]=0.f; scv[nb][2]=0.f; scv[nb][3]=0.f; }
            __builtin_amdgcn_s_setprio(1);
            #pragma unroll
            for (int ks = 0; ks < 4; ks++) {
                #pragma unroll
                for (int nb = 0; nb < 4; nb++) {
                    short8 kf = *(const short8*)&Ks[buf][(nb * 16 + ln) * 128 + (((ks * 4 + kq) ^ ln) * 8)];
                    scv[nb] = __builtin_amdgcn_mfma_f32_16x16x32_bf16(kf, qf[ks], scv[nb], 0, 0, 0);
                }
            }
            __builtin_amdgcn_s_setprio(0);

            // causal mask when the tile straddles this wave's diagonal
            if (kt * 64 + 63 > qrow0) {
                const int qi = qrow0 + ln;
                #pragma unroll
                for (int nb = 0; nb < 4; nb++)
                    #pragma unroll
                    for (int r = 0; r < 4; r++)
                        if (kt * 64 + nb * 16 + kq * 4 + r > qi) scv[nb][r] = -INFINITY;
            }

            // per-lane online softmax max (scores already in log2 domain);
            // nested triples fuse to v_max3
            float mx = fmaxf(fmaxf(scv[0][0], scv[0][1]), scv[0][2]);
            mx = fmaxf(fmaxf(mx, scv[0][3]), scv[1][0]);
            mx = fmaxf(fmaxf(mx, scv[1][1]), scv[1][2]);
            mx = fmaxf(fmaxf(mx, scv[1][3]), scv[2][0]);
            mx = fmaxf(fmaxf(mx, scv[2][1]), scv[2][2]);
            mx = fmaxf(fmaxf(mx, scv[2][3]), scv[3][0]);
            mx = fmaxf(fmaxf(mx, scv[3][1]), scv[3][2]);
            mx = fmaxf(mx, scv[3][3]);
            mx = fmaxf(mx, __shfl_xor(mx, 16));
            mx = fmaxf(mx, __shfl_xor(mx, 32));

            // T13 defer-max: skip rescale when growth bounded (P <= 2^8)
            float mt = mr;
            if (!__all(mx - mr <= DEFER_THR)) {
                mt = fmaxf(mr, mx);
                float al = exp2f(mr - mt);
                mr = mt;
                float alr[4];
                #pragma unroll
                for (int r = 0; r < 4; r++) alr[r] = __shfl(al, kq * 4 + r);
                #pragma unroll
                for (int dn = 0; dn < 8; dn++)
                    #pragma unroll
                    for (int r = 0; r < 4; r++) o[dn][r] *= alr[r];
                #pragma unroll
                for (int r = 0; r < 4; r++) lrv[r] *= alr[r];
            }

            // p truncated to bf16; stored to Ps (granule-swizzled)
            #pragma unroll
            for (int nb = 0; nb < 4; nb++) {
                const int gct = 2 * nb + (kq >> 1);
                const int pbase = ((gct ^ (ln & 7)) << 3) + ((kq & 1) << 2);
                #pragma unroll
                for (int rr = 0; rr < 2; rr++) {
                    unsigned int u0 = fbits(exp2f(scv[nb][2 * rr]     - mt));
                    unsigned int u1 = fbits(exp2f(scv[nb][2 * rr + 1] - mt));
                    *(unsigned int*)&Ps[wave][ln][pbase + 2 * rr] =
                        (u0 >> 16) | (u1 & 0xFFFF0000u);
                }
            }

            // O += P V ; denominator oe = P @ ones (sums STORED bf16 exactly)
            short8 pa0 = *(const short8*)&Ps[wave][ln][(kq ^ (ln & 7)) << 3];
            short8 pa1 = *(const short8*)&Ps[wave][ln][((4 + kq) ^ (ln & 7)) << 3];
            __builtin_amdgcn_s_setprio(1);
            floatx4 oe; oe[0] = 0.f; oe[1] = 0.f; oe[2] = 0.f; oe[3] = 0.f;
            oe = __builtin_amdgcn_mfma_f32_16x16x32_bf16(pa0, ones, oe, 0, 0, 0);
            oe = __builtin_amdgcn_mfma_f32_16x16x32_bf16(pa1, ones, oe, 0, 0, 0);
            #pragma unroll
            for (int dn = 0; dn < 8; dn++) {
                short8 b0 = *(const short8*)&Vs[buf][(dn * 16 + ln) * 64 + ((kq ^ (ln & 7)) * 8)];
                o[dn] = __builtin_amdgcn_mfma_f32_16x16x32_bf16(pa0, b0, o[dn], 0, 0, 0);
                short8 b1 = *(const short8*)&Vs[buf][(dn * 16 + ln) * 64 + (((4 + kq) ^ (ln & 7)) * 8)];
                o[dn] = __builtin_amdgcn_mfma_f32_16x16x32_bf16(pa1, b1, o[dn], 0, 0, 0);
            }
            __builtin_amdgcn_s_setprio(0);
            #pragma unroll
            for (int r = 0; r < 4; r++) lrv[r] += oe[r];
        }

        __builtin_amdgcn_s_barrier();   // all waves done reading buf before
                                        // next iteration's stage overwrites it
    }

    // epilogue: 1/l already in o-layout (row = kq*4+r), write ctx
    #pragma unroll
    for (int r = 0; r < 4; r++) {
        const float lrr = 1.0f / lrv[r];
        size_t rowoff = (size_t)(b * S_ + qrow0 + kq * 4 + r) * (H_ * D_) + h * D_;
        #pragma unroll
        for (int dn = 0; dn < 8; dn++)
            ctx[rowoff + dn * 16 + ln] = f2b(o[dn][r] * lrr);
    }
}

// ---------------------------------------------------------------------------
// kernel_launch — ws layout (bf16 buffers, total 88 MB):
//   WtIn [3072][2048] @0 (12MB) | WtOut [2048][2048] @12MB (8MB)
//   x16 [4096][2048] @20MB (16MB, ctx aliases after GEMM1)
//   qkv [4096][3072] @36MB (24MB) | q @60MB (16MB) | k @76MB (4MB)
//   v @80MB (4MB) | vT @84MB (4MB)
// ---------------------------------------------------------------------------
extern "C" void kernel_launch(void* const* d_in, const int* in_sizes, int n_in,
                              void* d_out, int out_size, void* d_ws, size_t ws_size,
                              hipStream_t stream)
{
    const float* x     = (const float*)d_in[0];
    const float* W_in  = (const float*)d_in[1];
    const float* b_in  = (const float*)d_in[2];
    const float* cw    = (const float*)d_in[3];
    const float* cb    = (const float*)d_in[4];
    const float* W_out = (const float*)d_in[5];
    const float* b_out = (const float*)d_in[6];
    float* out = (float*)d_out;
    char* ws = (char*)d_ws;

    const size_t MB = 1024 * 1024;
    unsigned short* WtIn  = (unsigned short*)(ws);
    unsigned short* WtOut = (unsigned short*)(ws + 12 * MB);
    unsigned short* x16   = (unsigned short*)(ws + 20 * MB);
    unsigned short* qkv   = (unsigned short*)(ws + 36 * MB);
    unsigned short* qa    = (unsigned short*)(ws + 60 * MB);
    unsigned short* ka    = (unsigned short*)(ws + 76 * MB);
    unsigned short* va    = (unsigned short*)(ws + 80 * MB);
    unsigned short* vTa   = (unsigned short*)(ws + 84 * MB);
    unsigned short* ctx   = (unsigned short*)(ws + 20 * MB);  // aliases x16

    dim3 tb(32, 8);
    hipLaunchKernelGGL(cvt_f32_bf16, dim3(8192), dim3(256), 0, stream, x, x16, 8388608);
    hipLaunchKernelGGL(transpose_f32_bf16, dim3(96, 64), tb, 0, stream, W_in,  WtIn,  2048, 3072);
    hipLaunchKernelGGL(transpose_f32_bf16, dim3(64, 64), tb, 0, stream, W_out, WtOut, 2048, 2048);
    // GEMM1: 4096x3072x2048, 256x192 tiles -> 16x16 = 256 blocks (full device)
    hipLaunchKernelGGL(gemm1_192, dim3(256), dim3(512), 0, stream,
                       x16, WtIn, b_in, qkv, 4096, 3072, 2048);
    hipLaunchKernelGGL(conv_rot, dim3(4096), dim3(256), 0, stream, qkv, cw, cb, qa, ka, va);
    hipLaunchKernelGGL(transpose_bf16, dim3(4, 64, 8), tb, 0, stream, va, vTa, 2048, 128);
    // attn: QBLK=128, 8 waves, grid (h=16, qy=16, b=2) = 512 blocks, 2/CU
    hipLaunchKernelGGL(attn, dim3(16, 16, 2), dim3(512), 0, stream, qa, ka, vTa, ctx);
    // GEMM2: 4096x2048x2048, 256x128 tiles -> 16x16 = 256 blocks (full device)
    hipLaunchKernelGGL(gemm2_128, dim3(256), dim3(512), 0, stream,
                       ctx, WtOut, b_out, out, 4096, 2048, 2048);
}